// Round 2
// baseline (13046.411 us; speedup 1.0000x reference)
//
#include <hip/hip_runtime.h>
#include <cstddef>
#include <cstdint>

constexpr int N_NODES = 16384;
constexpr int D_MODEL = 512;
constexpr int C_OUT   = 40;
constexpr int CW      = 256;                 // channel chunk width
constexpr int ND      = N_NODES * D_MODEL;   // per-timestep elements (512-ch)
constexpr int M2      = 2 * N_NODES;         // T*N rows

typedef int i32x4 __attribute__((ext_vector_type(4)));

// digit scales: w ≈ Σ d_j * S_j, residual ≤ 2^-38 (5 digits)
#define S0 0.001953125                      // 2^-9
#define S1 1.52587890625e-05                // 2^-16
#define S2 1.1920928955078125e-07           // 2^-23
#define S3 9.31322574615478515625e-10       // 2^-30
#define S4 7.2759576141834259033203125e-12  // 2^-37

// digit-plane offsets within the per-layer buffer (bytes)
#define WD_Q 0
#define WD_K 1310720
#define WD_V 2621440
#define WD_O 3932160
#define WD_1 5242880
#define WD_2 7864320
#define WD_TOTAL 10485760

// ===========================================================================
// Per-layer weight -> 5 signed-i8 digit planes in MFMA B-fragment order:
// byte at ((k/16)*N + n)*80 + j*16 + (k%16).
// One thread per (k-group-of-16, n): 16 coalesced column loads, digits
// built in registers, 5x16B fully-contiguous vector stores (80 B/thread).
// ===========================================================================
__global__ __launch_bounds__(256)
void w_digits_layer(const float* __restrict__ wq, const float* __restrict__ wk,
                    const float* __restrict__ wv, const float* __restrict__ wo,
                    const float* __restrict__ w1, const float* __restrict__ w2,
                    uint8_t* __restrict__ Wd) {
    int idx = blockIdx.x * 256 + threadIdx.x;   // [0, 131072)
    const float* W;
    uint8_t* outb;
    int N, rem;
    if (idx < 65536) {                          // wq,wk,wv,wo: 4 x (32 kg x 512 n)
        int mm = idx >> 14;
        rem = idx & 16383;
        const float* ptrs[4] = {wq, wk, wv, wo};
        W = ptrs[mm]; outb = Wd + (size_t)mm * 1310720; N = 512;
    } else if (idx < 98304) {                   // w1: 32 kg x 1024 n
        rem = idx - 65536; W = w1; outb = Wd + WD_1; N = 1024;
    } else {                                    // w2: 64 kg x 512 n
        rem = idx - 98304; W = w2; outb = Wd + WD_2; N = 512;
    }
    int kg = rem / N, n = rem - kg * N;
    const float* Wp = W + (size_t)kg * 16 * N + n;
    uint8_t* out = outb + (size_t)(kg * N + n) * 80;
    const double scl[5] = {512.0, 65536.0, 8388608.0, 1073741824.0, 137438953472.0};
    const double inv[5] = {S0, S1, S2, S3, S4};
    union { uint8_t b[5][16]; i32x4 v[5]; } db;
#pragma unroll
    for (int kk = 0; kk < 16; ++kk) {
        double r = (double)Wp[(size_t)kk * N];
#pragma unroll
        for (int j = 0; j < 5; ++j) {
            int d = (int)rint(r * scl[j]);
            d = d > 127 ? 127 : (d < -127 ? -127 : d);
            r -= (double)d * inv[j];
            db.b[j][kk] = (uint8_t)(int8_t)d;
        }
    }
#pragma unroll
    for (int j = 0; j < 5; ++j)
        *reinterpret_cast<i32x4*>(out + j * 16) = db.v[j];
}

// ===========================================================================
// Spike GEMM via i8 MFMA, exact fixed-point. 128-row blocks, LDS-staged B.
// Fused per-column BN stats AND (new) last-block BN finalize: the final
// block converts (sum,sumsq) -> (scale,shift) in place, so the bn_* kernels
// need no per-thread f64 sqrt/div. Same f64 expression order (bit-identical).
// ===========================================================================
__global__ __launch_bounds__(256)
void gemm_i8_bits(const uint64_t* __restrict__ bits, int kWords,
                  const uint8_t* __restrict__ Wd, int Nmat, int colOff,
                  double* __restrict__ C, int ldc, int K,
                  double* __restrict__ sum, double* __restrict__ sumsq,
                  const float* __restrict__ g, const float* __restrict__ b,
                  double invM, int* __restrict__ ctr) {
    __shared__ __attribute__((aligned(16))) uint8_t Bs[20480];
    const int lane = threadIdx.x & 63;
    const int wv   = threadIdx.x >> 6;
    const int m    = lane & 15;
    const int q    = lane >> 4;
    const int rowT = blockIdx.y * 128 + wv * 32;   // this wave's 32-row tile
    const int colB = blockIdx.x * 64;

    i32x4 acc[2][4][5];
#pragma unroll
    for (int rt = 0; rt < 2; ++rt)
#pragma unroll
        for (int t = 0; t < 4; ++t)
#pragma unroll
            for (int j = 0; j < 5; ++j) acc[rt][t][j] = (i32x4){0, 0, 0, 0};

    const uint64_t* brow0 = bits + (size_t)(rowT + m) * kWords;
    const uint64_t* brow1 = brow0 + (size_t)16 * kWords;
    const size_t cb = (size_t)(colOff + colB);

    for (int kb = 0; kb < K; kb += 64) {
        // --- load the 4-ktile x 64-col x 80B digit tile (20KB) to registers ---
        i32x4 tmp[5];
        const size_t kt0 = (size_t)(kb >> 4);
#pragma unroll
        for (int c5 = 0; c5 < 5; ++c5) {
            int c  = threadIdx.x + c5 * 256;       // [0,1280) 16B chunks
            int kt = c / 320;                      // ktile (5120B each, contiguous)
            int of = c - kt * 320;
            tmp[c5] = *reinterpret_cast<const i32x4*>(
                Wd + ((kt0 + (size_t)kt) * Nmat + cb) * 80 + (size_t)of * 16);
        }
        // --- A spike fragments for both row-tiles ---
        uint64_t wb0 = brow0[kb >> 6];
        uint64_t wb1 = brow1[kb >> 6];
        uint32_t hw0 = (uint32_t)(wb0 >> (q * 16)) & 0xFFFFu;
        uint32_t hw1 = (uint32_t)(wb1 >> (q * 16)) & 0xFFFFu;
        i32x4 af0, af1;
#pragma unroll
        for (int i = 0; i < 4; ++i) {
            af0[i] = (int)((((hw0 >> (4 * i)) & 0xFu) * 0x00204081u) & 0x01010101u);
            af1[i] = (int)((((hw1 >> (4 * i)) & 0xFu) * 0x00204081u) & 0x01010101u);
        }
        __syncthreads();                 // previous tile fully consumed
#pragma unroll
        for (int c5 = 0; c5 < 5; ++c5) {
            int c  = threadIdx.x + c5 * 256;
            int kt = c / 320;
            int of = c - kt * 320;
            *reinterpret_cast<i32x4*>(Bs + kt * 5120 + of * 16) = tmp[c5];
        }
        __syncthreads();                 // tile staged
#pragma unroll
        for (int t = 0; t < 4; ++t) {
            const uint8_t* bt = Bs + q * 5120 + (t * 16 + m) * 80;
            i32x4 bf[5];
#pragma unroll
            for (int j = 0; j < 5; ++j)
                bf[j] = *reinterpret_cast<const i32x4*>(bt + j * 16);
#pragma unroll
            for (int j = 0; j < 5; ++j) {
                acc[0][t][j] = __builtin_amdgcn_mfma_i32_16x16x64_i8(af0, bf[j], acc[0][t][j], 0, 0, 0);
                acc[1][t][j] = __builtin_amdgcn_mfma_i32_16x16x64_i8(af1, bf[j], acc[1][t][j], 0, 0, 0);
            }
        }
    }

    double sarr[4], qarr[4];
#pragma unroll
    for (int t = 0; t < 4; ++t) { sarr[t] = 0.0; qarr[t] = 0.0; }
#pragma unroll
    for (int rt = 0; rt < 2; ++rt) {
        const int orow = rowT + rt * 16 + q * 4;
#pragma unroll
        for (int t = 0; t < 4; ++t) {
            double* Cc = C + (size_t)orow * ldc + colB + t * 16 + m;
#pragma unroll
            for (int i = 0; i < 4; ++i) {
                double p = (double)acc[rt][t][0][i] * S0 + (double)acc[rt][t][1][i] * S1
                         + (double)acc[rt][t][2][i] * S2 + (double)acc[rt][t][3][i] * S3
                         + (double)acc[rt][t][4][i] * S4;
                Cc[(size_t)i * ldc] = p;
                sarr[t] += p; qarr[t] += p * p;
            }
        }
    }
    __shared__ double ls[4][64], lq[4][64];
#pragma unroll
    for (int t = 0; t < 4; ++t) {
        double s = sarr[t], qq = qarr[t];
        s  += __shfl_xor(s, 16);  s  += __shfl_xor(s, 32);
        qq += __shfl_xor(qq, 16); qq += __shfl_xor(qq, 32);
        if (lane < 16) { ls[wv][t * 16 + lane] = s; lq[wv][t * 16 + lane] = qq; }
    }
    __syncthreads();
    if (threadIdx.x < 64) {
        int t = threadIdx.x;
        double s  = ls[0][t] + ls[1][t] + ls[2][t] + ls[3][t];
        double qq = lq[0][t] + lq[1][t] + lq[2][t] + lq[3][t];
        atomicAdd(&sum[colB + t], s);
        atomicAdd(&sumsq[colB + t], qq);
    }
    // ---- last-block BN finalize: (sum,sumsq) -> (sc,sh) in place ----
    __threadfence();
    __shared__ int isLast;
    if (threadIdx.x == 0) {
        int total = (int)(gridDim.x * gridDim.y);
        isLast = (atomicAdd(ctr, 1) == total - 1) ? 1 : 0;
    }
    __syncthreads();
    if (isLast) {
        int c = threadIdx.x;                       // 256 channels
        double s  = atomicAdd(&sum[c], 0.0);       // device-coherent reads
        double qq = atomicAdd(&sumsq[c], 0.0);
        double mn  = s * invM;
        double var = qq * invM - mn * mn;
        double sc = (double)g[c] / sqrt(var + 1e-5);
        double sh = (double)b[c] - mn * sc;
        sum[c]   = sc;
        sumsq[c] = sh;
    }
}

// head GEMM: exact f64 gather (immune to any MFMA layout quirk)
__global__ __launch_bounds__(256)
void head_gather(const uint64_t* __restrict__ bits, const float* __restrict__ W,
                 const float* __restrict__ bias, float* __restrict__ Y) {
    const int lane = threadIdx.x & 63;
    const int wid  = threadIdx.x >> 6;
    const int r = blockIdx.x * 4 + wid;
    if (lane >= C_OUT) return;
    double acc = (double)bias[lane];
    const uint64_t* bw = bits + (size_t)r * 8;
    for (int j = 0; j < 8; ++j) {
        uint64_t w = bw[j];
        const float* Wk = W + (size_t)j * 64 * C_OUT + lane;
        while (w) {
            int k = __builtin_ctzll(w);
            w &= w - 1;
            acc += (double)Wk[(size_t)k * C_OUT];
        }
    }
    Y[(size_t)r * C_OUT + lane] = (float)acc;
}

// GEMM (float A, double out) — fc0 only.
// v3: f32 LDS staging (exact: convert to f64 at the FMA), float4 LDS reads,
// XOR swizzle kills the 4-way Bs-read bank conflicts.
__global__ __launch_bounds__(256)
void gemm_f32d(const float* __restrict__ A, int lda,
               const float* __restrict__ B, int ldb,
               const float* __restrict__ bias,
               double* __restrict__ C, int ldc, int M, int Nc, int K) {
    __shared__ float As[16][64];
    __shared__ float Bs[16][64];
    const int tid = threadIdx.x;
    const int tx  = tid & 15, ty = tid >> 4;
    const int row0 = blockIdx.y * 64 + ty * 4;
    const int col0 = blockIdx.x * 64 + tx * 4;
    const int ar = tid >> 2, ak = (tid & 3) * 4;   // A: row ar, k ak..ak+3
    const int bk = tid >> 4, bn = (tid & 15) * 4;  // B: k-row bk, cols bn..bn+3
    const int gm = blockIdx.y * 64 + ar;
    double acc[4][4];
#pragma unroll
    for (int i = 0; i < 4; i++)
#pragma unroll
        for (int j = 0; j < 4; j++) acc[i][j] = 0.0;
    for (int k0 = 0; k0 < K; k0 += 16) {
        float4 av = *reinterpret_cast<const float4*>(&A[(size_t)gm * lda + k0 + ak]);
        const float* avp = reinterpret_cast<const float*>(&av);
#pragma unroll
        for (int j = 0; j < 4; j++)
            As[ak + j][ar ^ ((ak + j) & 12)] = avp[j];
        float4 bv = *reinterpret_cast<const float4*>(
            &B[(size_t)(k0 + bk) * ldb + blockIdx.x * 64 + bn]);
        *reinterpret_cast<float4*>(&Bs[bk][bn ^ ((bk & 3) << 2)]) = bv;
        __syncthreads();
#pragma unroll
        for (int kk = 0; kk < 16; kk++) {
            float4 a4 = *reinterpret_cast<const float4*>(&As[kk][(ty * 4) ^ (kk & 12)]);
            float4 b4 = *reinterpret_cast<const float4*>(&Bs[kk][(tx * 4) ^ ((kk & 3) << 2)]);
            const float* ap = reinterpret_cast<const float*>(&a4);
            const float* bp = reinterpret_cast<const float*>(&b4);
#pragma unroll
            for (int i = 0; i < 4; i++)
#pragma unroll
                for (int j = 0; j < 4; j++)
                    acc[i][j] = fma((double)ap[i], (double)bp[j], acc[i][j]);
        }
        __syncthreads();
    }
#pragma unroll
    for (int i = 0; i < 4; i++) {
        int r = row0 + i;
        if (r >= M) continue;
#pragma unroll
        for (int j = 0; j < 4; j++) {
            int c = col0 + j;
            if (c < Nc) {
                double v = acc[i][j];
                if (bias) v += (double)bias[c];
                C[(size_t)r * ldc + c] = v;
            }
        }
    }
}

// GEMM (float A/B/C, double acc) — GNN branch.
__global__ __launch_bounds__(256)
void gemm_f32(const float* __restrict__ A, int lda,
              const float* __restrict__ B, int ldb,
              const float* __restrict__ bias,
              float* __restrict__ C, int ldc, int M, int Nc, int K) {
    __shared__ float As[16][64];
    __shared__ float Bs[16][64];
    const int tid = threadIdx.x;
    const int tx  = tid & 15, ty = tid >> 4;
    const int row0 = blockIdx.y * 64 + ty * 4;
    const int col0 = blockIdx.x * 64 + tx * 4;
    const int ar = tid >> 2, ak = (tid & 3) * 4;
    const int bk = tid >> 4, bn = (tid & 15) * 4;
    const int gm = blockIdx.y * 64 + ar;
    double acc[4][4];
#pragma unroll
    for (int i = 0; i < 4; i++)
#pragma unroll
        for (int j = 0; j < 4; j++) acc[i][j] = 0.0;
    for (int k0 = 0; k0 < K; k0 += 16) {
#pragma unroll
        for (int j = 0; j < 4; j++) {
            int kk = k0 + ak + j;
            As[ak + j][ar] = (gm < M && kk < K) ? A[(size_t)gm * lda + kk] : 0.f;
        }
#pragma unroll
        for (int j = 0; j < 4; j++) {
            int gn = blockIdx.x * 64 + bn + j;
            int kk = k0 + bk;
            Bs[bk][bn + j] = (gn < Nc && kk < K) ? B[(size_t)kk * ldb + gn] : 0.f;
        }
        __syncthreads();
#pragma unroll
        for (int kk = 0; kk < 16; kk++) {
            float a4[4], b4[4];
#pragma unroll
            for (int i = 0; i < 4; i++) a4[i] = As[kk][ty * 4 + i];
#pragma unroll
            for (int j = 0; j < 4; j++) b4[j] = Bs[kk][tx * 4 + j];
#pragma unroll
            for (int i = 0; i < 4; i++)
#pragma unroll
                for (int j = 0; j < 4; j++) acc[i][j] = fma((double)a4[i], (double)b4[j], acc[i][j]);
        }
        __syncthreads();
    }
#pragma unroll
    for (int i = 0; i < 4; i++) {
        int r = row0 + i;
        if (r >= M) continue;
#pragma unroll
        for (int j = 0; j < 4; j++) {
            int c = col0 + j;
            if (c < Nc) {
                double v = acc[i][j];
                if (bias) v += (double)bias[c];
                C[(size_t)r * ldc + c] = (float)v;
            }
        }
    }
}

// BN stats for fp32 inputs (GNN branch) -> per-gate buffers
__global__ __launch_bounds__(256)
void col_stats_f(const float* __restrict__ X, int M, int Ch, int rowsPerBlock,
                 double* __restrict__ sum, double* __restrict__ sumsq) {
    const int cl = threadIdx.x & 63;
    const int c  = blockIdx.x * 64 + cl;
    const int rg = threadIdx.x >> 6;
    const int r0 = blockIdx.y * rowsPerBlock;
    const int r1 = min(r0 + rowsPerBlock, M);
    double s = 0.0, q = 0.0;
    if (c < Ch) {
        for (int r = r0 + rg; r < r1; r += 4) {
            double v = (double)X[(size_t)r * Ch + c];
            s += v; q += v * v;
        }
    }
    __shared__ double ls[4][64], lq[4][64];
    ls[rg][cl] = s; lq[rg][cl] = q;
    __syncthreads();
    if (rg == 0 && c < Ch) {
        s = ls[0][cl] + ls[1][cl] + ls[2][cl] + ls[3][cl];
        q = lq[0][cl] + lq[1][cl] + lq[2][cl] + lq[3][cl];
        atomicAdd(&sum[c], s);
        atomicAdd(&sumsq[c], q);
    }
}

// ===========================================================================
// LIF helpers (exact ref arithmetic, f64)
// ===========================================================================
__device__ __forceinline__ void lif2(double x0, double x1, bool& s0, bool& s1) {
    double v = x0 * 0.5;
    s0 = (v >= 1.0);
    v = s0 ? 0.0 : v;
    v = v + (x1 - v) * 0.5;
    s1 = (v >= 1.0);
}

__device__ __forceinline__ void bn_params(const double* sum, const double* sumsq,
                                          const float* g, const float* b, double invM,
                                          int c, double& sc, double& sh) {
    double m   = sum[c] * invM;
    double var = sumsq[c] * invM - m * m;
    sc = (double)g[c] / sqrt(var + 1e-5);
    sh = (double)b[c] - m * sc;
}

// attention output (exact fp32) -> spike bits
__global__ __launch_bounds__(256)
void lif_bits_f(const float* __restrict__ O, uint64_t* __restrict__ S) {
    int i = blockIdx.x * 256 + threadIdx.x;
    bool s0, s1;
    lif2((double)O[i], (double)O[(size_t)i + ND], s0, s1);
    uint64_t b0 = __ballot(s0), b1 = __ballot(s1);
    if ((threadIdx.x & 63) == 0) {
        int widx = i >> 6;
        S[widx] = b0;
        S[widx + N_NODES * 8] = b1;
    }
}

// BN(precomputed sc/sh) + LIF on a 256-ch chunk -> bits at chOff
__global__ __launch_bounds__(256)
void bn_lif_bits2(const double* __restrict__ X, const double* __restrict__ scsh,
                  uint64_t* __restrict__ S, int osWords, int chOffWords) {
    int i = blockIdx.x * 256 + threadIdx.x;   // i < N*256
    int n = i >> 8, c = i & 255;
    double sc = scsh[c], sh = scsh[c + 256];
    bool s0, s1;
    lif2((double)X[i] * sc + sh, (double)X[(size_t)i + (size_t)N_NODES * 256] * sc + sh, s0, s1);
    uint64_t b0 = __ballot(s0), b1 = __ballot(s1);
    if ((threadIdx.x & 63) == 0) {
        int widx = n * osWords + chOffWords + (c >> 6);
        S[widx] = b0;
        S[widx + N_NODES * osWords] = b1;
    }
}

// h += bn(X) (precomputed sc/sh) AND emit lif(h_new) bits for this chunk
__global__ __launch_bounds__(256)
void bn_add_lif2(const double* __restrict__ X, const double* __restrict__ scsh,
                 double* __restrict__ H, int chOff, uint64_t* __restrict__ S) {
    int i = blockIdx.x * 256 + threadIdx.x;   // i < N*256
    int n = i >> 8, c = i & 255;
    double sc = scsh[c], sh = scsh[c + 256];
    size_t hi = (size_t)n * 512 + chOff + c;
    double h0 = H[hi] + ((double)X[i] * sc + sh);
    double h1 = H[hi + ND] + ((double)X[(size_t)i + (size_t)N_NODES * 256] * sc + sh);
    H[hi] = h0;
    H[hi + ND] = h1;
    bool s0, s1;
    lif2(h0, h1, s0, s1);
    uint64_t b0 = __ballot(s0), b1 = __ballot(s1);
    if ((threadIdx.x & 63) == 0) {
        int widx = n * 8 + (chOff >> 6) + (c >> 6);
        S[widx] = b0;
        S[widx + N_NODES * 8] = b1;
    }
}

// LayerNorm(512)+ReLU on fc0 output; write both t-slices of h AND emit lif bits
__global__ __launch_bounds__(256)
void ln_relu_lif(const double* __restrict__ X, const float* __restrict__ g,
                 const float* __restrict__ b, double* __restrict__ H,
                 uint64_t* __restrict__ S) {
    int n = blockIdx.x;
    const double* x = X + (size_t)n * 512;
    int c0 = threadIdx.x, c1 = threadIdx.x + 256;
    double v0 = x[c0], v1 = x[c1];
    __shared__ double ls[256], lq[256];
    ls[threadIdx.x] = v0 + v1;
    lq[threadIdx.x] = v0 * v0 + v1 * v1;
    __syncthreads();
    for (int off = 128; off > 0; off >>= 1) {
        if (threadIdx.x < off) {
            ls[threadIdx.x] += ls[threadIdx.x + off];
            lq[threadIdx.x] += lq[threadIdx.x + off];
        }
        __syncthreads();
    }
    double m    = ls[0] * (1.0 / 512);
    double var  = lq[0] * (1.0 / 512) - m * m;
    double rstd = 1.0 / sqrt(var + 1e-5);
    double o0 = (v0 - m) * rstd * (double)g[c0] + (double)b[c0];
    double o1 = (v1 - m) * rstd * (double)g[c1] + (double)b[c1];
    o0 = o0 > 0.0 ? o0 : 0.0;
    o1 = o1 > 0.0 ? o1 : 0.0;
    double* h0 = H + (size_t)n * 512;
    h0[c0] = o0; h0[c1] = o1;
    h0[ND + c0] = o0; h0[ND + c1] = o1;
    // lif with x0 == x1 == o
    bool a0, a1, d0, d1;
    lif2(o0, o0, a0, a1);
    lif2(o1, o1, d0, d1);
    uint64_t ba0 = __ballot(a0), ba1 = __ballot(a1);
    uint64_t bd0 = __ballot(d0), bd1 = __ballot(d1);
    if ((threadIdx.x & 63) == 0) {
        int w = threadIdx.x >> 6;
        S[n * 8 + w] = ba0;
        S[n * 8 + w + N_NODES * 8] = ba1;
        S[n * 8 + 4 + w] = bd0;
        S[n * 8 + 4 + w + N_NODES * 8] = bd1;
    }
}

// ===========================================================================
// Attention on bit spikes (integer-exact in fp32).
// ===========================================================================
__global__ __launch_bounds__(256)
void kv_bits(const uint64_t* __restrict__ Kb, const uint64_t* __restrict__ Vb,
             float* __restrict__ KV, int nPerBlock) {
    const int th = blockIdx.x;
    const int t = th >> 3, h = th & 7;
    const int nbase = blockIdx.y * nPerBlock;
    const int e = threadIdx.x & 63, dg = threadIdx.x >> 6;
    float acc[16];
#pragma unroll
    for (int i = 0; i < 16; i++) acc[i] = 0.f;
    __shared__ float ks[8][64], vs[8][64];
    const size_t wbase = (size_t)t * N_NODES * 8 + h;
    for (int n0 = 0; n0 < nPerBlock; n0 += 8) {
        for (int idx = threadIdx.x; idx < 8 * 128; idx += 256) {
            int r = idx >> 7, c = idx & 127;
            size_t wi = wbase + (size_t)(nbase + n0 + r) * 8;
            if (c < 64) ks[r][c] = (float)((Kb[wi] >> c) & 1ull);
            else        vs[r][c - 64] = (float)((Vb[wi] >> (c - 64)) & 1ull);
        }
        __syncthreads();
#pragma unroll
        for (int r = 0; r < 8; ++r) {
            float ve = vs[r][e];
#pragma unroll
            for (int i = 0; i < 16; ++i) acc[i] += ks[r][dg * 16 + i] * ve;
        }
        __syncthreads();
    }
    float* kvp = KV + (size_t)th * 4096;
    for (int i = 0; i < 16; ++i)
        atomicAdd(&kvp[(dg * 16 + i) * 64 + e], acc[i]);
}

__global__ __launch_bounds__(256)
void o_bits(const uint64_t* __restrict__ Qb, const float* __restrict__ KV,
            float* __restrict__ O) {
    const int th = blockIdx.y;
    const int t = th >> 3, h = th & 7;
    const int nb = blockIdx.x;
    __shared__ float kvs[64][64];
    __shared__ float qs[64][65];
    const float* kvp = KV + (size_t)th * 4096;
    for (int idx = threadIdx.x; idx < 4096; idx += 256)
        kvs[idx >> 6][idx & 63] = kvp[idx];
    const size_t wbase = ((size_t)t * N_NODES + (size_t)nb * 64) * 8 + h;
    for (int idx = threadIdx.x; idx < 4096; idx += 256) {
        int r = idx >> 6, c = idx & 63;
        qs[r][c] = (float)((Qb[wbase + (size_t)r * 8] >> c) & 1ull);
    }
    __syncthreads();
    const int e = threadIdx.x & 63, rg = threadIdx.x >> 6;
    float acc[16];
#pragma unroll
    for (int i = 0; i < 16; i++) acc[i] = 0.f;
    for (int d = 0; d < 64; ++d) {
        float kv = kvs[d][e];
#pragma unroll
        for (int i = 0; i < 16; ++i) acc[i] += qs[rg * 16 + i][d] * kv;
    }
    const size_t obase = ((size_t)t * N_NODES + (size_t)nb * 64) * 512 + (size_t)h * 64;
    for (int i = 0; i < 16; ++i)
        O[obase + (size_t)(rg * 16 + i) * 512 + e] = acc[i] * 0.125f;
}

// ===========================================================================
// GNN branch (fp32)
// ===========================================================================
__global__ __launch_bounds__(256)
void deg_kernel(const int* __restrict__ col, float* __restrict__ deg, int E) {
    int e = blockIdx.x * 256 + threadIdx.x;
    if (e < E) atomicAdd(&deg[col[e]], 1.0f);
}

__global__ __launch_bounds__(256)
void dinv_kernel(float* __restrict__ deg, int n) {
    int i = blockIdx.x * 256 + threadIdx.x;
    if (i < n) {
        double d = (double)deg[i];
        deg[i] = d > 0.0 ? (float)(1.0 / sqrt(d)) : 0.f;
    }
}

__global__ __launch_bounds__(256)
void agg_kernel(const float* __restrict__ G, const int* __restrict__ row,
                const int* __restrict__ col, const float* __restrict__ dinv,
                float* __restrict__ out, int E) {
    int idx = blockIdx.x * 256 + threadIdx.x;
    int e = idx >> 6, c = idx & 63;
    if (e >= E || c >= C_OUT) return;
    int r = row[e], cl = col[e];
    float val = dinv[cl] * dinv[r];
    atomicAdd(&out[(size_t)cl * C_OUT + c], val * G[(size_t)r * C_OUT + c]);
}

__global__ __launch_bounds__(256)
void bn_relu_add_f2(const float* __restrict__ X,
                    const double* __restrict__ sum, const double* __restrict__ sumsq,
                    const float* __restrict__ g, const float* __restrict__ b, double invM,
                    const float* __restrict__ add, float* __restrict__ out, int NC, int Ch) {
    int i = blockIdx.x * 256 + threadIdx.x;
    if (i >= NC) return;
    int c = i % Ch;
    double sc, sh;
    bn_params(sum, sumsq, g, b, invM, c, sc, sh);
    double v = (double)X[i] * sc + sh;
    v = v > 0.0 ? v : 0.0;
    if (add) v += (double)add[i];
    out[i] = (float)v;
}

__global__ __launch_bounds__(256)
void mix_kernel(const float* __restrict__ G, const float* __restrict__ Y,
                float* __restrict__ P, int NC) {
    int i = blockIdx.x * 256 + threadIdx.x;
    if (i >= NC) return;
    double y = 0.5 * ((double)Y[i] + (double)Y[(size_t)i + NC]);
    P[i] = (float)(0.8 * (double)G[i] + 0.2 * y);
}

__global__ __launch_bounds__(256)
void final_fc_kernel(const float* __restrict__ A, const float* __restrict__ W,
                     const float* __restrict__ bias, float* __restrict__ out) {
    __shared__ float Ws[40][40];
    for (int idx = threadIdx.x; idx < 1600; idx += 256)
        Ws[idx / 40][idx % 40] = W[idx];
    __syncthreads();
    int i = blockIdx.x * 256 + threadIdx.x;
    if (i >= N_NODES * C_OUT) return;
    int n = i / 40, c = i - n * 40;
    const float* a = A + (size_t)n * 40;
    double acc = (double)bias[c];
#pragma unroll 8
    for (int k = 0; k < 40; ++k) acc += (double)a[k] * (double)Ws[k][c];
    out[i] = (float)acc;
}

// ===========================================================================
// Host orchestration
// ===========================================================================
static inline dim3 grid1(long n) { return dim3((unsigned)((n + 255) / 256)); }

extern "C" void kernel_launch(void* const* d_in, const int* in_sizes, int n_in,
                              void* d_out, int out_size, void* d_ws, size_t ws_size,
                              hipStream_t stream) {
    const float* x      = (const float*)d_in[0];
    const float* fc0_w  = (const float*)d_in[1];
    const float* fc0_b  = (const float*)d_in[2];
    const float* ln_g   = (const float*)d_in[3];
    const float* ln_b   = (const float*)d_in[4];
    const float* wq     = (const float*)d_in[5];
    const float* wk     = (const float*)d_in[6];
    const float* wv     = (const float*)d_in[7];
    const float* wo     = (const float*)d_in[8];
    const float* bnq_g  = (const float*)d_in[9];
    const float* bnq_b  = (const float*)d_in[10];
    const float* bnk_g  = (const float*)d_in[11];
    const float* bnk_b  = (const float*)d_in[12];
    const float* bnv_g  = (const float*)d_in[13];
    const float* bnv_b  = (const float*)d_in[14];
    const float* bno_g  = (const float*)d_in[15];
    const float* bno_b  = (const float*)d_in[16];
    const float* w1     = (const float*)d_in[17];
    const float* bn1_g  = (const float*)d_in[18];
    const float* bn1_b  = (const float*)d_in[19];
    const float* w2     = (const float*)d_in[20];
    const float* bn2_g  = (const float*)d_in[21];
    const float* bn2_b  = (const float*)d_in[22];
    const float* head_w = (const float*)d_in[23];
    const float* head_b = (const float*)d_in[24];
    const float* gfc_w  = (const float*)d_in[25];
    const float* gfc_b  = (const float*)d_in[26];
    const float* gbn0_g = (const float*)d_in[27];
    const float* gbn0_b = (const float*)d_in[28];
    const float* gconv_w= (const float*)d_in[29];
    const float* gconv_b= (const float*)d_in[30];
    const float* gbn_g  = (const float*)d_in[31];
    const float* gbn_b  = (const float*)d_in[32];
    const float* fc_w   = (const float*)d_in[33];
    const float* fc_b   = (const float*)d_in[34];
    const int*   edge   = (const int*)d_in[35];

    const int E = in_sizes[35] / 2;
    const int* erow = edge;
    const int* ecol = edge + E;
    const int NC = N_NODES * C_OUT;

    // ---- workspace layout (~234 MiB) ----
    uint8_t* wsbase = (uint8_t*)d_ws;
    size_t off = 0;
    auto alloc = [&](size_t bytes, size_t align) -> void* {
        off = (off + align - 1) & ~(align - 1);
        void* p = wsbase + off;
        off += bytes;
        return p;
    };
    double*   statBuf = (double*)alloc((size_t)64 * 512 * sizeof(double), 256);  // per-gate stats
    int*      ctrBuf  = (int*)alloc((size_t)64 * sizeof(int), 256);              // finalize counters
    double*   h_buf  = (double*)alloc((size_t)2 * ND * sizeof(double), 256);     // 134 MB
    double*   Pd     = (double*)alloc((size_t)M2 * CW * sizeof(double), 256);    // 67 MB
    float*    O32    = (float*)Pd;   // alias: attention output (exact fp32)
    uint8_t*  Wdig   = (uint8_t*)alloc((size_t)WD_TOTAL, 256);                   // 10.5 MB
    uint64_t* s_bits = (uint64_t*)alloc((size_t)2 * N_NODES * 8 * 8, 256);
    uint64_t* q_bits = (uint64_t*)alloc((size_t)2 * N_NODES * 8 * 8, 256);
    uint64_t* k_bits = (uint64_t*)alloc((size_t)2 * N_NODES * 8 * 8, 256);
    uint64_t* v_bits = (uint64_t*)alloc((size_t)2 * N_NODES * 8 * 8, 256);
    uint64_t* m_bits = (uint64_t*)alloc((size_t)2 * N_NODES * 16 * 8, 256);      // 4.2 MB
    float*    ybuf   = (float*)m_bits;  // alias: y written at head, after m_bits dead
    // (ybuf needs 5.24 MB; m_bits is 4.2 MB — extend with a pad alloc)
    (void)alloc((size_t)2 * NC * sizeof(float) > (size_t)2 * N_NODES * 16 * 8
                ? (size_t)2 * NC * sizeof(float) - (size_t)2 * N_NODES * 16 * 8 : 0, 256);
    float*    g0     = (float*)alloc((size_t)NC * sizeof(float), 256);
    float*    gg     = (float*)alloc((size_t)NC * sizeof(float), 256);
    float*    ag     = (float*)alloc((size_t)NC * sizeof(float), 256);
    float*    kvb    = (float*)alloc((size_t)65536 * sizeof(float), 256);
    float*    deg    = (float*)alloc((size_t)N_NODES * sizeof(float), 256);
    if (off > ws_size) return;

    const dim3 blk(256);
    const dim3 gLIF((unsigned)(ND / 256));
    const dim3 gCHK((unsigned)(N_NODES));
    const dim3 gGEMM(CW / 64, M2 / 128);
    const double invM2 = 1.0 / (double)M2;
    const double invMN = 1.0 / (double)N_NODES;

    hipMemsetAsync(statBuf, 0, (size_t)64 * 512 * sizeof(double), stream);
    hipMemsetAsync(ctrBuf, 0, (size_t)64 * sizeof(int), stream);

    int gate = 0;

    // ===== transformer branch =====
    hipLaunchKernelGGL(gemm_f32d, dim3(8, N_NODES / 64), blk, 0, stream,
                       x, 512, fc0_w, 512, fc0_b, Pd, 512, N_NODES, 512, 512);
    hipLaunchKernelGGL(ln_relu_lif, dim3(N_NODES), blk, 0, stream, Pd, ln_g, ln_b, h_buf, s_bits);

    for (int l = 0; l < 4; ++l) {
        // one prep launch for all 6 matrices of this layer
        hipLaunchKernelGGL(w_digits_layer, dim3(512), blk, 0, stream,
                           wq + (size_t)l * 262144, wk + (size_t)l * 262144,
                           wv + (size_t)l * 262144, wo + (size_t)l * 262144,
                           w1 + (size_t)l * 524288, w2 + (size_t)l * 524288, Wdig);

        uint64_t* qkvb[3] = {q_bits, k_bits, v_bits};
        const size_t wdoff[3] = {WD_Q, WD_K, WD_V};
        const float* gmat[3] = {bnq_g + l * 512, bnk_g + l * 512, bnv_g + l * 512};
        const float* bmat[3] = {bnq_b + l * 512, bnk_b + l * 512, bnv_b + l * 512};
        for (int j = 0; j < 3; ++j) {
            for (int c0 = 0; c0 < 512; c0 += CW) {
                double* st = statBuf + (size_t)gate * 512;
                int* ct = ctrBuf + gate;
                gate++;
                hipLaunchKernelGGL(gemm_i8_bits, gGEMM, blk, 0, stream,
                                   s_bits, 8, Wdig + wdoff[j], 512, c0, Pd, CW, 512,
                                   st, st + 256, gmat[j] + c0, bmat[j] + c0, invM2, ct);
                hipLaunchKernelGGL(bn_lif_bits2, gCHK, blk, 0, stream,
                                   Pd, st, qkvb[j], 8, c0 / 64);
            }
        }

        // attention (exact); lif output -> q_bits (free after o_bits)
        hipMemsetAsync(kvb, 0, 65536 * sizeof(float), stream);
        hipLaunchKernelGGL(kv_bits, dim3(16, 16), blk, 0, stream, k_bits, v_bits, kvb, 1024);
        hipLaunchKernelGGL(o_bits, dim3(N_NODES / 64, 16), blk, 0, stream, q_bits, kvb, O32);
        hipLaunchKernelGGL(lif_bits_f, gLIF, blk, 0, stream, O32, q_bits);

        // h += bn(lif(o) @ wo); emit s = lif(h_new) into s_bits
        for (int c0 = 0; c0 < 512; c0 += CW) {
            double* st = statBuf + (size_t)gate * 512;
            int* ct = ctrBuf + gate;
            gate++;
            hipLaunchKernelGGL(gemm_i8_bits, gGEMM, blk, 0, stream,
                               q_bits, 8, Wdig + WD_O, 512, c0, Pd, CW, 512,
                               st, st + 256, bno_g + l * 512 + c0, bno_b + l * 512 + c0, invM2, ct);
            hipLaunchKernelGGL(bn_add_lif2, gCHK, blk, 0, stream,
                               Pd, st, h_buf, c0, s_bits);
        }

        // MLP: m = lif(bn1(s @ w1)) in 4 chunks of 256
        for (int c0 = 0; c0 < 1024; c0 += CW) {
            double* st = statBuf + (size_t)gate * 512;
            int* ct = ctrBuf + gate;
            gate++;
            hipLaunchKernelGGL(gemm_i8_bits, gGEMM, blk, 0, stream,
                               s_bits, 8, Wdig + WD_1, 1024, c0, Pd, CW, 512,
                               st, st + 256, bn1_g + l * 1024 + c0, bn1_b + l * 1024 + c0, invM2, ct);
            hipLaunchKernelGGL(bn_lif_bits2, gCHK, blk, 0, stream,
                               Pd, st, m_bits, 16, c0 / 64);
        }
        // h += bn2(m @ w2); emit s = lif(h_new) for next layer / head
        for (int c0 = 0; c0 < 512; c0 += CW) {
            double* st = statBuf + (size_t)gate * 512;
            int* ct = ctrBuf + gate;
            gate++;
            hipLaunchKernelGGL(gemm_i8_bits, gGEMM, blk, 0, stream,
                               m_bits, 16, Wdig + WD_2, 512, c0, Pd, CW, 1024,
                               st, st + 256, bn2_g + l * 512 + c0, bn2_b + l * 512 + c0, invM2, ct);
            hipLaunchKernelGGL(bn_add_lif2, gCHK, blk, 0, stream,
                               Pd, st, h_buf, c0, s_bits);
        }
    }

    // head: y = s @ head_w + head_b (s_bits already = lif(h_final))
    hipLaunchKernelGGL(head_gather, dim3(M2 / 4), blk, 0, stream, s_bits, head_w, head_b, ybuf);

    // ===== GNN branch (fp32) =====
    hipLaunchKernelGGL(gemm_f32, dim3(1, N_NODES / 64), blk, 0, stream,
                       x, 512, gfc_w, 40, gfc_b, ag, 40, N_NODES, 40, 512);
    {
        double* st = statBuf + (size_t)gate * 512;
        gate++;
        dim3 gs(1, (N_NODES + 511) / 512);
        hipLaunchKernelGGL(col_stats_f, gs, blk, 0, stream, ag, N_NODES, 40, 512, st, st + 256);
        hipLaunchKernelGGL(bn_relu_add_f2, grid1(NC), blk, 0, stream,
                           ag, st, st + 256, gbn0_g, gbn0_b, invMN,
                           (const float*)nullptr, g0, NC, 40);
    }

    hipMemsetAsync(deg, 0, N_NODES * sizeof(float), stream);
    hipLaunchKernelGGL(deg_kernel, grid1(E), blk, 0, stream, ecol, deg, E);
    hipLaunchKernelGGL(dinv_kernel, grid1(N_NODES), blk, 0, stream, deg, N_NODES);

    const float* gsrc = g0;
    for (int i = 0; i < 2; ++i) {
        hipMemsetAsync(ag, 0, (size_t)NC * sizeof(float), stream);
        hipLaunchKernelGGL(agg_kernel, grid1((long)E * 64), blk, 0, stream,
                           gsrc, erow, ecol, deg, ag, E);
        hipLaunchKernelGGL(gemm_f32, dim3(1, N_NODES / 64), blk, 0, stream,
                           ag, 40, gconv_w + (size_t)i * 40 * 40, 40, gconv_b + i * 40,
                           gg, 40, N_NODES, 40, 40);
        double* st = statBuf + (size_t)gate * 512;
        gate++;
        dim3 gs(1, (N_NODES + 511) / 512);
        hipLaunchKernelGGL(col_stats_f, gs, blk, 0, stream, gg, N_NODES, 40, 512, st, st + 256);
        hipLaunchKernelGGL(bn_relu_add_f2, grid1(NC), blk, 0, stream,
                           gg, st, st + 256, gbn_g + i * 40, gbn_b + i * 40, invMN, g0, gg, NC, 40);
        gsrc = gg;
    }

    // out = (0.8*g + 0.2*mean_t(y)) @ fc_w + fc_b
    hipLaunchKernelGGL(mix_kernel, grid1(NC), blk, 0, stream, gg, ybuf, ag, NC);
    hipLaunchKernelGGL(final_fc_kernel, grid1((long)N_NODES * C_OUT), blk, 0, stream,
                       ag, fc_w, fc_b, (float*)d_out);
}

// Round 3
// 6605.022 us; speedup vs baseline: 1.9752x; 1.9752x over previous
//
#include <hip/hip_runtime.h>
#include <cstddef>
#include <cstdint>

constexpr int N_NODES = 16384;
constexpr int D_MODEL = 512;
constexpr int C_OUT   = 40;
constexpr int CW      = 256;                 // channel chunk width
constexpr int ND      = N_NODES * D_MODEL;   // per-timestep elements (512-ch)
constexpr int M2      = 2 * N_NODES;         // T*N rows

typedef int i32x4 __attribute__((ext_vector_type(4)));

// digit scales: w ≈ Σ d_j * S_j, residual ≤ 2^-38 (5 digits)
#define S0 0.001953125                      // 2^-9
#define S1 1.52587890625e-05                // 2^-16
#define S2 1.1920928955078125e-07           // 2^-23
#define S3 9.31322574615478515625e-10       // 2^-30
#define S4 7.2759576141834259033203125e-12  // 2^-37

// digit-plane offsets within the per-layer buffer (bytes)
#define WD_Q 0
#define WD_K 1310720
#define WD_V 2621440
#define WD_O 3932160
#define WD_1 5242880
#define WD_2 7864320
#define WD_TOTAL 10485760

// ===========================================================================
// Per-layer weight -> 5 signed-i8 digit planes in MFMA B-fragment order:
// byte at ((k/16)*N + n)*80 + j*16 + (k%16).
// One thread per (k-group-of-16, n): 16 coalesced column loads, digits
// built in registers, 5x16B fully-contiguous vector stores (80 B/thread).
// ===========================================================================
__global__ __launch_bounds__(256)
void w_digits_layer(const float* __restrict__ wq, const float* __restrict__ wk,
                    const float* __restrict__ wv, const float* __restrict__ wo,
                    const float* __restrict__ w1, const float* __restrict__ w2,
                    uint8_t* __restrict__ Wd) {
    int idx = blockIdx.x * 256 + threadIdx.x;   // [0, 131072)
    const float* W;
    uint8_t* outb;
    int N, rem;
    if (idx < 65536) {                          // wq,wk,wv,wo: 4 x (32 kg x 512 n)
        int mm = idx >> 14;
        rem = idx & 16383;
        const float* ptrs[4] = {wq, wk, wv, wo};
        W = ptrs[mm]; outb = Wd + (size_t)mm * 1310720; N = 512;
    } else if (idx < 98304) {                   // w1: 32 kg x 1024 n
        rem = idx - 65536; W = w1; outb = Wd + WD_1; N = 1024;
    } else {                                    // w2: 64 kg x 512 n
        rem = idx - 98304; W = w2; outb = Wd + WD_2; N = 512;
    }
    int kg = rem / N, n = rem - kg * N;
    const float* Wp = W + (size_t)kg * 16 * N + n;
    uint8_t* out = outb + (size_t)(kg * N + n) * 80;
    const double scl[5] = {512.0, 65536.0, 8388608.0, 1073741824.0, 137438953472.0};
    const double inv[5] = {S0, S1, S2, S3, S4};
    union { uint8_t b[5][16]; i32x4 v[5]; } db;
#pragma unroll
    for (int kk = 0; kk < 16; ++kk) {
        double r = (double)Wp[(size_t)kk * N];
#pragma unroll
        for (int j = 0; j < 5; ++j) {
            int d = (int)rint(r * scl[j]);
            d = d > 127 ? 127 : (d < -127 ? -127 : d);
            r -= (double)d * inv[j];
            db.b[j][kk] = (uint8_t)(int8_t)d;
        }
    }
#pragma unroll
    for (int j = 0; j < 5; ++j)
        *reinterpret_cast<i32x4*>(out + j * 16) = db.v[j];
}

// ===========================================================================
// Spike GEMM via i8 MFMA, exact fixed-point. 128-row blocks, LDS-staged B.
// Fused per-column BN stats into per-gate buffers. (NO device fences here —
// R2 showed a per-block __threadfence costs ~100µs/launch on 8-XCD MI355X.)
// ===========================================================================
__global__ __launch_bounds__(256)
void gemm_i8_bits(const uint64_t* __restrict__ bits, int kWords,
                  const uint8_t* __restrict__ Wd, int Nmat, int colOff,
                  double* __restrict__ C, int ldc, int K,
                  double* __restrict__ sum, double* __restrict__ sumsq) {
    __shared__ __attribute__((aligned(16))) uint8_t Bs[20480];
    const int lane = threadIdx.x & 63;
    const int wv   = threadIdx.x >> 6;
    const int m    = lane & 15;
    const int q    = lane >> 4;
    const int rowT = blockIdx.y * 128 + wv * 32;   // this wave's 32-row tile
    const int colB = blockIdx.x * 64;

    i32x4 acc[2][4][5];
#pragma unroll
    for (int rt = 0; rt < 2; ++rt)
#pragma unroll
        for (int t = 0; t < 4; ++t)
#pragma unroll
            for (int j = 0; j < 5; ++j) acc[rt][t][j] = (i32x4){0, 0, 0, 0};

    const uint64_t* brow0 = bits + (size_t)(rowT + m) * kWords;
    const uint64_t* brow1 = brow0 + (size_t)16 * kWords;
    const size_t cb = (size_t)(colOff + colB);

    for (int kb = 0; kb < K; kb += 64) {
        // --- load the 4-ktile x 64-col x 80B digit tile (20KB) to registers ---
        i32x4 tmp[5];
        const size_t kt0 = (size_t)(kb >> 4);
#pragma unroll
        for (int c5 = 0; c5 < 5; ++c5) {
            int c  = threadIdx.x + c5 * 256;       // [0,1280) 16B chunks
            int kt = c / 320;                      // ktile (5120B each, contiguous)
            int of = c - kt * 320;
            tmp[c5] = *reinterpret_cast<const i32x4*>(
                Wd + ((kt0 + (size_t)kt) * Nmat + cb) * 80 + (size_t)of * 16);
        }
        // --- A spike fragments for both row-tiles ---
        uint64_t wb0 = brow0[kb >> 6];
        uint64_t wb1 = brow1[kb >> 6];
        uint32_t hw0 = (uint32_t)(wb0 >> (q * 16)) & 0xFFFFu;
        uint32_t hw1 = (uint32_t)(wb1 >> (q * 16)) & 0xFFFFu;
        i32x4 af0, af1;
#pragma unroll
        for (int i = 0; i < 4; ++i) {
            af0[i] = (int)((((hw0 >> (4 * i)) & 0xFu) * 0x00204081u) & 0x01010101u);
            af1[i] = (int)((((hw1 >> (4 * i)) & 0xFu) * 0x00204081u) & 0x01010101u);
        }
        __syncthreads();                 // previous tile fully consumed
#pragma unroll
        for (int c5 = 0; c5 < 5; ++c5) {
            int c  = threadIdx.x + c5 * 256;
            int kt = c / 320;
            int of = c - kt * 320;
            *reinterpret_cast<i32x4*>(Bs + kt * 5120 + of * 16) = tmp[c5];
        }
        __syncthreads();                 // tile staged
#pragma unroll
        for (int t = 0; t < 4; ++t) {
            const uint8_t* bt = Bs + q * 5120 + (t * 16 + m) * 80;
            i32x4 bf[5];
#pragma unroll
            for (int j = 0; j < 5; ++j)
                bf[j] = *reinterpret_cast<const i32x4*>(bt + j * 16);
#pragma unroll
            for (int j = 0; j < 5; ++j) {
                acc[0][t][j] = __builtin_amdgcn_mfma_i32_16x16x64_i8(af0, bf[j], acc[0][t][j], 0, 0, 0);
                acc[1][t][j] = __builtin_amdgcn_mfma_i32_16x16x64_i8(af1, bf[j], acc[1][t][j], 0, 0, 0);
            }
        }
    }

    double sarr[4], qarr[4];
#pragma unroll
    for (int t = 0; t < 4; ++t) { sarr[t] = 0.0; qarr[t] = 0.0; }
#pragma unroll
    for (int rt = 0; rt < 2; ++rt) {
        const int orow = rowT + rt * 16 + q * 4;
#pragma unroll
        for (int t = 0; t < 4; ++t) {
            double* Cc = C + (size_t)orow * ldc + colB + t * 16 + m;
#pragma unroll
            for (int i = 0; i < 4; ++i) {
                double p = (double)acc[rt][t][0][i] * S0 + (double)acc[rt][t][1][i] * S1
                         + (double)acc[rt][t][2][i] * S2 + (double)acc[rt][t][3][i] * S3
                         + (double)acc[rt][t][4][i] * S4;
                Cc[(size_t)i * ldc] = p;
                sarr[t] += p; qarr[t] += p * p;
            }
        }
    }
    __shared__ double ls[4][64], lq[4][64];
#pragma unroll
    for (int t = 0; t < 4; ++t) {
        double s = sarr[t], qq = qarr[t];
        s  += __shfl_xor(s, 16);  s  += __shfl_xor(s, 32);
        qq += __shfl_xor(qq, 16); qq += __shfl_xor(qq, 32);
        if (lane < 16) { ls[wv][t * 16 + lane] = s; lq[wv][t * 16 + lane] = qq; }
    }
    __syncthreads();
    if (threadIdx.x < 64) {
        int t = threadIdx.x;
        double s  = ls[0][t] + ls[1][t] + ls[2][t] + ls[3][t];
        double qq = lq[0][t] + lq[1][t] + lq[2][t] + lq[3][t];
        atomicAdd(&sum[colB + t], s);
        atomicAdd(&sumsq[colB + t], qq);
    }
}

// head GEMM: exact f64 gather (immune to any MFMA layout quirk)
__global__ __launch_bounds__(256)
void head_gather(const uint64_t* __restrict__ bits, const float* __restrict__ W,
                 const float* __restrict__ bias, float* __restrict__ Y) {
    const int lane = threadIdx.x & 63;
    const int wid  = threadIdx.x >> 6;
    const int r = blockIdx.x * 4 + wid;
    if (lane >= C_OUT) return;
    double acc = (double)bias[lane];
    const uint64_t* bw = bits + (size_t)r * 8;
    for (int j = 0; j < 8; ++j) {
        uint64_t w = bw[j];
        const float* Wk = W + (size_t)j * 64 * C_OUT + lane;
        while (w) {
            int k = __builtin_ctzll(w);
            w &= w - 1;
            acc += (double)Wk[(size_t)k * C_OUT];
        }
    }
    Y[(size_t)r * C_OUT + lane] = (float)acc;
}

// GEMM (float A, double out) — fc0 only.
// f32 LDS staging (exact: convert to f64 at the FMA), float4 LDS reads,
// XOR swizzle kills the 4-way Bs-read bank conflicts. (Proven in R2: 247µs.)
__global__ __launch_bounds__(256)
void gemm_f32d(const float* __restrict__ A, int lda,
               const float* __restrict__ B, int ldb,
               const float* __restrict__ bias,
               double* __restrict__ C, int ldc, int M, int Nc, int K) {
    __shared__ float As[16][64];
    __shared__ float Bs[16][64];
    const int tid = threadIdx.x;
    const int tx  = tid & 15, ty = tid >> 4;
    const int row0 = blockIdx.y * 64 + ty * 4;
    const int col0 = blockIdx.x * 64 + tx * 4;
    const int ar = tid >> 2, ak = (tid & 3) * 4;   // A: row ar, k ak..ak+3
    const int bk = tid >> 4, bn = (tid & 15) * 4;  // B: k-row bk, cols bn..bn+3
    const int gm = blockIdx.y * 64 + ar;
    double acc[4][4];
#pragma unroll
    for (int i = 0; i < 4; i++)
#pragma unroll
        for (int j = 0; j < 4; j++) acc[i][j] = 0.0;
    for (int k0 = 0; k0 < K; k0 += 16) {
        float4 av = *reinterpret_cast<const float4*>(&A[(size_t)gm * lda + k0 + ak]);
        const float* avp = reinterpret_cast<const float*>(&av);
#pragma unroll
        for (int j = 0; j < 4; j++)
            As[ak + j][ar ^ ((ak + j) & 12)] = avp[j];
        float4 bv = *reinterpret_cast<const float4*>(
            &B[(size_t)(k0 + bk) * ldb + blockIdx.x * 64 + bn]);
        *reinterpret_cast<float4*>(&Bs[bk][bn ^ ((bk & 3) << 2)]) = bv;
        __syncthreads();
#pragma unroll
        for (int kk = 0; kk < 16; kk++) {
            float4 a4 = *reinterpret_cast<const float4*>(&As[kk][(ty * 4) ^ (kk & 12)]);
            float4 b4 = *reinterpret_cast<const float4*>(&Bs[kk][(tx * 4) ^ ((kk & 3) << 2)]);
            const float* ap = reinterpret_cast<const float*>(&a4);
            const float* bp = reinterpret_cast<const float*>(&b4);
#pragma unroll
            for (int i = 0; i < 4; i++)
#pragma unroll
                for (int j = 0; j < 4; j++)
                    acc[i][j] = fma((double)ap[i], (double)bp[j], acc[i][j]);
        }
        __syncthreads();
    }
#pragma unroll
    for (int i = 0; i < 4; i++) {
        int r = row0 + i;
        if (r >= M) continue;
#pragma unroll
        for (int j = 0; j < 4; j++) {
            int c = col0 + j;
            if (c < Nc) {
                double v = acc[i][j];
                if (bias) v += (double)bias[c];
                C[(size_t)r * ldc + c] = v;
            }
        }
    }
}

// GEMM (float A/B/C, double acc) — GNN branch.
__global__ __launch_bounds__(256)
void gemm_f32(const float* __restrict__ A, int lda,
              const float* __restrict__ B, int ldb,
              const float* __restrict__ bias,
              float* __restrict__ C, int ldc, int M, int Nc, int K) {
    __shared__ float As[16][64];
    __shared__ float Bs[16][64];
    const int tid = threadIdx.x;
    const int tx  = tid & 15, ty = tid >> 4;
    const int row0 = blockIdx.y * 64 + ty * 4;
    const int col0 = blockIdx.x * 64 + tx * 4;
    const int ar = tid >> 2, ak = (tid & 3) * 4;
    const int bk = tid >> 4, bn = (tid & 15) * 4;
    const int gm = blockIdx.y * 64 + ar;
    double acc[4][4];
#pragma unroll
    for (int i = 0; i < 4; i++)
#pragma unroll
        for (int j = 0; j < 4; j++) acc[i][j] = 0.0;
    for (int k0 = 0; k0 < K; k0 += 16) {
#pragma unroll
        for (int j = 0; j < 4; j++) {
            int kk = k0 + ak + j;
            As[ak + j][ar] = (gm < M && kk < K) ? A[(size_t)gm * lda + kk] : 0.f;
        }
#pragma unroll
        for (int j = 0; j < 4; j++) {
            int gn = blockIdx.x * 64 + bn + j;
            int kk = k0 + bk;
            Bs[bk][bn + j] = (gn < Nc && kk < K) ? B[(size_t)kk * ldb + gn] : 0.f;
        }
        __syncthreads();
#pragma unroll
        for (int kk = 0; kk < 16; kk++) {
            float a4[4], b4[4];
#pragma unroll
            for (int i = 0; i < 4; i++) a4[i] = As[kk][ty * 4 + i];
#pragma unroll
            for (int j = 0; j < 4; j++) b4[j] = Bs[kk][tx * 4 + j];
#pragma unroll
            for (int i = 0; i < 4; i++)
#pragma unroll
                for (int j = 0; j < 4; j++) acc[i][j] = fma((double)a4[i], (double)b4[j], acc[i][j]);
        }
        __syncthreads();
    }
#pragma unroll
    for (int i = 0; i < 4; i++) {
        int r = row0 + i;
        if (r >= M) continue;
#pragma unroll
        for (int j = 0; j < 4; j++) {
            int c = col0 + j;
            if (c < Nc) {
                double v = acc[i][j];
                if (bias) v += (double)bias[c];
                C[(size_t)r * ldc + c] = (float)v;
            }
        }
    }
}

// BN stats for fp32 inputs (GNN branch) -> per-gate buffers
__global__ __launch_bounds__(256)
void col_stats_f(const float* __restrict__ X, int M, int Ch, int rowsPerBlock,
                 double* __restrict__ sum, double* __restrict__ sumsq) {
    const int cl = threadIdx.x & 63;
    const int c  = blockIdx.x * 64 + cl;
    const int rg = threadIdx.x >> 6;
    const int r0 = blockIdx.y * rowsPerBlock;
    const int r1 = min(r0 + rowsPerBlock, M);
    double s = 0.0, q = 0.0;
    if (c < Ch) {
        for (int r = r0 + rg; r < r1; r += 4) {
            double v = (double)X[(size_t)r * Ch + c];
            s += v; q += v * v;
        }
    }
    __shared__ double ls[4][64], lq[4][64];
    ls[rg][cl] = s; lq[rg][cl] = q;
    __syncthreads();
    if (rg == 0 && c < Ch) {
        s = ls[0][cl] + ls[1][cl] + ls[2][cl] + ls[3][cl];
        q = lq[0][cl] + lq[1][cl] + lq[2][cl] + lq[3][cl];
        atomicAdd(&sum[c], s);
        atomicAdd(&sumsq[c], q);
    }
}

// ===========================================================================
// LIF helpers (exact ref arithmetic, f64)
// ===========================================================================
__device__ __forceinline__ void lif2(double x0, double x1, bool& s0, bool& s1) {
    double v = x0 * 0.5;
    s0 = (v >= 1.0);
    v = s0 ? 0.0 : v;
    v = v + (x1 - v) * 0.5;
    s1 = (v >= 1.0);
}

__device__ __forceinline__ void bn_params(const double* sum, const double* sumsq,
                                          const float* g, const float* b, double invM,
                                          int c, double& sc, double& sh) {
    double m   = sum[c] * invM;
    double var = sumsq[c] * invM - m * m;
    sc = (double)g[c] / sqrt(var + 1e-5);
    sh = (double)b[c] - m * sc;
}

// BN(inline finalize) + LIF on a 256-ch chunk -> bits at chOff
__global__ __launch_bounds__(256)
void bn_lif_bits2(const double* __restrict__ X,
                  const double* __restrict__ sum, const double* __restrict__ sumsq,
                  const float* __restrict__ g, const float* __restrict__ b, double invM,
                  uint64_t* __restrict__ S, int osWords, int chOffWords) {
    int i = blockIdx.x * 256 + threadIdx.x;   // i < N*256
    int n = i >> 8, c = i & 255;
    double sc, sh;
    bn_params(sum, sumsq, g, b, invM, c, sc, sh);
    bool s0, s1;
    lif2((double)X[i] * sc + sh, (double)X[(size_t)i + (size_t)N_NODES * 256] * sc + sh, s0, s1);
    uint64_t b0 = __ballot(s0), b1 = __ballot(s1);
    if ((threadIdx.x & 63) == 0) {
        int widx = n * osWords + chOffWords + (c >> 6);
        S[widx] = b0;
        S[widx + N_NODES * osWords] = b1;
    }
}

// h += bn(X) (inline finalize) AND emit lif(h_new) bits for this chunk
__global__ __launch_bounds__(256)
void bn_add_lif2(const double* __restrict__ X,
                 const double* __restrict__ sum, const double* __restrict__ sumsq,
                 const float* __restrict__ g, const float* __restrict__ b, double invM,
                 double* __restrict__ H, int chOff, uint64_t* __restrict__ S) {
    int i = blockIdx.x * 256 + threadIdx.x;   // i < N*256
    int n = i >> 8, c = i & 255;
    double sc, sh;
    bn_params(sum, sumsq, g, b, invM, c, sc, sh);
    size_t hi = (size_t)n * 512 + chOff + c;
    double h0 = H[hi] + ((double)X[i] * sc + sh);
    double h1 = H[hi + ND] + ((double)X[(size_t)i + (size_t)N_NODES * 256] * sc + sh);
    H[hi] = h0;
    H[hi + ND] = h1;
    bool s0, s1;
    lif2(h0, h1, s0, s1);
    uint64_t b0 = __ballot(s0), b1 = __ballot(s1);
    if ((threadIdx.x & 63) == 0) {
        int widx = n * 8 + (chOff >> 6) + (c >> 6);
        S[widx] = b0;
        S[widx + N_NODES * 8] = b1;
    }
}

// LayerNorm(512)+ReLU on fc0 output; write both t-slices of h AND emit lif bits
__global__ __launch_bounds__(256)
void ln_relu_lif(const double* __restrict__ X, const float* __restrict__ g,
                 const float* __restrict__ b, double* __restrict__ H,
                 uint64_t* __restrict__ S) {
    int n = blockIdx.x;
    const double* x = X + (size_t)n * 512;
    int c0 = threadIdx.x, c1 = threadIdx.x + 256;
    double v0 = x[c0], v1 = x[c1];
    __shared__ double ls[256], lq[256];
    ls[threadIdx.x] = v0 + v1;
    lq[threadIdx.x] = v0 * v0 + v1 * v1;
    __syncthreads();
    for (int off = 128; off > 0; off >>= 1) {
        if (threadIdx.x < off) {
            ls[threadIdx.x] += ls[threadIdx.x + off];
            lq[threadIdx.x] += lq[threadIdx.x + off];
        }
        __syncthreads();
    }
    double m    = ls[0] * (1.0 / 512);
    double var  = lq[0] * (1.0 / 512) - m * m;
    double rstd = 1.0 / sqrt(var + 1e-5);
    double o0 = (v0 - m) * rstd * (double)g[c0] + (double)b[c0];
    double o1 = (v1 - m) * rstd * (double)g[c1] + (double)b[c1];
    o0 = o0 > 0.0 ? o0 : 0.0;
    o1 = o1 > 0.0 ? o1 : 0.0;
    double* h0 = H + (size_t)n * 512;
    h0[c0] = o0; h0[c1] = o1;
    h0[ND + c0] = o0; h0[ND + c1] = o1;
    // lif with x0 == x1 == o
    bool a0, a1, d0, d1;
    lif2(o0, o0, a0, a1);
    lif2(o1, o1, d0, d1);
    uint64_t ba0 = __ballot(a0), ba1 = __ballot(a1);
    uint64_t bd0 = __ballot(d0), bd1 = __ballot(d1);
    if ((threadIdx.x & 63) == 0) {
        int w = threadIdx.x >> 6;
        S[n * 8 + w] = ba0;
        S[n * 8 + w + N_NODES * 8] = ba1;
        S[n * 8 + 4 + w] = bd0;
        S[n * 8 + 4 + w + N_NODES * 8] = bd1;
    }
}

// ===========================================================================
// Attention on bit spikes (integer-exact in fp32).
// ===========================================================================
__global__ __launch_bounds__(256)
void kv_bits(const uint64_t* __restrict__ Kb, const uint64_t* __restrict__ Vb,
             float* __restrict__ KV, int nPerBlock) {
    const int th = blockIdx.x;
    const int t = th >> 3, h = th & 7;
    const int nbase = blockIdx.y * nPerBlock;
    const int e = threadIdx.x & 63, dg = threadIdx.x >> 6;
    float acc[16];
#pragma unroll
    for (int i = 0; i < 16; i++) acc[i] = 0.f;
    __shared__ float ks[16][64], vs[16][64];
    const size_t wbase = (size_t)t * N_NODES * 8 + h;
    for (int n0 = 0; n0 < nPerBlock; n0 += 16) {
        for (int idx = threadIdx.x; idx < 16 * 128; idx += 256) {
            int r = idx >> 7, c = idx & 127;
            size_t wi = wbase + (size_t)(nbase + n0 + r) * 8;
            if (c < 64) ks[r][c] = (float)((Kb[wi] >> c) & 1ull);
            else        vs[r][c - 64] = (float)((Vb[wi] >> (c - 64)) & 1ull);
        }
        __syncthreads();
#pragma unroll
        for (int r = 0; r < 16; ++r) {
            float ve = vs[r][e];
#pragma unroll
            for (int i = 0; i < 16; ++i) acc[i] += ks[r][dg * 16 + i] * ve;
        }
        __syncthreads();
    }
    float* kvp = KV + (size_t)th * 4096;
    for (int i = 0; i < 16; ++i)
        atomicAdd(&kvp[(dg * 16 + i) * 64 + e], acc[i]);
}

// O = (Q @ KV) * 0.125 for BOTH timesteps, LIF in-register, emit bits.
// Replaces o_bits + lif_bits_f: removes the 134MB/layer O32 round-trip.
// In-place on S(=q_bits) is safe: each block reads exactly the (row,h)
// words it later writes; reads complete before any write.
__global__ __launch_bounds__(256)
void o_lif_bits(const uint64_t* __restrict__ Qb, const float* __restrict__ KV,
                uint64_t* __restrict__ S) {
    const int h  = blockIdx.y;     // 8 heads
    const int nb = blockIdx.x;     // N/64 row blocks
    __shared__ float kvs[64][64];
    __shared__ float qs[64][65];
    const int e = threadIdx.x & 63, rg = threadIdx.x >> 6;
    float acc0[16], acc1[16];
#pragma unroll
    for (int i = 0; i < 16; ++i) { acc0[i] = 0.f; acc1[i] = 0.f; }
#pragma unroll
    for (int t = 0; t < 2; ++t) {
        const float* kvp = KV + (size_t)(t * 8 + h) * 4096;
        for (int idx = threadIdx.x; idx < 4096; idx += 256)
            kvs[idx >> 6][idx & 63] = kvp[idx];
        const size_t wbase = ((size_t)t * N_NODES + (size_t)nb * 64) * 8 + h;
        for (int idx = threadIdx.x; idx < 4096; idx += 256) {
            int r = idx >> 6, c = idx & 63;
            qs[r][c] = (float)((Qb[wbase + (size_t)r * 8] >> c) & 1ull);
        }
        __syncthreads();
        float* acc = t == 0 ? acc0 : acc1;
        for (int d = 0; d < 64; ++d) {
            float kv = kvs[d][e];
#pragma unroll
            for (int i = 0; i < 16; ++i) acc[i] += qs[rg * 16 + i][d] * kv;
        }
        __syncthreads();   // LDS reloaded next t
    }
#pragma unroll
    for (int i = 0; i < 16; ++i) {
        float o0 = acc0[i] * 0.125f;
        float o1 = acc1[i] * 0.125f;
        bool s0, s1;
        lif2((double)o0, (double)o1, s0, s1);
        uint64_t b0 = __ballot(s0), b1 = __ballot(s1);
        if (e == 0) {
            size_t row = (size_t)nb * 64 + rg * 16 + i;
            S[row * 8 + h] = b0;
            S[row * 8 + h + (size_t)N_NODES * 8] = b1;
        }
    }
}

// ===========================================================================
// GNN branch (fp32)
// ===========================================================================
__global__ __launch_bounds__(256)
void deg_kernel(const int* __restrict__ col, float* __restrict__ deg, int E) {
    int e = blockIdx.x * 256 + threadIdx.x;
    if (e < E) atomicAdd(&deg[col[e]], 1.0f);
}

__global__ __launch_bounds__(256)
void dinv_kernel(float* __restrict__ deg, int n) {
    int i = blockIdx.x * 256 + threadIdx.x;
    if (i < n) {
        double d = (double)deg[i];
        deg[i] = d > 0.0 ? (float)(1.0 / sqrt(d)) : 0.f;
    }
}

__global__ __launch_bounds__(256)
void agg_kernel(const float* __restrict__ G, const int* __restrict__ row,
                const int* __restrict__ col, const float* __restrict__ dinv,
                float* __restrict__ out, int E) {
    int idx = blockIdx.x * 256 + threadIdx.x;
    int e = idx >> 6, c = idx & 63;
    if (e >= E || c >= C_OUT) return;
    int r = row[e], cl = col[e];
    float val = dinv[cl] * dinv[r];
    atomicAdd(&out[(size_t)cl * C_OUT + c], val * G[(size_t)r * C_OUT + c]);
}

__global__ __launch_bounds__(256)
void bn_relu_add_f2(const float* __restrict__ X,
                    const double* __restrict__ sum, const double* __restrict__ sumsq,
                    const float* __restrict__ g, const float* __restrict__ b, double invM,
                    const float* __restrict__ add, float* __restrict__ out, int NC, int Ch) {
    int i = blockIdx.x * 256 + threadIdx.x;
    if (i >= NC) return;
    int c = i % Ch;
    double sc, sh;
    bn_params(sum, sumsq, g, b, invM, c, sc, sh);
    double v = (double)X[i] * sc + sh;
    v = v > 0.0 ? v : 0.0;
    if (add) v += (double)add[i];
    out[i] = (float)v;
}

__global__ __launch_bounds__(256)
void mix_kernel(const float* __restrict__ G, const float* __restrict__ Y,
                float* __restrict__ P, int NC) {
    int i = blockIdx.x * 256 + threadIdx.x;
    if (i >= NC) return;
    double y = 0.5 * ((double)Y[i] + (double)Y[(size_t)i + NC]);
    P[i] = (float)(0.8 * (double)G[i] + 0.2 * y);
}

__global__ __launch_bounds__(256)
void final_fc_kernel(const float* __restrict__ A, const float* __restrict__ W,
                     const float* __restrict__ bias, float* __restrict__ out) {
    __shared__ float Ws[40][40];
    for (int idx = threadIdx.x; idx < 1600; idx += 256)
        Ws[idx / 40][idx % 40] = W[idx];
    __syncthreads();
    int i = blockIdx.x * 256 + threadIdx.x;
    if (i >= N_NODES * C_OUT) return;
    int n = i / 40, c = i - n * 40;
    const float* a = A + (size_t)n * 40;
    double acc = (double)bias[c];
#pragma unroll 8
    for (int k = 0; k < 40; ++k) acc += (double)a[k] * (double)Ws[k][c];
    out[i] = (float)acc;
}

// ===========================================================================
// Host orchestration
// ===========================================================================
static inline dim3 grid1(long n) { return dim3((unsigned)((n + 255) / 256)); }

extern "C" void kernel_launch(void* const* d_in, const int* in_sizes, int n_in,
                              void* d_out, int out_size, void* d_ws, size_t ws_size,
                              hipStream_t stream) {
    const float* x      = (const float*)d_in[0];
    const float* fc0_w  = (const float*)d_in[1];
    const float* fc0_b  = (const float*)d_in[2];
    const float* ln_g   = (const float*)d_in[3];
    const float* ln_b   = (const float*)d_in[4];
    const float* wq     = (const float*)d_in[5];
    const float* wk     = (const float*)d_in[6];
    const float* wv     = (const float*)d_in[7];
    const float* wo     = (const float*)d_in[8];
    const float* bnq_g  = (const float*)d_in[9];
    const float* bnq_b  = (const float*)d_in[10];
    const float* bnk_g  = (const float*)d_in[11];
    const float* bnk_b  = (const float*)d_in[12];
    const float* bnv_g  = (const float*)d_in[13];
    const float* bnv_b  = (const float*)d_in[14];
    const float* bno_g  = (const float*)d_in[15];
    const float* bno_b  = (const float*)d_in[16];
    const float* w1     = (const float*)d_in[17];
    const float* bn1_g  = (const float*)d_in[18];
    const float* bn1_b  = (const float*)d_in[19];
    const float* w2     = (const float*)d_in[20];
    const float* bn2_g  = (const float*)d_in[21];
    const float* bn2_b  = (const float*)d_in[22];
    const float* head_w = (const float*)d_in[23];
    const float* head_b = (const float*)d_in[24];
    const float* gfc_w  = (const float*)d_in[25];
    const float* gfc_b  = (const float*)d_in[26];
    const float* gbn0_g = (const float*)d_in[27];
    const float* gbn0_b = (const float*)d_in[28];
    const float* gconv_w= (const float*)d_in[29];
    const float* gconv_b= (const float*)d_in[30];
    const float* gbn_g  = (const float*)d_in[31];
    const float* gbn_b  = (const float*)d_in[32];
    const float* fc_w   = (const float*)d_in[33];
    const float* fc_b   = (const float*)d_in[34];
    const int*   edge   = (const int*)d_in[35];

    const int E = in_sizes[35] / 2;
    const int* erow = edge;
    const int* ecol = edge + E;
    const int NC = N_NODES * C_OUT;

    // ---- workspace layout (~234 MiB) ----
    uint8_t* wsbase = (uint8_t*)d_ws;
    size_t off = 0;
    auto alloc = [&](size_t bytes, size_t align) -> void* {
        off = (off + align - 1) & ~(align - 1);
        void* p = wsbase + off;
        off += bytes;
        return p;
    };
    double*   statBuf = (double*)alloc((size_t)64 * 512 * sizeof(double), 256);  // per-gate stats
    double*   h_buf  = (double*)alloc((size_t)2 * ND * sizeof(double), 256);     // 134 MB
    double*   Pd     = (double*)alloc((size_t)M2 * CW * sizeof(double), 256);    // 67 MB
    uint8_t*  Wdig   = (uint8_t*)alloc((size_t)WD_TOTAL, 256);                   // 10.5 MB
    uint64_t* s_bits = (uint64_t*)alloc((size_t)2 * N_NODES * 8 * 8, 256);
    uint64_t* q_bits = (uint64_t*)alloc((size_t)2 * N_NODES * 8 * 8, 256);
    uint64_t* k_bits = (uint64_t*)alloc((size_t)2 * N_NODES * 8 * 8, 256);
    uint64_t* v_bits = (uint64_t*)alloc((size_t)2 * N_NODES * 8 * 8, 256);
    uint64_t* m_bits = (uint64_t*)alloc((size_t)2 * N_NODES * 16 * 8, 256);      // 4.2 MB
    float*    ybuf   = (float*)m_bits;  // alias: y written at head, after m_bits dead
    // (ybuf needs 5.24 MB; m_bits is 4.2 MB — extend with a pad alloc)
    (void)alloc((size_t)2 * NC * sizeof(float) > (size_t)2 * N_NODES * 16 * 8
                ? (size_t)2 * NC * sizeof(float) - (size_t)2 * N_NODES * 16 * 8 : 0, 256);
    float*    g0     = (float*)alloc((size_t)NC * sizeof(float), 256);
    float*    gg     = (float*)alloc((size_t)NC * sizeof(float), 256);
    float*    ag     = (float*)alloc((size_t)NC * sizeof(float), 256);
    float*    kvb    = (float*)alloc((size_t)65536 * sizeof(float), 256);
    float*    deg    = (float*)alloc((size_t)N_NODES * sizeof(float), 256);
    if (off > ws_size) return;

    const dim3 blk(256);
    const dim3 gCHK((unsigned)(N_NODES));
    const dim3 gGEMM(CW / 64, M2 / 128);
    const double invM2 = 1.0 / (double)M2;
    const double invMN = 1.0 / (double)N_NODES;

    hipMemsetAsync(statBuf, 0, (size_t)64 * 512 * sizeof(double), stream);

    int gate = 0;
    auto nextStat = [&]() { return statBuf + (size_t)(gate++) * 512; };

    // ===== transformer branch =====
    hipLaunchKernelGGL(gemm_f32d, dim3(8, N_NODES / 64), blk, 0, stream,
                       x, 512, fc0_w, 512, fc0_b, Pd, 512, N_NODES, 512, 512);
    hipLaunchKernelGGL(ln_relu_lif, dim3(N_NODES), blk, 0, stream, Pd, ln_g, ln_b, h_buf, s_bits);

    for (int l = 0; l < 4; ++l) {
        // one prep launch for all 6 matrices of this layer
        hipLaunchKernelGGL(w_digits_layer, dim3(512), blk, 0, stream,
                           wq + (size_t)l * 262144, wk + (size_t)l * 262144,
                           wv + (size_t)l * 262144, wo + (size_t)l * 262144,
                           w1 + (size_t)l * 524288, w2 + (size_t)l * 524288, Wdig);

        uint64_t* qkvb[3] = {q_bits, k_bits, v_bits};
        const size_t wdoff[3] = {WD_Q, WD_K, WD_V};
        const float* gmat[3] = {bnq_g + l * 512, bnk_g + l * 512, bnv_g + l * 512};
        const float* bmat[3] = {bnq_b + l * 512, bnk_b + l * 512, bnv_b + l * 512};
        for (int j = 0; j < 3; ++j) {
            for (int c0 = 0; c0 < 512; c0 += CW) {
                double* st = nextStat();
                hipLaunchKernelGGL(gemm_i8_bits, gGEMM, blk, 0, stream,
                                   s_bits, 8, Wdig + wdoff[j], 512, c0, Pd, CW, 512, st, st + 256);
                hipLaunchKernelGGL(bn_lif_bits2, gCHK, blk, 0, stream,
                                   Pd, st, st + 256, gmat[j] + c0, bmat[j] + c0, invM2,
                                   qkvb[j], 8, c0 / 64);
            }
        }

        // attention (exact); fused O-proj input: lif(o) bits -> q_bits in place
        hipMemsetAsync(kvb, 0, 65536 * sizeof(float), stream);
        hipLaunchKernelGGL(kv_bits, dim3(16, 16), blk, 0, stream, k_bits, v_bits, kvb, 1024);
        hipLaunchKernelGGL(o_lif_bits, dim3(N_NODES / 64, 8), blk, 0, stream, q_bits, kvb, q_bits);

        // h += bn(lif(o) @ wo); emit s = lif(h_new) into s_bits
        for (int c0 = 0; c0 < 512; c0 += CW) {
            double* st = nextStat();
            hipLaunchKernelGGL(gemm_i8_bits, gGEMM, blk, 0, stream,
                               q_bits, 8, Wdig + WD_O, 512, c0, Pd, CW, 512, st, st + 256);
            hipLaunchKernelGGL(bn_add_lif2, gCHK, blk, 0, stream,
                               Pd, st, st + 256, bno_g + l * 512 + c0, bno_b + l * 512 + c0,
                               invM2, h_buf, c0, s_bits);
        }

        // MLP: m = lif(bn1(s @ w1)) in 4 chunks of 256
        for (int c0 = 0; c0 < 1024; c0 += CW) {
            double* st = nextStat();
            hipLaunchKernelGGL(gemm_i8_bits, gGEMM, blk, 0, stream,
                               s_bits, 8, Wdig + WD_1, 1024, c0, Pd, CW, 512, st, st + 256);
            hipLaunchKernelGGL(bn_lif_bits2, gCHK, blk, 0, stream,
                               Pd, st, st + 256, bn1_g + l * 1024 + c0, bn1_b + l * 1024 + c0,
                               invM2, m_bits, 16, c0 / 64);
        }
        // h += bn2(m @ w2); emit s = lif(h_new) for next layer / head
        for (int c0 = 0; c0 < 512; c0 += CW) {
            double* st = nextStat();
            hipLaunchKernelGGL(gemm_i8_bits, gGEMM, blk, 0, stream,
                               m_bits, 16, Wdig + WD_2, 512, c0, Pd, CW, 1024, st, st + 256);
            hipLaunchKernelGGL(bn_add_lif2, gCHK, blk, 0, stream,
                               Pd, st, st + 256, bn2_g + l * 512 + c0, bn2_b + l * 512 + c0,
                               invM2, h_buf, c0, s_bits);
        }
    }

    // head: y = s @ head_w + head_b (s_bits already = lif(h_final))
    hipLaunchKernelGGL(head_gather, dim3(M2 / 4), blk, 0, stream, s_bits, head_w, head_b, ybuf);

    // ===== GNN branch (fp32) =====
    hipLaunchKernelGGL(gemm_f32, dim3(1, N_NODES / 64), blk, 0, stream,
                       x, 512, gfc_w, 40, gfc_b, ag, 40, N_NODES, 40, 512);
    {
        double* st = nextStat();
        dim3 gs(1, (N_NODES + 511) / 512);
        hipLaunchKernelGGL(col_stats_f, gs, blk, 0, stream, ag, N_NODES, 40, 512, st, st + 256);
        hipLaunchKernelGGL(bn_relu_add_f2, grid1(NC), blk, 0, stream,
                           ag, st, st + 256, gbn0_g, gbn0_b, invMN,
                           (const float*)nullptr, g0, NC, 40);
    }

    hipMemsetAsync(deg, 0, N_NODES * sizeof(float), stream);
    hipLaunchKernelGGL(deg_kernel, grid1(E), blk, 0, stream, ecol, deg, E);
    hipLaunchKernelGGL(dinv_kernel, grid1(N_NODES), blk, 0, stream, deg, N_NODES);

    const float* gsrc = g0;
    for (int i = 0; i < 2; ++i) {
        hipMemsetAsync(ag, 0, (size_t)NC * sizeof(float), stream);
        hipLaunchKernelGGL(agg_kernel, grid1((long)E * 64), blk, 0, stream,
                           gsrc, erow, ecol, deg, ag, E);
        hipLaunchKernelGGL(gemm_f32, dim3(1, N_NODES / 64), blk, 0, stream,
                           ag, 40, gconv_w + (size_t)i * 40 * 40, 40, gconv_b + i * 40,
                           gg, 40, N_NODES, 40, 40);
        double* st = nextStat();
        dim3 gs(1, (N_NODES + 511) / 512);
        hipLaunchKernelGGL(col_stats_f, gs, blk, 0, stream, gg, N_NODES, 40, 512, st, st + 256);
        hipLaunchKernelGGL(bn_relu_add_f2, grid1(NC), blk, 0, stream,
                           gg, st, st + 256, gbn_g + i * 40, gbn_b + i * 40, invMN, g0, gg, NC, 40);
        gsrc = gg;
    }

    // out = (0.8*g + 0.2*mean_t(y)) @ fc_w + fc_b
    hipLaunchKernelGGL(mix_kernel, grid1(NC), blk, 0, stream, gg, ybuf, ag, NC);
    hipLaunchKernelGGL(final_fc_kernel, grid1((long)N_NODES * C_OUT), blk, 0, stream,
                       ag, fc_w, fc_b, (float*)d_out);
}

// Round 4
// 6282.817 us; speedup vs baseline: 2.0765x; 1.0513x over previous
//
#include <hip/hip_runtime.h>
#include <cstddef>
#include <cstdint>

constexpr int N_NODES = 16384;
constexpr int D_MODEL = 512;
constexpr int C_OUT   = 40;
constexpr int CW      = 256;                 // channel chunk width
constexpr int ND      = N_NODES * D_MODEL;   // per-timestep elements (512-ch)
constexpr int M2      = 2 * N_NODES;         // T*N rows

typedef int i32x4 __attribute__((ext_vector_type(4)));

// digit scales: w ≈ Σ d_j * S_j, residual ≤ 2^-38 (5 digits)
#define S0 0.001953125                      // 2^-9
#define S1 1.52587890625e-05                // 2^-16
#define S2 1.1920928955078125e-07           // 2^-23
#define S3 9.31322574615478515625e-10       // 2^-30
#define S4 7.2759576141834259033203125e-12  // 2^-37

// digit-plane offsets within the per-layer buffer (bytes)
#define WD_Q 0
#define WD_K 1310720
#define WD_V 2621440
#define WD_O 3932160
#define WD_1 5242880
#define WD_2 7864320
#define WD_TOTAL 10485760

// ===========================================================================
// Per-layer weight -> 5 signed-i8 digit planes in MFMA B-fragment order:
// byte at ((k/16)*N + n)*80 + j*16 + (k%16).
// ===========================================================================
__global__ __launch_bounds__(256)
void w_digits_layer(const float* __restrict__ wq, const float* __restrict__ wk,
                    const float* __restrict__ wv, const float* __restrict__ wo,
                    const float* __restrict__ w1, const float* __restrict__ w2,
                    uint8_t* __restrict__ Wd) {
    int idx = blockIdx.x * 256 + threadIdx.x;   // [0, 131072)
    const float* W;
    uint8_t* outb;
    int N, rem;
    if (idx < 65536) {                          // wq,wk,wv,wo: 4 x (32 kg x 512 n)
        int mm = idx >> 14;
        rem = idx & 16383;
        const float* ptrs[4] = {wq, wk, wv, wo};
        W = ptrs[mm]; outb = Wd + (size_t)mm * 1310720; N = 512;
    } else if (idx < 98304) {                   // w1: 32 kg x 1024 n
        rem = idx - 65536; W = w1; outb = Wd + WD_1; N = 1024;
    } else {                                    // w2: 64 kg x 512 n
        rem = idx - 98304; W = w2; outb = Wd + WD_2; N = 512;
    }
    int kg = rem / N, n = rem - kg * N;
    const float* Wp = W + (size_t)kg * 16 * N + n;
    uint8_t* out = outb + (size_t)(kg * N + n) * 80;
    const double scl[5] = {512.0, 65536.0, 8388608.0, 1073741824.0, 137438953472.0};
    const double inv[5] = {S0, S1, S2, S3, S4};
    union { uint8_t b[5][16]; i32x4 v[5]; } db;
#pragma unroll
    for (int kk = 0; kk < 16; ++kk) {
        double r = (double)Wp[(size_t)kk * N];
#pragma unroll
        for (int j = 0; j < 5; ++j) {
            int d = (int)rint(r * scl[j]);
            d = d > 127 ? 127 : (d < -127 ? -127 : d);
            r -= (double)d * inv[j];
            db.b[j][kk] = (uint8_t)(int8_t)d;
        }
    }
#pragma unroll
    for (int j = 0; j < 5; ++j)
        *reinterpret_cast<i32x4*>(out + j * 16) = db.v[j];
}

// ===========================================================================
// Spike GEMM via i8 MFMA, exact fixed-point. 128-row blocks, LDS-staged B.
// BN stats accumulated in f64 from the EXACT p; activation stored as f32
// (halves the Pd round-trip; ~1e-6 perturbation, far under harness margin).
// ===========================================================================
__global__ __launch_bounds__(256)
void gemm_i8_bits(const uint64_t* __restrict__ bits, int kWords,
                  const uint8_t* __restrict__ Wd, int Nmat, int colOff,
                  float* __restrict__ C, int ldc, int K,
                  double* __restrict__ sum, double* __restrict__ sumsq) {
    __shared__ __attribute__((aligned(16))) uint8_t Bs[20480];
    const int lane = threadIdx.x & 63;
    const int wv   = threadIdx.x >> 6;
    const int m    = lane & 15;
    const int q    = lane >> 4;
    const int rowT = blockIdx.y * 128 + wv * 32;   // this wave's 32-row tile
    const int colB = blockIdx.x * 64;

    i32x4 acc[2][4][5];
#pragma unroll
    for (int rt = 0; rt < 2; ++rt)
#pragma unroll
        for (int t = 0; t < 4; ++t)
#pragma unroll
            for (int j = 0; j < 5; ++j) acc[rt][t][j] = (i32x4){0, 0, 0, 0};

    const uint64_t* brow0 = bits + (size_t)(rowT + m) * kWords;
    const uint64_t* brow1 = brow0 + (size_t)16 * kWords;
    const size_t cb = (size_t)(colOff + colB);

    for (int kb = 0; kb < K; kb += 64) {
        // --- load the 4-ktile x 64-col x 80B digit tile (20KB) to registers ---
        i32x4 tmp[5];
        const size_t kt0 = (size_t)(kb >> 4);
#pragma unroll
        for (int c5 = 0; c5 < 5; ++c5) {
            int c  = threadIdx.x + c5 * 256;       // [0,1280) 16B chunks
            int kt = c / 320;                      // ktile (5120B each, contiguous)
            int of = c - kt * 320;
            tmp[c5] = *reinterpret_cast<const i32x4*>(
                Wd + ((kt0 + (size_t)kt) * Nmat + cb) * 80 + (size_t)of * 16);
        }
        // --- A spike fragments for both row-tiles ---
        uint64_t wb0 = brow0[kb >> 6];
        uint64_t wb1 = brow1[kb >> 6];
        uint32_t hw0 = (uint32_t)(wb0 >> (q * 16)) & 0xFFFFu;
        uint32_t hw1 = (uint32_t)(wb1 >> (q * 16)) & 0xFFFFu;
        i32x4 af0, af1;
#pragma unroll
        for (int i = 0; i < 4; ++i) {
            af0[i] = (int)((((hw0 >> (4 * i)) & 0xFu) * 0x00204081u) & 0x01010101u);
            af1[i] = (int)((((hw1 >> (4 * i)) & 0xFu) * 0x00204081u) & 0x01010101u);
        }
        __syncthreads();                 // previous tile fully consumed
#pragma unroll
        for (int c5 = 0; c5 < 5; ++c5) {
            int c  = threadIdx.x + c5 * 256;
            int kt = c / 320;
            int of = c - kt * 320;
            *reinterpret_cast<i32x4*>(Bs + kt * 5120 + of * 16) = tmp[c5];
        }
        __syncthreads();                 // tile staged
#pragma unroll
        for (int t = 0; t < 4; ++t) {
            const uint8_t* bt = Bs + q * 5120 + (t * 16 + m) * 80;
            i32x4 bf[5];
#pragma unroll
            for (int j = 0; j < 5; ++j)
                bf[j] = *reinterpret_cast<const i32x4*>(bt + j * 16);
#pragma unroll
            for (int j = 0; j < 5; ++j) {
                acc[0][t][j] = __builtin_amdgcn_mfma_i32_16x16x64_i8(af0, bf[j], acc[0][t][j], 0, 0, 0);
                acc[1][t][j] = __builtin_amdgcn_mfma_i32_16x16x64_i8(af1, bf[j], acc[1][t][j], 0, 0, 0);
            }
        }
    }

    double sarr[4], qarr[4];
#pragma unroll
    for (int t = 0; t < 4; ++t) { sarr[t] = 0.0; qarr[t] = 0.0; }
#pragma unroll
    for (int rt = 0; rt < 2; ++rt) {
        const int orow = rowT + rt * 16 + q * 4;
#pragma unroll
        for (int t = 0; t < 4; ++t) {
            float* Cc = C + (size_t)orow * ldc + colB + t * 16 + m;
#pragma unroll
            for (int i = 0; i < 4; ++i) {
                double p = (double)acc[rt][t][0][i] * S0 + (double)acc[rt][t][1][i] * S1
                         + (double)acc[rt][t][2][i] * S2 + (double)acc[rt][t][3][i] * S3
                         + (double)acc[rt][t][4][i] * S4;
                Cc[(size_t)i * ldc] = (float)p;
                sarr[t] += p; qarr[t] += p * p;
            }
        }
    }
    __shared__ double ls[4][64], lq[4][64];
#pragma unroll
    for (int t = 0; t < 4; ++t) {
        double s = sarr[t], qq = qarr[t];
        s  += __shfl_xor(s, 16);  s  += __shfl_xor(s, 32);
        qq += __shfl_xor(qq, 16); qq += __shfl_xor(qq, 32);
        if (lane < 16) { ls[wv][t * 16 + lane] = s; lq[wv][t * 16 + lane] = qq; }
    }
    __syncthreads();
    if (threadIdx.x < 64) {
        int t = threadIdx.x;
        double s  = ls[0][t] + ls[1][t] + ls[2][t] + ls[3][t];
        double qq = lq[0][t] + lq[1][t] + lq[2][t] + lq[3][t];
        atomicAdd(&sum[colB + t], s);
        atomicAdd(&sumsq[colB + t], qq);
    }
}

// head GEMM: exact f64 gather (immune to any MFMA layout quirk)
__global__ __launch_bounds__(256)
void head_gather(const uint64_t* __restrict__ bits, const float* __restrict__ W,
                 const float* __restrict__ bias, float* __restrict__ Y) {
    const int lane = threadIdx.x & 63;
    const int wid  = threadIdx.x >> 6;
    const int r = blockIdx.x * 4 + wid;
    if (lane >= C_OUT) return;
    double acc = (double)bias[lane];
    const uint64_t* bw = bits + (size_t)r * 8;
    for (int j = 0; j < 8; ++j) {
        uint64_t w = bw[j];
        const float* Wk = W + (size_t)j * 64 * C_OUT + lane;
        while (w) {
            int k = __builtin_ctzll(w);
            w &= w - 1;
            acc += (double)Wk[(size_t)k * C_OUT];
        }
    }
    Y[(size_t)r * C_OUT + lane] = (float)acc;
}

// GEMM (float A, double out) — fc0 only.  (R2-proven: 245µs, low conflicts)
__global__ __launch_bounds__(256)
void gemm_f32d(const float* __restrict__ A, int lda,
               const float* __restrict__ B, int ldb,
               const float* __restrict__ bias,
               double* __restrict__ C, int ldc, int M, int Nc, int K) {
    __shared__ float As[16][64];
    __shared__ float Bs[16][64];
    const int tid = threadIdx.x;
    const int tx  = tid & 15, ty = tid >> 4;
    const int row0 = blockIdx.y * 64 + ty * 4;
    const int col0 = blockIdx.x * 64 + tx * 4;
    const int ar = tid >> 2, ak = (tid & 3) * 4;   // A: row ar, k ak..ak+3
    const int bk = tid >> 4, bn = (tid & 15) * 4;  // B: k-row bk, cols bn..bn+3
    const int gm = blockIdx.y * 64 + ar;
    double acc[4][4];
#pragma unroll
    for (int i = 0; i < 4; i++)
#pragma unroll
        for (int j = 0; j < 4; j++) acc[i][j] = 0.0;
    for (int k0 = 0; k0 < K; k0 += 16) {
        float4 av = *reinterpret_cast<const float4*>(&A[(size_t)gm * lda + k0 + ak]);
        const float* avp = reinterpret_cast<const float*>(&av);
#pragma unroll
        for (int j = 0; j < 4; j++)
            As[ak + j][ar ^ ((ak + j) & 12)] = avp[j];
        float4 bv = *reinterpret_cast<const float4*>(
            &B[(size_t)(k0 + bk) * ldb + blockIdx.x * 64 + bn]);
        *reinterpret_cast<float4*>(&Bs[bk][bn ^ ((bk & 3) << 2)]) = bv;
        __syncthreads();
#pragma unroll
        for (int kk = 0; kk < 16; kk++) {
            float4 a4 = *reinterpret_cast<const float4*>(&As[kk][(ty * 4) ^ (kk & 12)]);
            float4 b4 = *reinterpret_cast<const float4*>(&Bs[kk][(tx * 4) ^ ((kk & 3) << 2)]);
            const float* ap = reinterpret_cast<const float*>(&a4);
            const float* bp = reinterpret_cast<const float*>(&b4);
#pragma unroll
            for (int i = 0; i < 4; i++)
#pragma unroll
                for (int j = 0; j < 4; j++)
                    acc[i][j] = fma((double)ap[i], (double)bp[j], acc[i][j]);
        }
        __syncthreads();
    }
#pragma unroll
    for (int i = 0; i < 4; i++) {
        int r = row0 + i;
        if (r >= M) continue;
#pragma unroll
        for (int j = 0; j < 4; j++) {
            int c = col0 + j;
            if (c < Nc) {
                double v = acc[i][j];
                if (bias) v += (double)bias[c];
                C[(size_t)r * ldc + c] = v;
            }
        }
    }
}

// GEMM (float A/B/C, double acc) — GNN branch.
__global__ __launch_bounds__(256)
void gemm_f32(const float* __restrict__ A, int lda,
              const float* __restrict__ B, int ldb,
              const float* __restrict__ bias,
              float* __restrict__ C, int ldc, int M, int Nc, int K) {
    __shared__ float As[16][64];
    __shared__ float Bs[16][64];
    const int tid = threadIdx.x;
    const int tx  = tid & 15, ty = tid >> 4;
    const int row0 = blockIdx.y * 64 + ty * 4;
    const int col0 = blockIdx.x * 64 + tx * 4;
    const int ar = tid >> 2, ak = (tid & 3) * 4;
    const int bk = tid >> 4, bn = (tid & 15) * 4;
    const int gm = blockIdx.y * 64 + ar;
    double acc[4][4];
#pragma unroll
    for (int i = 0; i < 4; i++)
#pragma unroll
        for (int j = 0; j < 4; j++) acc[i][j] = 0.0;
    for (int k0 = 0; k0 < K; k0 += 16) {
#pragma unroll
        for (int j = 0; j < 4; j++) {
            int kk = k0 + ak + j;
            As[ak + j][ar] = (gm < M && kk < K) ? A[(size_t)gm * lda + kk] : 0.f;
        }
#pragma unroll
        for (int j = 0; j < 4; j++) {
            int gn = blockIdx.x * 64 + bn + j;
            int kk = k0 + bk;
            Bs[bk][bn + j] = (gn < Nc && kk < K) ? B[(size_t)kk * ldb + gn] : 0.f;
        }
        __syncthreads();
#pragma unroll
        for (int kk = 0; kk < 16; kk++) {
            float a4[4], b4[4];
#pragma unroll
            for (int i = 0; i < 4; i++) a4[i] = As[kk][ty * 4 + i];
#pragma unroll
            for (int j = 0; j < 4; j++) b4[j] = Bs[kk][tx * 4 + j];
#pragma unroll
            for (int i = 0; i < 4; i++)
#pragma unroll
                for (int j = 0; j < 4; j++) acc[i][j] = fma((double)a4[i], (double)b4[j], acc[i][j]);
        }
        __syncthreads();
    }
#pragma unroll
    for (int i = 0; i < 4; i++) {
        int r = row0 + i;
        if (r >= M) continue;
#pragma unroll
        for (int j = 0; j < 4; j++) {
            int c = col0 + j;
            if (c < Nc) {
                double v = acc[i][j];
                if (bias) v += (double)bias[c];
                C[(size_t)r * ldc + c] = (float)v;
            }
        }
    }
}

// BN stats for fp32 inputs (GNN branch) -> per-gate buffers
__global__ __launch_bounds__(256)
void col_stats_f(const float* __restrict__ X, int M, int Ch, int rowsPerBlock,
                 double* __restrict__ sum, double* __restrict__ sumsq) {
    const int cl = threadIdx.x & 63;
    const int c  = blockIdx.x * 64 + cl;
    const int rg = threadIdx.x >> 6;
    const int r0 = blockIdx.y * rowsPerBlock;
    const int r1 = min(r0 + rowsPerBlock, M);
    double s = 0.0, q = 0.0;
    if (c < Ch) {
        for (int r = r0 + rg; r < r1; r += 4) {
            double v = (double)X[(size_t)r * Ch + c];
            s += v; q += v * v;
        }
    }
    __shared__ double ls[4][64], lq[4][64];
    ls[rg][cl] = s; lq[rg][cl] = q;
    __syncthreads();
    if (rg == 0 && c < Ch) {
        s = ls[0][cl] + ls[1][cl] + ls[2][cl] + ls[3][cl];
        q = lq[0][cl] + lq[1][cl] + lq[2][cl] + lq[3][cl];
        atomicAdd(&sum[c], s);
        atomicAdd(&sumsq[c], q);
    }
}

// ===========================================================================
// LIF helpers (exact ref arithmetic, f64)
// ===========================================================================
__device__ __forceinline__ void lif2(double x0, double x1, bool& s0, bool& s1) {
    double v = x0 * 0.5;
    s0 = (v >= 1.0);
    v = s0 ? 0.0 : v;
    v = v + (x1 - v) * 0.5;
    s1 = (v >= 1.0);
}

__device__ __forceinline__ void bn_params(const double* sum, const double* sumsq,
                                          const float* g, const float* b, double invM,
                                          int c, double& sc, double& sh) {
    double m   = sum[c] * invM;
    double var = sumsq[c] * invM - m * m;
    sc = (double)g[c] / sqrt(var + 1e-5);
    sh = (double)b[c] - m * sc;
}

// BN(inline finalize) + LIF on a 256-ch chunk (f32 activations) -> bits
__global__ __launch_bounds__(256)
void bn_lif_bits2(const float* __restrict__ X,
                  const double* __restrict__ sum, const double* __restrict__ sumsq,
                  const float* __restrict__ g, const float* __restrict__ b, double invM,
                  uint64_t* __restrict__ S, int osWords, int chOffWords) {
    int i = blockIdx.x * 256 + threadIdx.x;   // i < N*256
    int n = i >> 8, c = i & 255;
    double sc, sh;
    bn_params(sum, sumsq, g, b, invM, c, sc, sh);
    bool s0, s1;
    lif2((double)X[i] * sc + sh, (double)X[(size_t)i + (size_t)N_NODES * 256] * sc + sh, s0, s1);
    uint64_t b0 = __ballot(s0), b1 = __ballot(s1);
    if ((threadIdx.x & 63) == 0) {
        int widx = n * osWords + chOffWords + (c >> 6);
        S[widx] = b0;
        S[widx + N_NODES * osWords] = b1;
    }
}

// h += bn(X) (f32 activations) AND emit lif(h_new) bits for this chunk
__global__ __launch_bounds__(256)
void bn_add_lif2(const float* __restrict__ X,
                 const double* __restrict__ sum, const double* __restrict__ sumsq,
                 const float* __restrict__ g, const float* __restrict__ b, double invM,
                 double* __restrict__ H, int chOff, uint64_t* __restrict__ S) {
    int i = blockIdx.x * 256 + threadIdx.x;   // i < N*256
    int n = i >> 8, c = i & 255;
    double sc, sh;
    bn_params(sum, sumsq, g, b, invM, c, sc, sh);
    size_t hi = (size_t)n * 512 + chOff + c;
    double h0 = H[hi] + ((double)X[i] * sc + sh);
    double h1 = H[hi + ND] + ((double)X[(size_t)i + (size_t)N_NODES * 256] * sc + sh);
    H[hi] = h0;
    H[hi + ND] = h1;
    bool s0, s1;
    lif2(h0, h1, s0, s1);
    uint64_t b0 = __ballot(s0), b1 = __ballot(s1);
    if ((threadIdx.x & 63) == 0) {
        int widx = n * 8 + (chOff >> 6) + (c >> 6);
        S[widx] = b0;
        S[widx + N_NODES * 8] = b1;
    }
}

// LayerNorm(512)+ReLU on fc0 output; write both t-slices of h AND emit lif bits
__global__ __launch_bounds__(256)
void ln_relu_lif(const double* __restrict__ X, const float* __restrict__ g,
                 const float* __restrict__ b, double* __restrict__ H,
                 uint64_t* __restrict__ S) {
    int n = blockIdx.x;
    const double* x = X + (size_t)n * 512;
    int c0 = threadIdx.x, c1 = threadIdx.x + 256;
    double v0 = x[c0], v1 = x[c1];
    __shared__ double ls[256], lq[256];
    ls[threadIdx.x] = v0 + v1;
    lq[threadIdx.x] = v0 * v0 + v1 * v1;
    __syncthreads();
    for (int off = 128; off > 0; off >>= 1) {
        if (threadIdx.x < off) {
            ls[threadIdx.x] += ls[threadIdx.x + off];
            lq[threadIdx.x] += lq[threadIdx.x + off];
        }
        __syncthreads();
    }
    double m    = ls[0] * (1.0 / 512);
    double var  = lq[0] * (1.0 / 512) - m * m;
    double rstd = 1.0 / sqrt(var + 1e-5);
    double o0 = (v0 - m) * rstd * (double)g[c0] + (double)b[c0];
    double o1 = (v1 - m) * rstd * (double)g[c1] + (double)b[c1];
    o0 = o0 > 0.0 ? o0 : 0.0;
    o1 = o1 > 0.0 ? o1 : 0.0;
    double* h0 = H + (size_t)n * 512;
    h0[c0] = o0; h0[c1] = o1;
    h0[ND + c0] = o0; h0[ND + c1] = o1;
    // lif with x0 == x1 == o
    bool a0, a1, d0, d1;
    lif2(o0, o0, a0, a1);
    lif2(o1, o1, d0, d1);
    uint64_t ba0 = __ballot(a0), ba1 = __ballot(a1);
    uint64_t bd0 = __ballot(d0), bd1 = __ballot(d1);
    if ((threadIdx.x & 63) == 0) {
        int w = threadIdx.x >> 6;
        S[n * 8 + w] = ba0;
        S[n * 8 + w + N_NODES * 8] = ba1;
        S[n * 8 + 4 + w] = bd0;
        S[n * 8 + 4 + w + N_NODES * 8] = bd1;
    }
}

// ===========================================================================
// Attention on bit spikes (integer-exact in fp32).
// ===========================================================================
__global__ __launch_bounds__(256)
void kv_bits(const uint64_t* __restrict__ Kb, const uint64_t* __restrict__ Vb,
             float* __restrict__ KV, int nPerBlock) {
    const int th = blockIdx.x;
    const int t = th >> 3, h = th & 7;
    const int nbase = blockIdx.y * nPerBlock;
    const int e = threadIdx.x & 63, dg = threadIdx.x >> 6;
    float acc[16];
#pragma unroll
    for (int i = 0; i < 16; i++) acc[i] = 0.f;
    __shared__ float ks[16][64], vs[16][64];
    const size_t wbase = (size_t)t * N_NODES * 8 + h;
    for (int n0 = 0; n0 < nPerBlock; n0 += 16) {
        for (int idx = threadIdx.x; idx < 16 * 128; idx += 256) {
            int r = idx >> 7, c = idx & 127;
            size_t wi = wbase + (size_t)(nbase + n0 + r) * 8;
            if (c < 64) ks[r][c] = (float)((Kb[wi] >> c) & 1ull);
            else        vs[r][c - 64] = (float)((Vb[wi] >> (c - 64)) & 1ull);
        }
        __syncthreads();
#pragma unroll
        for (int r = 0; r < 16; ++r) {
            float ve = vs[r][e];
#pragma unroll
            for (int i = 0; i < 16; ++i) acc[i] += ks[r][dg * 16 + i] * ve;
        }
        __syncthreads();
    }
    float* kvp = KV + (size_t)th * 4096;
    for (int i = 0; i < 16; ++i)
        atomicAdd(&kvp[(dg * 16 + i) * 64 + e], acc[i]);
}

// O = (Q @ KV) * 0.125 for BOTH timesteps, LIF in-register, emit bits.
__global__ __launch_bounds__(256)
void o_lif_bits(const uint64_t* __restrict__ Qb, const float* __restrict__ KV,
                uint64_t* __restrict__ S) {
    const int h  = blockIdx.y;     // 8 heads
    const int nb = blockIdx.x;     // N/64 row blocks
    __shared__ float kvs[64][64];
    __shared__ float qs[64][65];
    const int e = threadIdx.x & 63, rg = threadIdx.x >> 6;
    float acc0[16], acc1[16];
#pragma unroll
    for (int i = 0; i < 16; ++i) { acc0[i] = 0.f; acc1[i] = 0.f; }
#pragma unroll
    for (int t = 0; t < 2; ++t) {
        const float* kvp = KV + (size_t)(t * 8 + h) * 4096;
        for (int idx = threadIdx.x; idx < 4096; idx += 256)
            kvs[idx >> 6][idx & 63] = kvp[idx];
        const size_t wbase = ((size_t)t * N_NODES + (size_t)nb * 64) * 8 + h;
        for (int idx = threadIdx.x; idx < 4096; idx += 256) {
            int r = idx >> 6, c = idx & 63;
            qs[r][c] = (float)((Qb[wbase + (size_t)r * 8] >> c) & 1ull);
        }
        __syncthreads();
        float* acc = t == 0 ? acc0 : acc1;
        for (int d = 0; d < 64; ++d) {
            float kv = kvs[d][e];
#pragma unroll
            for (int i = 0; i < 16; ++i) acc[i] += qs[rg * 16 + i][d] * kv;
        }
        __syncthreads();   // LDS reloaded next t
    }
#pragma unroll
    for (int i = 0; i < 16; ++i) {
        float o0 = acc0[i] * 0.125f;
        float o1 = acc1[i] * 0.125f;
        bool s0, s1;
        lif2((double)o0, (double)o1, s0, s1);
        uint64_t b0 = __ballot(s0), b1 = __ballot(s1);
        if (e == 0) {
            size_t row = (size_t)nb * 64 + rg * 16 + i;
            S[row * 8 + h] = b0;
            S[row * 8 + h + (size_t)N_NODES * 8] = b1;
        }
    }
}

// ===========================================================================
// GNN branch (fp32)
// ===========================================================================
__global__ __launch_bounds__(256)
void deg_kernel(const int* __restrict__ col, float* __restrict__ deg, int E) {
    int e = blockIdx.x * 256 + threadIdx.x;
    if (e < E) atomicAdd(&deg[col[e]], 1.0f);
}

__global__ __launch_bounds__(256)
void dinv_kernel(float* __restrict__ deg, int n) {
    int i = blockIdx.x * 256 + threadIdx.x;
    if (i < n) {
        double d = (double)deg[i];
        deg[i] = d > 0.0 ? (float)(1.0 / sqrt(d)) : 0.f;
    }
}

// 40 threads per edge (no idle lanes)
__global__ __launch_bounds__(256)
void agg_kernel(const float* __restrict__ G, const int* __restrict__ row,
                const int* __restrict__ col, const float* __restrict__ dinv,
                float* __restrict__ out, int E) {
    int idx = blockIdx.x * 256 + threadIdx.x;
    int e = idx / C_OUT, c = idx - e * C_OUT;
    if (e >= E) return;
    int r = row[e], cl = col[e];
    float val = dinv[cl] * dinv[r];
    atomicAdd(&out[(size_t)cl * C_OUT + c], val * G[(size_t)r * C_OUT + c]);
}

__global__ __launch_bounds__(256)
void bn_relu_add_f2(const float* __restrict__ X,
                    const double* __restrict__ sum, const double* __restrict__ sumsq,
                    const float* __restrict__ g, const float* __restrict__ b, double invM,
                    const float* __restrict__ add, float* __restrict__ out, int NC, int Ch) {
    int i = blockIdx.x * 256 + threadIdx.x;
    if (i >= NC) return;
    int c = i % Ch;
    double sc, sh;
    bn_params(sum, sumsq, g, b, invM, c, sc, sh);
    double v = (double)X[i] * sc + sh;
    v = v > 0.0 ? v : 0.0;
    if (add) v += (double)add[i];
    out[i] = (float)v;
}

__global__ __launch_bounds__(256)
void mix_kernel(const float* __restrict__ G, const float* __restrict__ Y,
                float* __restrict__ P, int NC) {
    int i = blockIdx.x * 256 + threadIdx.x;
    if (i >= NC) return;
    double y = 0.5 * ((double)Y[i] + (double)Y[(size_t)i + NC]);
    P[i] = (float)(0.8 * (double)G[i] + 0.2 * y);
}

__global__ __launch_bounds__(256)
void final_fc_kernel(const float* __restrict__ A, const float* __restrict__ W,
                     const float* __restrict__ bias, float* __restrict__ out) {
    __shared__ float Ws[40][40];
    for (int idx = threadIdx.x; idx < 1600; idx += 256)
        Ws[idx / 40][idx % 40] = W[idx];
    __syncthreads();
    int i = blockIdx.x * 256 + threadIdx.x;
    if (i >= N_NODES * C_OUT) return;
    int n = i / 40, c = i - n * 40;
    const float* a = A + (size_t)n * 40;
    double acc = (double)bias[c];
#pragma unroll 8
    for (int k = 0; k < 40; ++k) acc += (double)a[k] * (double)Ws[k][c];
    out[i] = (float)acc;
}

// ===========================================================================
// Host orchestration
// ===========================================================================
static inline dim3 grid1(long n) { return dim3((unsigned)((n + 255) / 256)); }

extern "C" void kernel_launch(void* const* d_in, const int* in_sizes, int n_in,
                              void* d_out, int out_size, void* d_ws, size_t ws_size,
                              hipStream_t stream) {
    const float* x      = (const float*)d_in[0];
    const float* fc0_w  = (const float*)d_in[1];
    const float* fc0_b  = (const float*)d_in[2];
    const float* ln_g   = (const float*)d_in[3];
    const float* ln_b   = (const float*)d_in[4];
    const float* wq     = (const float*)d_in[5];
    const float* wk     = (const float*)d_in[6];
    const float* wv     = (const float*)d_in[7];
    const float* wo     = (const float*)d_in[8];
    const float* bnq_g  = (const float*)d_in[9];
    const float* bnq_b  = (const float*)d_in[10];
    const float* bnk_g  = (const float*)d_in[11];
    const float* bnk_b  = (const float*)d_in[12];
    const float* bnv_g  = (const float*)d_in[13];
    const float* bnv_b  = (const float*)d_in[14];
    const float* bno_g  = (const float*)d_in[15];
    const float* bno_b  = (const float*)d_in[16];
    const float* w1     = (const float*)d_in[17];
    const float* bn1_g  = (const float*)d_in[18];
    const float* bn1_b  = (const float*)d_in[19];
    const float* w2     = (const float*)d_in[20];
    const float* bn2_g  = (const float*)d_in[21];
    const float* bn2_b  = (const float*)d_in[22];
    const float* head_w = (const float*)d_in[23];
    const float* head_b = (const float*)d_in[24];
    const float* gfc_w  = (const float*)d_in[25];
    const float* gfc_b  = (const float*)d_in[26];
    const float* gbn0_g = (const float*)d_in[27];
    const float* gbn0_b = (const float*)d_in[28];
    const float* gconv_w= (const float*)d_in[29];
    const float* gconv_b= (const float*)d_in[30];
    const float* gbn_g  = (const float*)d_in[31];
    const float* gbn_b  = (const float*)d_in[32];
    const float* fc_w   = (const float*)d_in[33];
    const float* fc_b   = (const float*)d_in[34];
    const int*   edge   = (const int*)d_in[35];

    const int E = in_sizes[35] / 2;
    const int* erow = edge;
    const int* ecol = edge + E;
    const int NC = N_NODES * C_OUT;

    // ---- workspace layout (~234 MiB) ----
    uint8_t* wsbase = (uint8_t*)d_ws;
    size_t off = 0;
    auto alloc = [&](size_t bytes, size_t align) -> void* {
        off = (off + align - 1) & ~(align - 1);
        void* p = wsbase + off;
        off += bytes;
        return p;
    };
    double*   statBuf = (double*)alloc((size_t)64 * 512 * sizeof(double), 256);  // per-gate stats
    double*   h_buf  = (double*)alloc((size_t)2 * ND * sizeof(double), 256);     // 134 MB
    double*   Pd     = (double*)alloc((size_t)M2 * CW * sizeof(double), 256);    // 67 MB
    float*    Pf     = (float*)Pd;   // f32 view for the i8 GEMM -> bn path
    uint8_t*  Wdig   = (uint8_t*)alloc((size_t)WD_TOTAL, 256);                   // 10.5 MB
    uint64_t* s_bits = (uint64_t*)alloc((size_t)2 * N_NODES * 8 * 8, 256);
    uint64_t* q_bits = (uint64_t*)alloc((size_t)2 * N_NODES * 8 * 8, 256);
    uint64_t* k_bits = (uint64_t*)alloc((size_t)2 * N_NODES * 8 * 8, 256);
    uint64_t* v_bits = (uint64_t*)alloc((size_t)2 * N_NODES * 8 * 8, 256);
    uint64_t* m_bits = (uint64_t*)alloc((size_t)2 * N_NODES * 16 * 8, 256);      // 4.2 MB
    float*    ybuf   = (float*)m_bits;  // alias: y written at head, after m_bits dead
    (void)alloc((size_t)2 * NC * sizeof(float) > (size_t)2 * N_NODES * 16 * 8
                ? (size_t)2 * NC * sizeof(float) - (size_t)2 * N_NODES * 16 * 8 : 0, 256);
    float*    g0     = (float*)alloc((size_t)NC * sizeof(float), 256);
    float*    gg     = (float*)alloc((size_t)NC * sizeof(float), 256);
    float*    ag     = (float*)alloc((size_t)NC * sizeof(float), 256);
    float*    kvb    = (float*)alloc((size_t)65536 * sizeof(float), 256);
    float*    deg    = (float*)alloc((size_t)N_NODES * sizeof(float), 256);
    if (off > ws_size) return;

    const dim3 blk(256);
    const dim3 gCHK((unsigned)(N_NODES));
    const dim3 gGEMM(CW / 64, M2 / 128);
    const double invM2 = 1.0 / (double)M2;
    const double invMN = 1.0 / (double)N_NODES;

    hipMemsetAsync(statBuf, 0, (size_t)64 * 512 * sizeof(double), stream);

    int gate = 0;
    auto nextStat = [&]() { return statBuf + (size_t)(gate++) * 512; };

    // ===== transformer branch =====
    hipLaunchKernelGGL(gemm_f32d, dim3(8, N_NODES / 64), blk, 0, stream,
                       x, 512, fc0_w, 512, fc0_b, Pd, 512, N_NODES, 512, 512);
    hipLaunchKernelGGL(ln_relu_lif, dim3(N_NODES), blk, 0, stream, Pd, ln_g, ln_b, h_buf, s_bits);

    for (int l = 0; l < 4; ++l) {
        // one prep launch for all 6 matrices of this layer
        hipLaunchKernelGGL(w_digits_layer, dim3(512), blk, 0, stream,
                           wq + (size_t)l * 262144, wk + (size_t)l * 262144,
                           wv + (size_t)l * 262144, wo + (size_t)l * 262144,
                           w1 + (size_t)l * 524288, w2 + (size_t)l * 524288, Wdig);

        uint64_t* qkvb[3] = {q_bits, k_bits, v_bits};
        const size_t wdoff[3] = {WD_Q, WD_K, WD_V};
        const float* gmat[3] = {bnq_g + l * 512, bnk_g + l * 512, bnv_g + l * 512};
        const float* bmat[3] = {bnq_b + l * 512, bnk_b + l * 512, bnv_b + l * 512};
        for (int j = 0; j < 3; ++j) {
            for (int c0 = 0; c0 < 512; c0 += CW) {
                double* st = nextStat();
                hipLaunchKernelGGL(gemm_i8_bits, gGEMM, blk, 0, stream,
                                   s_bits, 8, Wdig + wdoff[j], 512, c0, Pf, CW, 512, st, st + 256);
                hipLaunchKernelGGL(bn_lif_bits2, gCHK, blk, 0, stream,
                                   Pf, st, st + 256, gmat[j] + c0, bmat[j] + c0, invM2,
                                   qkvb[j], 8, c0 / 64);
            }
        }

        // attention (exact); fused O-proj input: lif(o) bits -> q_bits in place
        hipMemsetAsync(kvb, 0, 65536 * sizeof(float), stream);
        hipLaunchKernelGGL(kv_bits, dim3(16, 16), blk, 0, stream, k_bits, v_bits, kvb, 1024);
        hipLaunchKernelGGL(o_lif_bits, dim3(N_NODES / 64, 8), blk, 0, stream, q_bits, kvb, q_bits);

        // h += bn(lif(o) @ wo); emit s = lif(h_new) into s_bits
        for (int c0 = 0; c0 < 512; c0 += CW) {
            double* st = nextStat();
            hipLaunchKernelGGL(gemm_i8_bits, gGEMM, blk, 0, stream,
                               q_bits, 8, Wdig + WD_O, 512, c0, Pf, CW, 512, st, st + 256);
            hipLaunchKernelGGL(bn_add_lif2, gCHK, blk, 0, stream,
                               Pf, st, st + 256, bno_g + l * 512 + c0, bno_b + l * 512 + c0,
                               invM2, h_buf, c0, s_bits);
        }

        // MLP: m = lif(bn1(s @ w1)) in 4 chunks of 256
        for (int c0 = 0; c0 < 1024; c0 += CW) {
            double* st = nextStat();
            hipLaunchKernelGGL(gemm_i8_bits, gGEMM, blk, 0, stream,
                               s_bits, 8, Wdig + WD_1, 1024, c0, Pf, CW, 512, st, st + 256);
            hipLaunchKernelGGL(bn_lif_bits2, gCHK, blk, 0, stream,
                               Pf, st, st + 256, bn1_g + l * 1024 + c0, bn1_b + l * 1024 + c0,
                               invM2, m_bits, 16, c0 / 64);
        }
        // h += bn2(m @ w2); emit s = lif(h_new) for next layer / head
        for (int c0 = 0; c0 < 512; c0 += CW) {
            double* st = nextStat();
            hipLaunchKernelGGL(gemm_i8_bits, gGEMM, blk, 0, stream,
                               m_bits, 16, Wdig + WD_2, 512, c0, Pf, CW, 1024, st, st + 256);
            hipLaunchKernelGGL(bn_add_lif2, gCHK, blk, 0, stream,
                               Pf, st, st + 256, bn2_g + l * 512 + c0, bn2_b + l * 512 + c0,
                               invM2, h_buf, c0, s_bits);
        }
    }

    // head: y = s @ head_w + head_b (s_bits already = lif(h_final))
    hipLaunchKernelGGL(head_gather, dim3(M2 / 4), blk, 0, stream, s_bits, head_w, head_b, ybuf);

    // ===== GNN branch (fp32) =====
    hipLaunchKernelGGL(gemm_f32, dim3(1, N_NODES / 64), blk, 0, stream,
                       x, 512, gfc_w, 40, gfc_b, ag, 40, N_NODES, 40, 512);
    {
        double* st = nextStat();
        dim3 gs(1, (N_NODES + 511) / 512);
        hipLaunchKernelGGL(col_stats_f, gs, blk, 0, stream, ag, N_NODES, 40, 512, st, st + 256);
        hipLaunchKernelGGL(bn_relu_add_f2, grid1(NC), blk, 0, stream,
                           ag, st, st + 256, gbn0_g, gbn0_b, invMN,
                           (const float*)nullptr, g0, NC, 40);
    }

    hipMemsetAsync(deg, 0, N_NODES * sizeof(float), stream);
    hipLaunchKernelGGL(deg_kernel, grid1(E), blk, 0, stream, ecol, deg, E);
    hipLaunchKernelGGL(dinv_kernel, grid1(N_NODES), blk, 0, stream, deg, N_NODES);

    const float* gsrc = g0;
    for (int i = 0; i < 2; ++i) {
        hipMemsetAsync(ag, 0, (size_t)NC * sizeof(float), stream);
        hipLaunchKernelGGL(agg_kernel, grid1((long)E * C_OUT), blk, 0, stream,
                           gsrc, erow, ecol, deg, ag, E);
        hipLaunchKernelGGL(gemm_f32, dim3(1, N_NODES / 64), blk, 0, stream,
                           ag, 40, gconv_w + (size_t)i * 40 * 40, 40, gconv_b + i * 40,
                           gg, 40, N_NODES, 40, 40);
        double* st = nextStat();
        dim3 gs(1, (N_NODES + 511) / 512);
        hipLaunchKernelGGL(col_stats_f, gs, blk, 0, stream, gg, N_NODES, 40, 512, st, st + 256);
        hipLaunchKernelGGL(bn_relu_add_f2, grid1(NC), blk, 0, stream,
                           gg, st, st + 256, gbn_g + i * 40, gbn_b + i * 40, invMN, g0, gg, NC, 40);
        gsrc = gg;
    }

    // out = (0.8*g + 0.2*mean_t(y)) @ fc_w + fc_b
    hipLaunchKernelGGL(mix_kernel, grid1(NC), blk, 0, stream, gg, ybuf, ag, NC);
    hipLaunchKernelGGL(final_fc_kernel, grid1((long)N_NODES * C_OUT), blk, 0, stream,
                       ag, fc_w, fc_b, (float*)d_out);
}

// Round 5
// 5814.859 us; speedup vs baseline: 2.2436x; 1.0805x over previous
//
#include <hip/hip_runtime.h>
#include <cstddef>
#include <cstdint>

constexpr int N_NODES = 16384;
constexpr int D_MODEL = 512;
constexpr int C_OUT   = 40;
constexpr int ND      = N_NODES * D_MODEL;   // per-timestep elements (512-ch)
constexpr int M2      = 2 * N_NODES;         // T*N rows

typedef int i32x4 __attribute__((ext_vector_type(4)));

// digit scales: w ≈ Σ d_j * S_j, residual ≤ 2^-38 (5 digits)
#define S0 0.001953125                      // 2^-9
#define S1 1.52587890625e-05                // 2^-16
#define S2 1.1920928955078125e-07           // 2^-23
#define S3 9.31322574615478515625e-10       // 2^-30
#define S4 7.2759576141834259033203125e-12  // 2^-37

// digit-plane offsets within the per-layer buffer (bytes)
#define WD_Q 0
#define WD_K 1310720
#define WD_V 2621440
#define WD_O 3932160
#define WD_1 5242880
#define WD_2 7864320
#define WD_TOTAL 10485760

// ===========================================================================
// Per-layer weight -> 5 signed-i8 digit planes in MFMA B-fragment order:
// byte at ((k/16)*N + n)*80 + j*16 + (k%16).
// ===========================================================================
__global__ __launch_bounds__(256)
void w_digits_layer(const float* __restrict__ wq, const float* __restrict__ wk,
                    const float* __restrict__ wv, const float* __restrict__ wo,
                    const float* __restrict__ w1, const float* __restrict__ w2,
                    uint8_t* __restrict__ Wd) {
    int idx = blockIdx.x * 256 + threadIdx.x;   // [0, 131072)
    const float* W;
    uint8_t* outb;
    int N, rem;
    if (idx < 65536) {                          // wq,wk,wv,wo: 4 x (32 kg x 512 n)
        int mm = idx >> 14;
        rem = idx & 16383;
        const float* ptrs[4] = {wq, wk, wv, wo};
        W = ptrs[mm]; outb = Wd + (size_t)mm * 1310720; N = 512;
    } else if (idx < 98304) {                   // w1: 32 kg x 1024 n
        rem = idx - 65536; W = w1; outb = Wd + WD_1; N = 1024;
    } else {                                    // w2: 64 kg x 512 n
        rem = idx - 98304; W = w2; outb = Wd + WD_2; N = 512;
    }
    int kg = rem / N, n = rem - kg * N;
    const float* Wp = W + (size_t)kg * 16 * N + n;
    uint8_t* out = outb + (size_t)(kg * N + n) * 80;
    const double scl[5] = {512.0, 65536.0, 8388608.0, 1073741824.0, 137438953472.0};
    const double inv[5] = {S0, S1, S2, S3, S4};
    union { uint8_t b[5][16]; i32x4 v[5]; } db;
#pragma unroll
    for (int kk = 0; kk < 16; ++kk) {
        double r = (double)Wp[(size_t)kk * N];
#pragma unroll
        for (int j = 0; j < 5; ++j) {
            int d = (int)rint(r * scl[j]);
            d = d > 127 ? 127 : (d < -127 ? -127 : d);
            r -= (double)d * inv[j];
            db.b[j][kk] = (uint8_t)(int8_t)d;
        }
    }
#pragma unroll
    for (int j = 0; j < 5; ++j)
        *reinterpret_cast<i32x4*>(out + j * 16) = db.v[j];
}

// ===========================================================================
// Spike GEMM via i8 MFMA, exact fixed-point. 128-row blocks, LDS-staged B.
// BN stats accumulated in f64 from the EXACT p; activation stored as f32.
// ===========================================================================
__global__ __launch_bounds__(256)
void gemm_i8_bits(const uint64_t* __restrict__ bits, int kWords,
                  const uint8_t* __restrict__ Wd, int Nmat, int colOff,
                  float* __restrict__ C, int ldc, int K,
                  double* __restrict__ sum, double* __restrict__ sumsq) {
    __shared__ __attribute__((aligned(16))) uint8_t Bs[20480];
    const int lane = threadIdx.x & 63;
    const int wv   = threadIdx.x >> 6;
    const int m    = lane & 15;
    const int q    = lane >> 4;
    const int rowT = blockIdx.y * 128 + wv * 32;   // this wave's 32-row tile
    const int colB = blockIdx.x * 64;

    i32x4 acc[2][4][5];
#pragma unroll
    for (int rt = 0; rt < 2; ++rt)
#pragma unroll
        for (int t = 0; t < 4; ++t)
#pragma unroll
            for (int j = 0; j < 5; ++j) acc[rt][t][j] = (i32x4){0, 0, 0, 0};

    const uint64_t* brow0 = bits + (size_t)(rowT + m) * kWords;
    const uint64_t* brow1 = brow0 + (size_t)16 * kWords;
    const size_t cb = (size_t)(colOff + colB);

    for (int kb = 0; kb < K; kb += 64) {
        // --- load the 4-ktile x 64-col x 80B digit tile (20KB) to registers ---
        i32x4 tmp[5];
        const size_t kt0 = (size_t)(kb >> 4);
#pragma unroll
        for (int c5 = 0; c5 < 5; ++c5) {
            int c  = threadIdx.x + c5 * 256;       // [0,1280) 16B chunks
            int kt = c / 320;                      // ktile (5120B each, contiguous)
            int of = c - kt * 320;
            tmp[c5] = *reinterpret_cast<const i32x4*>(
                Wd + ((kt0 + (size_t)kt) * Nmat + cb) * 80 + (size_t)of * 16);
        }
        // --- A spike fragments for both row-tiles ---
        uint64_t wb0 = brow0[kb >> 6];
        uint64_t wb1 = brow1[kb >> 6];
        uint32_t hw0 = (uint32_t)(wb0 >> (q * 16)) & 0xFFFFu;
        uint32_t hw1 = (uint32_t)(wb1 >> (q * 16)) & 0xFFFFu;
        i32x4 af0, af1;
#pragma unroll
        for (int i = 0; i < 4; ++i) {
            af0[i] = (int)((((hw0 >> (4 * i)) & 0xFu) * 0x00204081u) & 0x01010101u);
            af1[i] = (int)((((hw1 >> (4 * i)) & 0xFu) * 0x00204081u) & 0x01010101u);
        }
        __syncthreads();                 // previous tile fully consumed
#pragma unroll
        for (int c5 = 0; c5 < 5; ++c5) {
            int c  = threadIdx.x + c5 * 256;
            int kt = c / 320;
            int of = c - kt * 320;
            *reinterpret_cast<i32x4*>(Bs + kt * 5120 + of * 16) = tmp[c5];
        }
        __syncthreads();                 // tile staged
#pragma unroll
        for (int t = 0; t < 4; ++t) {
            const uint8_t* bt = Bs + q * 5120 + (t * 16 + m) * 80;
            i32x4 bf[5];
#pragma unroll
            for (int j = 0; j < 5; ++j)
                bf[j] = *reinterpret_cast<const i32x4*>(bt + j * 16);
#pragma unroll
            for (int j = 0; j < 5; ++j) {
                acc[0][t][j] = __builtin_amdgcn_mfma_i32_16x16x64_i8(af0, bf[j], acc[0][t][j], 0, 0, 0);
                acc[1][t][j] = __builtin_amdgcn_mfma_i32_16x16x64_i8(af1, bf[j], acc[1][t][j], 0, 0, 0);
            }
        }
    }

    double sarr[4], qarr[4];
#pragma unroll
    for (int t = 0; t < 4; ++t) { sarr[t] = 0.0; qarr[t] = 0.0; }
#pragma unroll
    for (int rt = 0; rt < 2; ++rt) {
        const int orow = rowT + rt * 16 + q * 4;
#pragma unroll
        for (int t = 0; t < 4; ++t) {
            float* Cc = C + (size_t)orow * ldc + colB + t * 16 + m;
#pragma unroll
            for (int i = 0; i < 4; ++i) {
                double p = (double)acc[rt][t][0][i] * S0 + (double)acc[rt][t][1][i] * S1
                         + (double)acc[rt][t][2][i] * S2 + (double)acc[rt][t][3][i] * S3
                         + (double)acc[rt][t][4][i] * S4;
                Cc[(size_t)i * ldc] = (float)p;
                sarr[t] += p; qarr[t] += p * p;
            }
        }
    }
    __shared__ double ls[4][64], lq[4][64];
#pragma unroll
    for (int t = 0; t < 4; ++t) {
        double s = sarr[t], qq = qarr[t];
        s  += __shfl_xor(s, 16);  s  += __shfl_xor(s, 32);
        qq += __shfl_xor(qq, 16); qq += __shfl_xor(qq, 32);
        if (lane < 16) { ls[wv][t * 16 + lane] = s; lq[wv][t * 16 + lane] = qq; }
    }
    __syncthreads();
    if (threadIdx.x < 64) {
        int t = threadIdx.x;
        double s  = ls[0][t] + ls[1][t] + ls[2][t] + ls[3][t];
        double qq = lq[0][t] + lq[1][t] + lq[2][t] + lq[3][t];
        atomicAdd(&sum[colB + t], s);
        atomicAdd(&sumsq[colB + t], qq);
    }
}

// head GEMM: exact f64 gather (immune to any MFMA layout quirk)
__global__ __launch_bounds__(256)
void head_gather(const uint64_t* __restrict__ bits, const float* __restrict__ W,
                 const float* __restrict__ bias, float* __restrict__ Y) {
    const int lane = threadIdx.x & 63;
    const int wid  = threadIdx.x >> 6;
    const int r = blockIdx.x * 4 + wid;
    if (lane >= C_OUT) return;
    double acc = (double)bias[lane];
    const uint64_t* bw = bits + (size_t)r * 8;
    for (int j = 0; j < 8; ++j) {
        uint64_t w = bw[j];
        const float* Wk = W + (size_t)j * 64 * C_OUT + lane;
        while (w) {
            int k = __builtin_ctzll(w);
            w &= w - 1;
            acc += (double)Wk[(size_t)k * C_OUT];
        }
    }
    Y[(size_t)r * C_OUT + lane] = (float)acc;
}

// GEMM (float A, float out, f64 acc) — fc0 only. Swizzled f32 LDS (R2-proven).
__global__ __launch_bounds__(256)
void gemm_f32d(const float* __restrict__ A, int lda,
               const float* __restrict__ B, int ldb,
               const float* __restrict__ bias,
               float* __restrict__ C, int ldc, int M, int Nc, int K) {
    __shared__ float As[16][64];
    __shared__ float Bs[16][64];
    const int tid = threadIdx.x;
    const int tx  = tid & 15, ty = tid >> 4;
    const int row0 = blockIdx.y * 64 + ty * 4;
    const int col0 = blockIdx.x * 64 + tx * 4;
    const int ar = tid >> 2, ak = (tid & 3) * 4;   // A: row ar, k ak..ak+3
    const int bk = tid >> 4, bn = (tid & 15) * 4;  // B: k-row bk, cols bn..bn+3
    const int gm = blockIdx.y * 64 + ar;
    double acc[4][4];
#pragma unroll
    for (int i = 0; i < 4; i++)
#pragma unroll
        for (int j = 0; j < 4; j++) acc[i][j] = 0.0;
    for (int k0 = 0; k0 < K; k0 += 16) {
        float4 av = *reinterpret_cast<const float4*>(&A[(size_t)gm * lda + k0 + ak]);
        const float* avp = reinterpret_cast<const float*>(&av);
#pragma unroll
        for (int j = 0; j < 4; j++)
            As[ak + j][ar ^ ((ak + j) & 12)] = avp[j];
        float4 bv = *reinterpret_cast<const float4*>(
            &B[(size_t)(k0 + bk) * ldb + blockIdx.x * 64 + bn]);
        *reinterpret_cast<float4*>(&Bs[bk][bn ^ ((bk & 3) << 2)]) = bv;
        __syncthreads();
#pragma unroll
        for (int kk = 0; kk < 16; kk++) {
            float4 a4 = *reinterpret_cast<const float4*>(&As[kk][(ty * 4) ^ (kk & 12)]);
            float4 b4 = *reinterpret_cast<const float4*>(&Bs[kk][(tx * 4) ^ ((kk & 3) << 2)]);
            const float* ap = reinterpret_cast<const float*>(&a4);
            const float* bp = reinterpret_cast<const float*>(&b4);
#pragma unroll
            for (int i = 0; i < 4; i++)
#pragma unroll
                for (int j = 0; j < 4; j++)
                    acc[i][j] = fma((double)ap[i], (double)bp[j], acc[i][j]);
        }
        __syncthreads();
    }
#pragma unroll
    for (int i = 0; i < 4; i++) {
        int r = row0 + i;
        if (r >= M) continue;
#pragma unroll
        for (int j = 0; j < 4; j++) {
            int c = col0 + j;
            if (c < Nc) {
                double v = acc[i][j];
                if (bias) v += (double)bias[c];
                C[(size_t)r * ldc + c] = (float)v;
            }
        }
    }
}

// GEMM (float A/B/C, double acc) — GNN branch.
__global__ __launch_bounds__(256)
void gemm_f32(const float* __restrict__ A, int lda,
              const float* __restrict__ B, int ldb,
              const float* __restrict__ bias,
              float* __restrict__ C, int ldc, int M, int Nc, int K) {
    __shared__ float As[16][64];
    __shared__ float Bs[16][64];
    const int tid = threadIdx.x;
    const int tx  = tid & 15, ty = tid >> 4;
    const int row0 = blockIdx.y * 64 + ty * 4;
    const int col0 = blockIdx.x * 64 + tx * 4;
    const int ar = tid >> 2, ak = (tid & 3) * 4;
    const int bk = tid >> 4, bn = (tid & 15) * 4;
    const int gm = blockIdx.y * 64 + ar;
    double acc[4][4];
#pragma unroll
    for (int i = 0; i < 4; i++)
#pragma unroll
        for (int j = 0; j < 4; j++) acc[i][j] = 0.0;
    for (int k0 = 0; k0 < K; k0 += 16) {
#pragma unroll
        for (int j = 0; j < 4; j++) {
            int kk = k0 + ak + j;
            As[ak + j][ar] = (gm < M && kk < K) ? A[(size_t)gm * lda + kk] : 0.f;
        }
#pragma unroll
        for (int j = 0; j < 4; j++) {
            int gn = blockIdx.x * 64 + bn + j;
            int kk = k0 + bk;
            Bs[bk][bn + j] = (gn < Nc && kk < K) ? B[(size_t)kk * ldb + gn] : 0.f;
        }
        __syncthreads();
#pragma unroll
        for (int kk = 0; kk < 16; kk++) {
            float a4[4], b4[4];
#pragma unroll
            for (int i = 0; i < 4; i++) a4[i] = As[kk][ty * 4 + i];
#pragma unroll
            for (int j = 0; j < 4; j++) b4[j] = Bs[kk][tx * 4 + j];
#pragma unroll
            for (int i = 0; i < 4; i++)
#pragma unroll
                for (int j = 0; j < 4; j++) acc[i][j] = fma((double)a4[i], (double)b4[j], acc[i][j]);
        }
        __syncthreads();
    }
#pragma unroll
    for (int i = 0; i < 4; i++) {
        int r = row0 + i;
        if (r >= M) continue;
#pragma unroll
        for (int j = 0; j < 4; j++) {
            int c = col0 + j;
            if (c < Nc) {
                double v = acc[i][j];
                if (bias) v += (double)bias[c];
                C[(size_t)r * ldc + c] = (float)v;
            }
        }
    }
}

// BN stats for fp32 inputs (GNN branch) -> per-gate buffers
__global__ __launch_bounds__(256)
void col_stats_f(const float* __restrict__ X, int M, int Ch, int rowsPerBlock,
                 double* __restrict__ sum, double* __restrict__ sumsq) {
    const int cl = threadIdx.x & 63;
    const int c  = blockIdx.x * 64 + cl;
    const int rg = threadIdx.x >> 6;
    const int r0 = blockIdx.y * rowsPerBlock;
    const int r1 = min(r0 + rowsPerBlock, M);
    double s = 0.0, q = 0.0;
    if (c < Ch) {
        for (int r = r0 + rg; r < r1; r += 4) {
            double v = (double)X[(size_t)r * Ch + c];
            s += v; q += v * v;
        }
    }
    __shared__ double ls[4][64], lq[4][64];
    ls[rg][cl] = s; lq[rg][cl] = q;
    __syncthreads();
    if (rg == 0 && c < Ch) {
        s = ls[0][cl] + ls[1][cl] + ls[2][cl] + ls[3][cl];
        q = lq[0][cl] + lq[1][cl] + lq[2][cl] + lq[3][cl];
        atomicAdd(&sum[c], s);
        atomicAdd(&sumsq[c], q);
    }
}

// ===========================================================================
// LIF helpers (exact ref arithmetic, f64)
// ===========================================================================
__device__ __forceinline__ void lif2(double x0, double x1, bool& s0, bool& s1) {
    double v = x0 * 0.5;
    s0 = (v >= 1.0);
    v = s0 ? 0.0 : v;
    v = v + (x1 - v) * 0.5;
    s1 = (v >= 1.0);
}

__device__ __forceinline__ void bn_params(const double* sum, const double* sumsq,
                                          const float* g, const float* b, double invM,
                                          int c, double& sc, double& sh) {
    double m   = sum[c] * invM;
    double var = sumsq[c] * invM - m * m;
    sc = (double)g[c] / sqrt(var + 1e-5);
    sh = (double)b[c] - m * sc;
}

// BN + LIF over a full 512-col chunk (f32 activations) -> bits
__global__ __launch_bounds__(256)
void bn_lif_bits2(const float* __restrict__ X,
                  const double* __restrict__ sum, const double* __restrict__ sumsq,
                  const float* __restrict__ g, const float* __restrict__ b, double invM,
                  uint64_t* __restrict__ S, int osWords, int chOffWords) {
    int i = blockIdx.x * 256 + threadIdx.x;   // i < N*512
    int n = i >> 9, c = i & 511;
    double sc, sh;
    bn_params(sum, sumsq, g, b, invM, c, sc, sh);
    bool s0, s1;
    lif2((double)X[i] * sc + sh, (double)X[(size_t)i + (size_t)ND] * sc + sh, s0, s1);
    uint64_t b0 = __ballot(s0), b1 = __ballot(s1);
    if ((threadIdx.x & 63) == 0) {
        int widx = n * osWords + chOffWords + (c >> 6);
        S[widx] = b0;
        S[widx + N_NODES * osWords] = b1;
    }
}

// h += bn(X) over a full 512-col row (f32 H, f64 compute) AND emit lif(h) bits
__global__ __launch_bounds__(256)
void bn_add_lif2(const float* __restrict__ X,
                 const double* __restrict__ sum, const double* __restrict__ sumsq,
                 const float* __restrict__ g, const float* __restrict__ b, double invM,
                 float* __restrict__ H, uint64_t* __restrict__ S) {
    int i = blockIdx.x * 256 + threadIdx.x;   // i < N*512 (== n*512 + c)
    int n = i >> 9, c = i & 511;
    double sc, sh;
    bn_params(sum, sumsq, g, b, invM, c, sc, sh);
    double h0 = (double)H[i] + ((double)X[i] * sc + sh);
    double h1 = (double)H[(size_t)i + ND] + ((double)X[(size_t)i + ND] * sc + sh);
    H[i] = (float)h0;
    H[(size_t)i + ND] = (float)h1;
    bool s0, s1;
    lif2(h0, h1, s0, s1);
    uint64_t b0 = __ballot(s0), b1 = __ballot(s1);
    if ((threadIdx.x & 63) == 0) {
        int widx = n * 8 + (c >> 6);
        S[widx] = b0;
        S[widx + N_NODES * 8] = b1;
    }
}

// LayerNorm(512)+ReLU on fc0 output (f32); write both t-slices of h (f32) + lif bits
__global__ __launch_bounds__(256)
void ln_relu_lif(const float* __restrict__ X, const float* __restrict__ g,
                 const float* __restrict__ b, float* __restrict__ H,
                 uint64_t* __restrict__ S) {
    int n = blockIdx.x;
    const float* x = X + (size_t)n * 512;
    int c0 = threadIdx.x, c1 = threadIdx.x + 256;
    double v0 = (double)x[c0], v1 = (double)x[c1];
    __shared__ double ls[256], lq[256];
    ls[threadIdx.x] = v0 + v1;
    lq[threadIdx.x] = v0 * v0 + v1 * v1;
    __syncthreads();
    for (int off = 128; off > 0; off >>= 1) {
        if (threadIdx.x < off) {
            ls[threadIdx.x] += ls[threadIdx.x + off];
            lq[threadIdx.x] += lq[threadIdx.x + off];
        }
        __syncthreads();
    }
    double m    = ls[0] * (1.0 / 512);
    double var  = lq[0] * (1.0 / 512) - m * m;
    double rstd = 1.0 / sqrt(var + 1e-5);
    double o0 = (v0 - m) * rstd * (double)g[c0] + (double)b[c0];
    double o1 = (v1 - m) * rstd * (double)g[c1] + (double)b[c1];
    o0 = o0 > 0.0 ? o0 : 0.0;
    o1 = o1 > 0.0 ? o1 : 0.0;
    float* h0 = H + (size_t)n * 512;
    h0[c0] = (float)o0; h0[c1] = (float)o1;
    h0[ND + c0] = (float)o0; h0[ND + c1] = (float)o1;
    // lif with x0 == x1 == o
    bool a0, a1, d0, d1;
    lif2(o0, o0, a0, a1);
    lif2(o1, o1, d0, d1);
    uint64_t ba0 = __ballot(a0), ba1 = __ballot(a1);
    uint64_t bd0 = __ballot(d0), bd1 = __ballot(d1);
    if ((threadIdx.x & 63) == 0) {
        int w = threadIdx.x >> 6;
        S[n * 8 + w] = ba0;
        S[n * 8 + w + N_NODES * 8] = ba1;
        S[n * 8 + 4 + w] = bd0;
        S[n * 8 + 4 + w + N_NODES * 8] = bd1;
    }
}

// ===========================================================================
// Attention on bit spikes (integer-exact in fp32).
// ===========================================================================
__global__ __launch_bounds__(256)
void kv_bits(const uint64_t* __restrict__ Kb, const uint64_t* __restrict__ Vb,
             float* __restrict__ KV, int nPerBlock) {
    const int th = blockIdx.x;
    const int t = th >> 3, h = th & 7;
    const int nbase = blockIdx.y * nPerBlock;
    const int e = threadIdx.x & 63, dg = threadIdx.x >> 6;
    float acc[16];
#pragma unroll
    for (int i = 0; i < 16; i++) acc[i] = 0.f;
    __shared__ float ks[16][64], vs[16][64];
    const size_t wbase = (size_t)t * N_NODES * 8 + h;
    for (int n0 = 0; n0 < nPerBlock; n0 += 16) {
        for (int idx = threadIdx.x; idx < 16 * 128; idx += 256) {
            int r = idx >> 7, c = idx & 127;
            size_t wi = wbase + (size_t)(nbase + n0 + r) * 8;
            if (c < 64) ks[r][c] = (float)((Kb[wi] >> c) & 1ull);
            else        vs[r][c - 64] = (float)((Vb[wi] >> (c - 64)) & 1ull);
        }
        __syncthreads();
#pragma unroll
        for (int r = 0; r < 16; ++r) {
            float ve = vs[r][e];
#pragma unroll
            for (int i = 0; i < 16; ++i) acc[i] += ks[r][dg * 16 + i] * ve;
        }
        __syncthreads();
    }
    float* kvp = KV + (size_t)th * 4096;
    for (int i = 0; i < 16; ++i)
        atomicAdd(&kvp[(dg * 16 + i) * 64 + e], acc[i]);
}

// O = (Q @ KV) * 0.125 for BOTH timesteps, LIF in-register, emit bits.
__global__ __launch_bounds__(256)
void o_lif_bits(const uint64_t* __restrict__ Qb, const float* __restrict__ KV,
                uint64_t* __restrict__ S) {
    const int h  = blockIdx.y;     // 8 heads
    const int nb = blockIdx.x;     // N/64 row blocks
    __shared__ float kvs[64][64];
    __shared__ float qs[64][65];
    const int e = threadIdx.x & 63, rg = threadIdx.x >> 6;
    float acc0[16], acc1[16];
#pragma unroll
    for (int i = 0; i < 16; ++i) { acc0[i] = 0.f; acc1[i] = 0.f; }
#pragma unroll
    for (int t = 0; t < 2; ++t) {
        const float* kvp = KV + (size_t)(t * 8 + h) * 4096;
        for (int idx = threadIdx.x; idx < 4096; idx += 256)
            kvs[idx >> 6][idx & 63] = kvp[idx];
        const size_t wbase = ((size_t)t * N_NODES + (size_t)nb * 64) * 8 + h;
        for (int idx = threadIdx.x; idx < 4096; idx += 256) {
            int r = idx >> 6, c = idx & 63;
            qs[r][c] = (float)((Qb[wbase + (size_t)r * 8] >> c) & 1ull);
        }
        __syncthreads();
        float* acc = t == 0 ? acc0 : acc1;
        for (int d = 0; d < 64; ++d) {
            float kv = kvs[d][e];
#pragma unroll
            for (int i = 0; i < 16; ++i) acc[i] += qs[rg * 16 + i][d] * kv;
        }
        __syncthreads();   // LDS reloaded next t
    }
#pragma unroll
    for (int i = 0; i < 16; ++i) {
        float o0 = acc0[i] * 0.125f;
        float o1 = acc1[i] * 0.125f;
        bool s0, s1;
        lif2((double)o0, (double)o1, s0, s1);
        uint64_t b0 = __ballot(s0), b1 = __ballot(s1);
        if (e == 0) {
            size_t row = (size_t)nb * 64 + rg * 16 + i;
            S[row * 8 + h] = b0;
            S[row * 8 + h + (size_t)N_NODES * 8] = b1;
        }
    }
}

// ===========================================================================
// GNN branch (fp32)
// ===========================================================================
__global__ __launch_bounds__(256)
void deg_kernel(const int* __restrict__ col, float* __restrict__ deg, int E) {
    int e = blockIdx.x * 256 + threadIdx.x;
    if (e < E) atomicAdd(&deg[col[e]], 1.0f);
}

__global__ __launch_bounds__(256)
void dinv_kernel(float* __restrict__ deg, int n) {
    int i = blockIdx.x * 256 + threadIdx.x;
    if (i < n) {
        double d = (double)deg[i];
        deg[i] = d > 0.0 ? (float)(1.0 / sqrt(d)) : 0.f;
    }
}

// 40 threads per edge (no idle lanes)
__global__ __launch_bounds__(256)
void agg_kernel(const float* __restrict__ G, const int* __restrict__ row,
                const int* __restrict__ col, const float* __restrict__ dinv,
                float* __restrict__ out, int E) {
    int idx = blockIdx.x * 256 + threadIdx.x;
    int e = idx / C_OUT, c = idx - e * C_OUT;
    if (e >= E) return;
    int r = row[e], cl = col[e];
    float val = dinv[cl] * dinv[r];
    atomicAdd(&out[(size_t)cl * C_OUT + c], val * G[(size_t)r * C_OUT + c]);
}

__global__ __launch_bounds__(256)
void bn_relu_add_f2(const float* __restrict__ X,
                    const double* __restrict__ sum, const double* __restrict__ sumsq,
                    const float* __restrict__ g, const float* __restrict__ b, double invM,
                    const float* __restrict__ add, float* __restrict__ out, int NC, int Ch) {
    int i = blockIdx.x * 256 + threadIdx.x;
    if (i >= NC) return;
    int c = i % Ch;
    double sc, sh;
    bn_params(sum, sumsq, g, b, invM, c, sc, sh);
    double v = (double)X[i] * sc + sh;
    v = v > 0.0 ? v : 0.0;
    if (add) v += (double)add[i];
    out[i] = (float)v;
}

__global__ __launch_bounds__(256)
void mix_kernel(const float* __restrict__ G, const float* __restrict__ Y,
                float* __restrict__ P, int NC) {
    int i = blockIdx.x * 256 + threadIdx.x;
    if (i >= NC) return;
    double y = 0.5 * ((double)Y[i] + (double)Y[(size_t)i + NC]);
    P[i] = (float)(0.8 * (double)G[i] + 0.2 * y);
}

__global__ __launch_bounds__(256)
void final_fc_kernel(const float* __restrict__ A, const float* __restrict__ W,
                     const float* __restrict__ bias, float* __restrict__ out) {
    __shared__ float Ws[40][40];
    for (int idx = threadIdx.x; idx < 1600; idx += 256)
        Ws[idx / 40][idx % 40] = W[idx];
    __syncthreads();
    int i = blockIdx.x * 256 + threadIdx.x;
    if (i >= N_NODES * C_OUT) return;
    int n = i / 40, c = i - n * 40;
    const float* a = A + (size_t)n * 40;
    double acc = (double)bias[c];
#pragma unroll 8
    for (int k = 0; k < 40; ++k) acc += (double)a[k] * (double)Ws[k][c];
    out[i] = (float)acc;
}

// ===========================================================================
// Host orchestration
// ===========================================================================
static inline dim3 grid1(long n) { return dim3((unsigned)((n + 255) / 256)); }

extern "C" void kernel_launch(void* const* d_in, const int* in_sizes, int n_in,
                              void* d_out, int out_size, void* d_ws, size_t ws_size,
                              hipStream_t stream) {
    const float* x      = (const float*)d_in[0];
    const float* fc0_w  = (const float*)d_in[1];
    const float* fc0_b  = (const float*)d_in[2];
    const float* ln_g   = (const float*)d_in[3];
    const float* ln_b   = (const float*)d_in[4];
    const float* wq     = (const float*)d_in[5];
    const float* wk     = (const float*)d_in[6];
    const float* wv     = (const float*)d_in[7];
    const float* wo     = (const float*)d_in[8];
    const float* bnq_g  = (const float*)d_in[9];
    const float* bnq_b  = (const float*)d_in[10];
    const float* bnk_g  = (const float*)d_in[11];
    const float* bnk_b  = (const float*)d_in[12];
    const float* bnv_g  = (const float*)d_in[13];
    const float* bnv_b  = (const float*)d_in[14];
    const float* bno_g  = (const float*)d_in[15];
    const float* bno_b  = (const float*)d_in[16];
    const float* w1     = (const float*)d_in[17];
    const float* bn1_g  = (const float*)d_in[18];
    const float* bn1_b  = (const float*)d_in[19];
    const float* w2     = (const float*)d_in[20];
    const float* bn2_g  = (const float*)d_in[21];
    const float* bn2_b  = (const float*)d_in[22];
    const float* head_w = (const float*)d_in[23];
    const float* head_b = (const float*)d_in[24];
    const float* gfc_w  = (const float*)d_in[25];
    const float* gfc_b  = (const float*)d_in[26];
    const float* gbn0_g = (const float*)d_in[27];
    const float* gbn0_b = (const float*)d_in[28];
    const float* gconv_w= (const float*)d_in[29];
    const float* gconv_b= (const float*)d_in[30];
    const float* gbn_g  = (const float*)d_in[31];
    const float* gbn_b  = (const float*)d_in[32];
    const float* fc_w   = (const float*)d_in[33];
    const float* fc_b   = (const float*)d_in[34];
    const int*   edge   = (const int*)d_in[35];

    const int E = in_sizes[35] / 2;
    const int* erow = edge;
    const int* ecol = edge + E;
    const int NC = N_NODES * C_OUT;

    // ---- workspace layout (~170 MiB) ----
    uint8_t* wsbase = (uint8_t*)d_ws;
    size_t off = 0;
    auto alloc = [&](size_t bytes, size_t align) -> void* {
        off = (off + align - 1) & ~(align - 1);
        void* p = wsbase + off;
        off += bytes;
        return p;
    };
    double*   statBuf = (double*)alloc((size_t)64 * 1024 * sizeof(double), 256); // per-gate stats (512 sum + 512 sumsq)
    float*    h_buf  = (float*)alloc((size_t)2 * ND * sizeof(float), 256);       // 67 MB
    float*    Pf     = (float*)alloc((size_t)M2 * 512 * sizeof(float), 256);     // 67 MB
    uint8_t*  Wdig   = (uint8_t*)alloc((size_t)WD_TOTAL, 256);                   // 10.5 MB
    uint64_t* s_bits = (uint64_t*)alloc((size_t)2 * N_NODES * 8 * 8, 256);
    uint64_t* q_bits = (uint64_t*)alloc((size_t)2 * N_NODES * 8 * 8, 256);
    uint64_t* k_bits = (uint64_t*)alloc((size_t)2 * N_NODES * 8 * 8, 256);
    uint64_t* v_bits = (uint64_t*)alloc((size_t)2 * N_NODES * 8 * 8, 256);
    uint64_t* m_bits = (uint64_t*)alloc((size_t)2 * N_NODES * 16 * 8, 256);      // 4.2 MB
    float*    ybuf   = (float*)m_bits;  // alias: y written at head, after m_bits dead
    (void)alloc((size_t)2 * NC * sizeof(float) > (size_t)2 * N_NODES * 16 * 8
                ? (size_t)2 * NC * sizeof(float) - (size_t)2 * N_NODES * 16 * 8 : 0, 256);
    float*    g0     = (float*)alloc((size_t)NC * sizeof(float), 256);
    float*    gg     = (float*)alloc((size_t)NC * sizeof(float), 256);
    float*    ag     = (float*)alloc((size_t)NC * sizeof(float), 256);
    float*    kvb    = (float*)alloc((size_t)65536 * sizeof(float), 256);
    float*    deg    = (float*)alloc((size_t)N_NODES * sizeof(float), 256);
    if (off > ws_size) return;

    const dim3 blk(256);
    const dim3 gBN((unsigned)(2 * N_NODES));          // N*512/256
    const dim3 gGEMM(8, M2 / 128);                    // 512 cols per launch
    const double invM2 = 1.0 / (double)M2;
    const double invMN = 1.0 / (double)N_NODES;

    hipMemsetAsync(statBuf, 0, (size_t)64 * 1024 * sizeof(double), stream);

    int gate = 0;
    auto nextStat = [&]() { return statBuf + (size_t)(gate++) * 1024; };

    // ===== transformer branch =====
    hipLaunchKernelGGL(gemm_f32d, dim3(8, N_NODES / 64), blk, 0, stream,
                       x, 512, fc0_w, 512, fc0_b, Pf, 512, N_NODES, 512, 512);
    hipLaunchKernelGGL(ln_relu_lif, dim3(N_NODES), blk, 0, stream, Pf, ln_g, ln_b, h_buf, s_bits);

    for (int l = 0; l < 4; ++l) {
        // one prep launch for all 6 matrices of this layer
        hipLaunchKernelGGL(w_digits_layer, dim3(512), blk, 0, stream,
                           wq + (size_t)l * 262144, wk + (size_t)l * 262144,
                           wv + (size_t)l * 262144, wo + (size_t)l * 262144,
                           w1 + (size_t)l * 524288, w2 + (size_t)l * 524288, Wdig);

        uint64_t* qkvb[3] = {q_bits, k_bits, v_bits};
        const size_t wdoff[3] = {WD_Q, WD_K, WD_V};
        const float* gmat[3] = {bnq_g + l * 512, bnk_g + l * 512, bnv_g + l * 512};
        const float* bmat[3] = {bnq_b + l * 512, bnk_b + l * 512, bnv_b + l * 512};
        for (int j = 0; j < 3; ++j) {
            double* st = nextStat();
            hipLaunchKernelGGL(gemm_i8_bits, gGEMM, blk, 0, stream,
                               s_bits, 8, Wdig + wdoff[j], 512, 0, Pf, 512, 512, st, st + 512);
            hipLaunchKernelGGL(bn_lif_bits2, gBN, blk, 0, stream,
                               Pf, st, st + 512, gmat[j], bmat[j], invM2, qkvb[j], 8, 0);
        }

        // attention (exact); fused O-proj input: lif(o) bits -> q_bits in place
        hipMemsetAsync(kvb, 0, 65536 * sizeof(float), stream);
        hipLaunchKernelGGL(kv_bits, dim3(16, 16), blk, 0, stream, k_bits, v_bits, kvb, 1024);
        hipLaunchKernelGGL(o_lif_bits, dim3(N_NODES / 64, 8), blk, 0, stream, q_bits, kvb, q_bits);

        // h += bn(lif(o) @ wo); emit s = lif(h_new) into s_bits
        {
            double* st = nextStat();
            hipLaunchKernelGGL(gemm_i8_bits, gGEMM, blk, 0, stream,
                               q_bits, 8, Wdig + WD_O, 512, 0, Pf, 512, 512, st, st + 512);
            hipLaunchKernelGGL(bn_add_lif2, gBN, blk, 0, stream,
                               Pf, st, st + 512, bno_g + l * 512, bno_b + l * 512,
                               invM2, h_buf, s_bits);
        }

        // MLP: m = lif(bn1(s @ w1)) in 2 chunks of 512
        for (int c0 = 0; c0 < 1024; c0 += 512) {
            double* st = nextStat();
            hipLaunchKernelGGL(gemm_i8_bits, gGEMM, blk, 0, stream,
                               s_bits, 8, Wdig + WD_1, 1024, c0, Pf, 512, 512, st, st + 512);
            hipLaunchKernelGGL(bn_lif_bits2, gBN, blk, 0, stream,
                               Pf, st, st + 512, bn1_g + l * 1024 + c0, bn1_b + l * 1024 + c0,
                               invM2, m_bits, 16, c0 / 64);
        }
        // h += bn2(m @ w2); emit s = lif(h_new) for next layer / head
        {
            double* st = nextStat();
            hipLaunchKernelGGL(gemm_i8_bits, gGEMM, blk, 0, stream,
                               m_bits, 16, Wdig + WD_2, 512, 0, Pf, 512, 1024, st, st + 512);
            hipLaunchKernelGGL(bn_add_lif2, gBN, blk, 0, stream,
                               Pf, st, st + 512, bn2_g + l * 512, bn2_b + l * 512,
                               invM2, h_buf, s_bits);
        }
    }

    // head: y = s @ head_w + head_b (s_bits already = lif(h_final))
    hipLaunchKernelGGL(head_gather, dim3(M2 / 4), blk, 0, stream, s_bits, head_w, head_b, ybuf);

    // ===== GNN branch (fp32) =====
    hipLaunchKernelGGL(gemm_f32, dim3(1, N_NODES / 64), blk, 0, stream,
                       x, 512, gfc_w, 40, gfc_b, ag, 40, N_NODES, 40, 512);
    {
        double* st = nextStat();
        dim3 gs(1, (N_NODES + 511) / 512);
        hipLaunchKernelGGL(col_stats_f, gs, blk, 0, stream, ag, N_NODES, 40, 512, st, st + 512);
        hipLaunchKernelGGL(bn_relu_add_f2, grid1(NC), blk, 0, stream,
                           ag, st, st + 512, gbn0_g, gbn0_b, invMN,
                           (const float*)nullptr, g0, NC, 40);
    }

    hipMemsetAsync(deg, 0, N_NODES * sizeof(float), stream);
    hipLaunchKernelGGL(deg_kernel, grid1(E), blk, 0, stream, ecol, deg, E);
    hipLaunchKernelGGL(dinv_kernel, grid1(N_NODES), blk, 0, stream, deg, N_NODES);

    const float* gsrc = g0;
    for (int i = 0; i < 2; ++i) {
        hipMemsetAsync(ag, 0, (size_t)NC * sizeof(float), stream);
        hipLaunchKernelGGL(agg_kernel, grid1((long)E * C_OUT), blk, 0, stream,
                           gsrc, erow, ecol, deg, ag, E);
        hipLaunchKernelGGL(gemm_f32, dim3(1, N_NODES / 64), blk, 0, stream,
                           ag, 40, gconv_w + (size_t)i * 40 * 40, 40, gconv_b + i * 40,
                           gg, 40, N_NODES, 40, 40);
        double* st = nextStat();
        dim3 gs(1, (N_NODES + 511) / 512);
        hipLaunchKernelGGL(col_stats_f, gs, blk, 0, stream, gg, N_NODES, 40, 512, st, st + 512);
        hipLaunchKernelGGL(bn_relu_add_f2, grid1(NC), blk, 0, stream,
                           gg, st, st + 512, gbn_g + i * 40, gbn_b + i * 40, invMN, g0, gg, NC, 40);
        gsrc = gg;
    }

    // out = (0.8*g + 0.2*mean_t(y)) @ fc_w + fc_b
    hipLaunchKernelGGL(mix_kernel, grid1(NC), blk, 0, stream, gg, ybuf, ag, NC);
    hipLaunchKernelGGL(final_fc_kernel, grid1((long)N_NODES * C_OUT), blk, 0, stream,
                       ag, fc_w, fc_b, (float*)d_out);
}

// Round 7
// 5764.698 us; speedup vs baseline: 2.2632x; 1.0087x over previous
//
#include <hip/hip_runtime.h>
#include <cstddef>
#include <cstdint>

constexpr int N_NODES = 16384;
constexpr int D_MODEL = 512;
constexpr int C_OUT   = 40;
constexpr int ND      = N_NODES * D_MODEL;   // per-timestep elements (512-ch)
constexpr int M2      = 2 * N_NODES;         // T*N rows

typedef int i32x4 __attribute__((ext_vector_type(4)));

// digit scales: w ≈ Σ d_j * S_j, residual ≤ 2^-38 (5 digits)
#define S0 0.001953125                      // 2^-9
#define S1 1.52587890625e-05                // 2^-16
#define S2 1.1920928955078125e-07           // 2^-23
#define S3 9.31322574615478515625e-10       // 2^-30
#define S4 7.2759576141834259033203125e-12  // 2^-37

// digit-plane offsets within the per-layer buffer (bytes)
#define WD_Q 0
#define WD_K 1310720
#define WD_V 2621440
#define WD_O 3932160
#define WD_1 5242880
#define WD_2 7864320
#define WD_TOTAL 10485760

// LDS ktile stride: 5120 data bytes + 32 pad -> q-groups land on distinct
// bank offsets (+8 banks per q). Kills the 8-way ds_read_b128 conflict
// (banks were (20m mod 32, period 8) x (all q aliased); now only the free
// 2-way m/m+8 alias remains).
#define KT_STRIDE 5152

// ===========================================================================
// Per-layer weight -> 5 signed-i8 digit planes in MFMA B-fragment order:
// byte at ((k/16)*N + n)*80 + j*16 + (k%16).
// ===========================================================================
__global__ __launch_bounds__(256)
void w_digits_layer(const float* __restrict__ wq, const float* __restrict__ wk,
                    const float* __restrict__ wv, const float* __restrict__ wo,
                    const float* __restrict__ w1, const float* __restrict__ w2,
                    uint8_t* __restrict__ Wd) {
    int idx = blockIdx.x * 256 + threadIdx.x;   // [0, 131072)
    const float* W;
    uint8_t* outb;
    int N, rem;
    if (idx < 65536) {                          // wq,wk,wv,wo: 4 x (32 kg x 512 n)
        int mm = idx >> 14;
        rem = idx & 16383;
        const float* ptrs[4] = {wq, wk, wv, wo};
        W = ptrs[mm]; outb = Wd + (size_t)mm * 1310720; N = 512;
    } else if (idx < 98304) {                   // w1: 32 kg x 1024 n
        rem = idx - 65536; W = w1; outb = Wd + WD_1; N = 1024;
    } else {                                    // w2: 64 kg x 512 n
        rem = idx - 98304; W = w2; outb = Wd + WD_2; N = 512;
    }
    int kg = rem / N, n = rem - kg * N;
    const float* Wp = W + (size_t)kg * 16 * N + n;
    uint8_t* out = outb + (size_t)(kg * N + n) * 80;
    const double scl[5] = {512.0, 65536.0, 8388608.0, 1073741824.0, 137438953472.0};
    const double inv[5] = {S0, S1, S2, S3, S4};
    union { uint8_t b[5][16]; i32x4 v[5]; } db;
#pragma unroll
    for (int kk = 0; kk < 16; ++kk) {
        double r = (double)Wp[(size_t)kk * N];
#pragma unroll
        for (int j = 0; j < 5; ++j) {
            int d = (int)rint(r * scl[j]);
            d = d > 127 ? 127 : (d < -127 ? -127 : d);
            r -= (double)d * inv[j];
            db.b[j][kk] = (uint8_t)(int8_t)d;
        }
    }
#pragma unroll
    for (int j = 0; j < 5; ++j)
        *reinterpret_cast<i32x4*>(out + j * 16) = db.v[j];
}

// ===========================================================================
// Spike GEMM via i8 MFMA, exact fixed-point. 128-row blocks, LDS-staged B
// with bank-conflict-free ktile padding. BN stats in f64 from exact p;
// activation stored f32.
// ===========================================================================
__global__ __launch_bounds__(256)
void gemm_i8_bits(const uint64_t* __restrict__ bits, int kWords,
                  const uint8_t* __restrict__ Wd, int Nmat, int colOff,
                  float* __restrict__ C, int ldc, int K,
                  double* __restrict__ sum, double* __restrict__ sumsq) {
    __shared__ __attribute__((aligned(16))) uint8_t Bs[4 * KT_STRIDE];
    const int lane = threadIdx.x & 63;
    const int wv   = threadIdx.x >> 6;
    const int m    = lane & 15;
    const int q    = lane >> 4;
    const int rowT = blockIdx.y * 128 + wv * 32;   // this wave's 32-row tile
    const int colB = blockIdx.x * 64;

    i32x4 acc[2][4][5];
#pragma unroll
    for (int rt = 0; rt < 2; ++rt)
#pragma unroll
        for (int t = 0; t < 4; ++t)
#pragma unroll
            for (int j = 0; j < 5; ++j) acc[rt][t][j] = (i32x4){0, 0, 0, 0};

    const uint64_t* brow0 = bits + (size_t)(rowT + m) * kWords;
    const uint64_t* brow1 = brow0 + (size_t)16 * kWords;
    const size_t cb = (size_t)(colOff + colB);

    for (int kb = 0; kb < K; kb += 64) {
        // --- load the 4-ktile x 64-col x 80B digit tile (20KB) to registers ---
        i32x4 tmp[5];
        const size_t kt0 = (size_t)(kb >> 4);
#pragma unroll
        for (int c5 = 0; c5 < 5; ++c5) {
            int c  = threadIdx.x + c5 * 256;       // [0,1280) 16B chunks
            int kt = c / 320;                      // ktile (5120B data each)
            int of = c - kt * 320;
            tmp[c5] = *reinterpret_cast<const i32x4*>(
                Wd + ((kt0 + (size_t)kt) * Nmat + cb) * 80 + (size_t)of * 16);
        }
        // --- A spike fragments for both row-tiles ---
        uint64_t wb0 = brow0[kb >> 6];
        uint64_t wb1 = brow1[kb >> 6];
        uint32_t hw0 = (uint32_t)(wb0 >> (q * 16)) & 0xFFFFu;
        uint32_t hw1 = (uint32_t)(wb1 >> (q * 16)) & 0xFFFFu;
        i32x4 af0, af1;
#pragma unroll
        for (int i = 0; i < 4; ++i) {
            af0[i] = (int)((((hw0 >> (4 * i)) & 0xFu) * 0x00204081u) & 0x01010101u);
            af1[i] = (int)((((hw1 >> (4 * i)) & 0xFu) * 0x00204081u) & 0x01010101u);
        }
        __syncthreads();                 // previous tile fully consumed
#pragma unroll
        for (int c5 = 0; c5 < 5; ++c5) {
            int c  = threadIdx.x + c5 * 256;
            int kt = c / 320;
            int of = c - kt * 320;
            *reinterpret_cast<i32x4*>(Bs + kt * KT_STRIDE + of * 16) = tmp[c5];
        }
        __syncthreads();                 // tile staged
#pragma unroll
        for (int t = 0; t < 4; ++t) {
            const uint8_t* bt = Bs + q * KT_STRIDE + (t * 16 + m) * 80;
            i32x4 bf[5];
#pragma unroll
            for (int j = 0; j < 5; ++j)
                bf[j] = *reinterpret_cast<const i32x4*>(bt + j * 16);
#pragma unroll
            for (int j = 0; j < 5; ++j) {
                acc[0][t][j] = __builtin_amdgcn_mfma_i32_16x16x64_i8(af0, bf[j], acc[0][t][j], 0, 0, 0);
                acc[1][t][j] = __builtin_amdgcn_mfma_i32_16x16x64_i8(af1, bf[j], acc[1][t][j], 0, 0, 0);
            }
        }
    }

    double sarr[4], qarr[4];
#pragma unroll
    for (int t = 0; t < 4; ++t) { sarr[t] = 0.0; qarr[t] = 0.0; }
#pragma unroll
    for (int rt = 0; rt < 2; ++rt) {
        const int orow = rowT + rt * 16 + q * 4;
#pragma unroll
        for (int t = 0; t < 4; ++t) {
            float* Cc = C + (size_t)orow * ldc + colB + t * 16 + m;
#pragma unroll
            for (int i = 0; i < 4; ++i) {
                double p = (double)acc[rt][t][0][i] * S0 + (double)acc[rt][t][1][i] * S1
                         + (double)acc[rt][t][2][i] * S2 + (double)acc[rt][t][3][i] * S3
                         + (double)acc[rt][t][4][i] * S4;
                Cc[(size_t)i * ldc] = (float)p;
                sarr[t] += p; qarr[t] += p * p;
            }
        }
    }
    __shared__ double ls[4][64], lq[4][64];
#pragma unroll
    for (int t = 0; t < 4; ++t) {
        double s = sarr[t], qq = qarr[t];
        s  += __shfl_xor(s, 16);  s  += __shfl_xor(s, 32);
        qq += __shfl_xor(qq, 16); qq += __shfl_xor(qq, 32);
        if (lane < 16) { ls[wv][t * 16 + lane] = s; lq[wv][t * 16 + lane] = qq; }
    }
    __syncthreads();
    if (threadIdx.x < 64) {
        int t = threadIdx.x;
        double s  = ls[0][t] + ls[1][t] + ls[2][t] + ls[3][t];
        double qq = lq[0][t] + lq[1][t] + lq[2][t] + lq[3][t];
        atomicAdd(&sum[colB + t], s);
        atomicAdd(&sumsq[colB + t], qq);
    }
}

// head GEMM: exact f64 gather (immune to any MFMA layout quirk)
__global__ __launch_bounds__(256)
void head_gather(const uint64_t* __restrict__ bits, const float* __restrict__ W,
                 const float* __restrict__ bias, float* __restrict__ Y) {
    const int lane = threadIdx.x & 63;
    const int wid  = threadIdx.x >> 6;
    const int r = blockIdx.x * 4 + wid;
    if (lane >= C_OUT) return;
    double acc = (double)bias[lane];
    const uint64_t* bw = bits + (size_t)r * 8;
    for (int j = 0; j < 8; ++j) {
        uint64_t w = bw[j];
        const float* Wk = W + (size_t)j * 64 * C_OUT + lane;
        while (w) {
            int k = __builtin_ctzll(w);
            w &= w - 1;
            acc += (double)Wk[(size_t)k * C_OUT];
        }
    }
    Y[(size_t)r * C_OUT + lane] = (float)acc;
}

// GEMM (float A, float out, f64 acc) — fc0 only. Swizzled f32 LDS (R2-proven).
__global__ __launch_bounds__(256)
void gemm_f32d(const float* __restrict__ A, int lda,
               const float* __restrict__ B, int ldb,
               const float* __restrict__ bias,
               float* __restrict__ C, int ldc, int M, int Nc, int K) {
    __shared__ float As[16][64];
    __shared__ float Bs[16][64];
    const int tid = threadIdx.x;
    const int tx  = tid & 15, ty = tid >> 4;
    const int row0 = blockIdx.y * 64 + ty * 4;
    const int col0 = blockIdx.x * 64 + tx * 4;
    const int ar = tid >> 2, ak = (tid & 3) * 4;   // A: row ar, k ak..ak+3
    const int bk = tid >> 4, bn = (tid & 15) * 4;  // B: k-row bk, cols bn..bn+3
    const int gm = blockIdx.y * 64 + ar;
    double acc[4][4];
#pragma unroll
    for (int i = 0; i < 4; i++)
#pragma unroll
        for (int j = 0; j < 4; j++) acc[i][j] = 0.0;
    for (int k0 = 0; k0 < K; k0 += 16) {
        float4 av = *reinterpret_cast<const float4*>(&A[(size_t)gm * lda + k0 + ak]);
        const float* avp = reinterpret_cast<const float*>(&av);
#pragma unroll
        for (int j = 0; j < 4; j++)
            As[ak + j][ar ^ ((ak + j) & 12)] = avp[j];
        float4 bv = *reinterpret_cast<const float4*>(
            &B[(size_t)(k0 + bk) * ldb + blockIdx.x * 64 + bn]);
        *reinterpret_cast<float4*>(&Bs[bk][bn ^ ((bk & 3) << 2)]) = bv;
        __syncthreads();
#pragma unroll
        for (int kk = 0; kk < 16; kk++) {
            float4 a4 = *reinterpret_cast<const float4*>(&As[kk][(ty * 4) ^ (kk & 12)]);
            float4 b4 = *reinterpret_cast<const float4*>(&Bs[kk][(tx * 4) ^ ((kk & 3) << 2)]);
            const float* ap = reinterpret_cast<const float*>(&a4);
            const float* bp = reinterpret_cast<const float*>(&b4);
#pragma unroll
            for (int i = 0; i < 4; i++)
#pragma unroll
                for (int j = 0; j < 4; j++)
                    acc[i][j] = fma((double)ap[i], (double)bp[j], acc[i][j]);
        }
        __syncthreads();
    }
#pragma unroll
    for (int i = 0; i < 4; i++) {
        int r = row0 + i;
        if (r >= M) continue;
#pragma unroll
        for (int j = 0; j < 4; j++) {
            int c = col0 + j;
            if (c < Nc) {
                double v = acc[i][j];
                if (bias) v += (double)bias[c];
                C[(size_t)r * ldc + c] = (float)v;
            }
        }
    }
}

// GEMM (float A/B/C, double acc) — GNN branch.
__global__ __launch_bounds__(256)
void gemm_f32(const float* __restrict__ A, int lda,
              const float* __restrict__ B, int ldb,
              const float* __restrict__ bias,
              float* __restrict__ C, int ldc, int M, int Nc, int K) {
    __shared__ float As[16][64];
    __shared__ float Bs[16][64];
    const int tid = threadIdx.x;
    const int tx  = tid & 15, ty = tid >> 4;
    const int row0 = blockIdx.y * 64 + ty * 4;
    const int col0 = blockIdx.x * 64 + tx * 4;
    const int ar = tid >> 2, ak = (tid & 3) * 4;
    const int bk = tid >> 4, bn = (tid & 15) * 4;
    const int gm = blockIdx.y * 64 + ar;
    double acc[4][4];
#pragma unroll
    for (int i = 0; i < 4; i++)
#pragma unroll
        for (int j = 0; j < 4; j++) acc[i][j] = 0.0;
    for (int k0 = 0; k0 < K; k0 += 16) {
#pragma unroll
        for (int j = 0; j < 4; j++) {
            int kk = k0 + ak + j;
            As[ak + j][ar] = (gm < M && kk < K) ? A[(size_t)gm * lda + kk] : 0.f;
        }
#pragma unroll
        for (int j = 0; j < 4; j++) {
            int gn = blockIdx.x * 64 + bn + j;
            int kk = k0 + bk;
            Bs[bk][bn + j] = (gn < Nc && kk < K) ? B[(size_t)kk * ldb + gn] : 0.f;
        }
        __syncthreads();
#pragma unroll
        for (int kk = 0; kk < 16; kk++) {
            float a4[4], b4[4];
#pragma unroll
            for (int i = 0; i < 4; i++) a4[i] = As[kk][ty * 4 + i];
#pragma unroll
            for (int j = 0; j < 4; j++) b4[j] = Bs[kk][tx * 4 + j];
#pragma unroll
            for (int i = 0; i < 4; i++)
#pragma unroll
                for (int j = 0; j < 4; j++) acc[i][j] = fma((double)a4[i], (double)b4[j], acc[i][j]);
        }
        __syncthreads();
    }
#pragma unroll
    for (int i = 0; i < 4; i++) {
        int r = row0 + i;
        if (r >= M) continue;
#pragma unroll
        for (int j = 0; j < 4; j++) {
            int c = col0 + j;
            if (c < Nc) {
                double v = acc[i][j];
                if (bias) v += (double)bias[c];
                C[(size_t)r * ldc + c] = (float)v;
            }
        }
    }
}

// BN stats for fp32 inputs (GNN branch) -> per-gate buffers
__global__ __launch_bounds__(256)
void col_stats_f(const float* __restrict__ X, int M, int Ch, int rowsPerBlock,
                 double* __restrict__ sum, double* __restrict__ sumsq) {
    const int cl = threadIdx.x & 63;
    const int c  = blockIdx.x * 64 + cl;
    const int rg = threadIdx.x >> 6;
    const int r0 = blockIdx.y * rowsPerBlock;
    const int r1 = min(r0 + rowsPerBlock, M);
    double s = 0.0, q = 0.0;
    if (c < Ch) {
        for (int r = r0 + rg; r < r1; r += 4) {
            double v = (double)X[(size_t)r * Ch + c];
            s += v; q += v * v;
        }
    }
    __shared__ double ls[4][64], lq[4][64];
    ls[rg][cl] = s; lq[rg][cl] = q;
    __syncthreads();
    if (rg == 0 && c < Ch) {
        s = ls[0][cl] + ls[1][cl] + ls[2][cl] + ls[3][cl];
        q = lq[0][cl] + lq[1][cl] + lq[2][cl] + lq[3][cl];
        atomicAdd(&sum[c], s);
        atomicAdd(&sumsq[c], q);
    }
}

// ===========================================================================
// LIF helpers (exact ref arithmetic, f64)
// ===========================================================================
__device__ __forceinline__ void lif2(double x0, double x1, bool& s0, bool& s1) {
    double v = x0 * 0.5;
    s0 = (v >= 1.0);
    v = s0 ? 0.0 : v;
    v = v + (x1 - v) * 0.5;
    s1 = (v >= 1.0);
}

__device__ __forceinline__ void bn_params(const double* sum, const double* sumsq,
                                          const float* g, const float* b, double invM,
                                          int c, double& sc, double& sh) {
    double m   = sum[c] * invM;
    double var = sumsq[c] * invM - m * m;
    sc = (double)g[c] / sqrt(var + 1e-5);
    sh = (double)b[c] - m * sc;
}

// BN + LIF over a full chunk of (1<<chBits) cols (f32 activations) -> bits
__global__ __launch_bounds__(256)
void bn_lif_bits2(const float* __restrict__ X,
                  const double* __restrict__ sum, const double* __restrict__ sumsq,
                  const float* __restrict__ g, const float* __restrict__ b, double invM,
                  uint64_t* __restrict__ S, int chBits, int osWords) {
    int i = blockIdx.x * 256 + threadIdx.x;   // i < N << chBits
    int n = i >> chBits, c = i & ((1 << chBits) - 1);
    double sc, sh;
    bn_params(sum, sumsq, g, b, invM, c, sc, sh);
    bool s0, s1;
    lif2((double)X[i] * sc + sh,
         (double)X[(size_t)i + ((size_t)N_NODES << chBits)] * sc + sh, s0, s1);
    uint64_t b0 = __ballot(s0), b1 = __ballot(s1);
    if ((threadIdx.x & 63) == 0) {
        int widx = n * osWords + (c >> 6);
        S[widx] = b0;
        S[widx + N_NODES * osWords] = b1;
    }
}

// h += bn(X) over a full 512-col row (f32 H, f64 compute) AND emit lif(h) bits
__global__ __launch_bounds__(256)
void bn_add_lif2(const float* __restrict__ X,
                 const double* __restrict__ sum, const double* __restrict__ sumsq,
                 const float* __restrict__ g, const float* __restrict__ b, double invM,
                 float* __restrict__ H, uint64_t* __restrict__ S) {
    int i = blockIdx.x * 256 + threadIdx.x;   // i < N*512 (== n*512 + c)
    int n = i >> 9, c = i & 511;
    double sc, sh;
    bn_params(sum, sumsq, g, b, invM, c, sc, sh);
    double h0 = (double)H[i] + ((double)X[i] * sc + sh);
    double h1 = (double)H[(size_t)i + ND] + ((double)X[(size_t)i + ND] * sc + sh);
    H[i] = (float)h0;
    H[(size_t)i + ND] = (float)h1;
    bool s0, s1;
    lif2(h0, h1, s0, s1);
    uint64_t b0 = __ballot(s0), b1 = __ballot(s1);
    if ((threadIdx.x & 63) == 0) {
        int widx = n * 8 + (c >> 6);
        S[widx] = b0;
        S[widx + N_NODES * 8] = b1;
    }
}

// LayerNorm(512)+ReLU on fc0 output (f32); write both t-slices of h (f32) + lif bits
__global__ __launch_bounds__(256)
void ln_relu_lif(const float* __restrict__ X, const float* __restrict__ g,
                 const float* __restrict__ b, float* __restrict__ H,
                 uint64_t* __restrict__ S) {
    int n = blockIdx.x;
    const float* x = X + (size_t)n * 512;
    int c0 = threadIdx.x, c1 = threadIdx.x + 256;
    double v0 = (double)x[c0], v1 = (double)x[c1];
    __shared__ double ls[256], lq[256];
    ls[threadIdx.x] = v0 + v1;
    lq[threadIdx.x] = v0 * v0 + v1 * v1;
    __syncthreads();
    for (int off = 128; off > 0; off >>= 1) {
        if (threadIdx.x < off) {
            ls[threadIdx.x] += ls[threadIdx.x + off];
            lq[threadIdx.x] += lq[threadIdx.x + off];
        }
        __syncthreads();
    }
    double m    = ls[0] * (1.0 / 512);
    double var  = lq[0] * (1.0 / 512) - m * m;
    double rstd = 1.0 / sqrt(var + 1e-5);
    double o0 = (v0 - m) * rstd * (double)g[c0] + (double)b[c0];
    double o1 = (v1 - m) * rstd * (double)g[c1] + (double)b[c1];
    o0 = o0 > 0.0 ? o0 : 0.0;
    o1 = o1 > 0.0 ? o1 : 0.0;
    float* h0 = H + (size_t)n * 512;
    h0[c0] = (float)o0; h0[c1] = (float)o1;
    h0[ND + c0] = (float)o0; h0[ND + c1] = (float)o1;
    // lif with x0 == x1 == o
    bool a0, a1, d0, d1;
    lif2(o0, o0, a0, a1);
    lif2(o1, o1, d0, d1);
    uint64_t ba0 = __ballot(a0), ba1 = __ballot(a1);
    uint64_t bd0 = __ballot(d0), bd1 = __ballot(d1);
    if ((threadIdx.x & 63) == 0) {
        int w = threadIdx.x >> 6;
        S[n * 8 + w] = ba0;
        S[n * 8 + w + N_NODES * 8] = ba1;
        S[n * 8 + 4 + w] = bd0;
        S[n * 8 + 4 + w + N_NODES * 8] = bd1;
    }
}

// ===========================================================================
// Attention on bit spikes (integer-exact in fp32).
// ===========================================================================
__global__ __launch_bounds__(256)
void kv_bits(const uint64_t* __restrict__ Kb, const uint64_t* __restrict__ Vb,
             float* __restrict__ KV, int nPerBlock) {
    const int th = blockIdx.x;
    const int t = th >> 3, h = th & 7;
    const int nbase = blockIdx.y * nPerBlock;
    const int e = threadIdx.x & 63, dg = threadIdx.x >> 6;
    float acc[16];
#pragma unroll
    for (int i = 0; i < 16; i++) acc[i] = 0.f;
    __shared__ float ks[16][64], vs[16][64];
    const size_t wbase = (size_t)t * N_NODES * 8 + h;
    for (int n0 = 0; n0 < nPerBlock; n0 += 16) {
        for (int idx = threadIdx.x; idx < 16 * 128; idx += 256) {
            int r = idx >> 7, c = idx & 127;
            size_t wi = wbase + (size_t)(nbase + n0 + r) * 8;
            if (c < 64) ks[r][c] = (float)((Kb[wi] >> c) & 1ull);
            else        vs[r][c - 64] = (float)((Vb[wi] >> (c - 64)) & 1ull);
        }
        __syncthreads();
#pragma unroll
        for (int r = 0; r < 16; ++r) {
            float ve = vs[r][e];
#pragma unroll
            for (int i = 0; i < 16; ++i) acc[i] += ks[r][dg * 16 + i] * ve;
        }
        __syncthreads();
    }
    float* kvp = KV + (size_t)th * 4096;
    for (int i = 0; i < 16; ++i)
        atomicAdd(&kvp[(dg * 16 + i) * 64 + e], acc[i]);
}

// O = (Q @ KV) * 0.125 for BOTH timesteps, LIF in-register, emit bits.
__global__ __launch_bounds__(256)
void o_lif_bits(const uint64_t* __restrict__ Qb, const float* __restrict__ KV,
                uint64_t* __restrict__ S) {
    const int h  = blockIdx.y;     // 8 heads
    const int nb = blockIdx.x;     // N/64 row blocks
    __shared__ float kvs[64][64];
    __shared__ float qs[64][65];
    const int e = threadIdx.x & 63, rg = threadIdx.x >> 6;
    float acc0[16], acc1[16];
#pragma unroll
    for (int i = 0; i < 16; ++i) { acc0[i] = 0.f; acc1[i] = 0.f; }
#pragma unroll
    for (int t = 0; t < 2; ++t) {
        const float* kvp = KV + (size_t)(t * 8 + h) * 4096;
        for (int idx = threadIdx.x; idx < 4096; idx += 256)
            kvs[idx >> 6][idx & 63] = kvp[idx];
        const size_t wbase = ((size_t)t * N_NODES + (size_t)nb * 64) * 8 + h;
        for (int idx = threadIdx.x; idx < 4096; idx += 256) {
            int r = idx >> 6, c = idx & 63;
            qs[r][c] = (float)((Qb[wbase + (size_t)r * 8] >> c) & 1ull);
        }
        __syncthreads();
        float* acc = t == 0 ? acc0 : acc1;
        for (int d = 0; d < 64; ++d) {
            float kv = kvs[d][e];
#pragma unroll
            for (int i = 0; i < 16; ++i) acc[i] += qs[rg * 16 + i][d] * kv;
        }
        __syncthreads();   // LDS reloaded next t
    }
#pragma unroll
    for (int i = 0; i < 16; ++i) {
        float o0 = acc0[i] * 0.125f;
        float o1 = acc1[i] * 0.125f;
        bool s0, s1;
        lif2((double)o0, (double)o1, s0, s1);
        uint64_t b0 = __ballot(s0), b1 = __ballot(s1);
        if (e == 0) {
            size_t row = (size_t)nb * 64 + rg * 16 + i;
            S[row * 8 + h] = b0;
            S[row * 8 + h + (size_t)N_NODES * 8] = b1;
        }
    }
}

// ===========================================================================
// GNN branch (fp32)
// ===========================================================================
__global__ __launch_bounds__(256)
void deg_kernel(const int* __restrict__ col, float* __restrict__ deg, int E) {
    int e = blockIdx.x * 256 + threadIdx.x;
    if (e < E) atomicAdd(&deg[col[e]], 1.0f);
}

__global__ __launch_bounds__(256)
void dinv_kernel(float* __restrict__ deg, int n) {
    int i = blockIdx.x * 256 + threadIdx.x;
    if (i < n) {
        double d = (double)deg[i];
        deg[i] = d > 0.0 ? (float)(1.0 / sqrt(d)) : 0.f;
    }
}

// 40 threads per edge (no idle lanes)
__global__ __launch_bounds__(256)
void agg_kernel(const float* __restrict__ G, const int* __restrict__ row,
                const int* __restrict__ col, const float* __restrict__ dinv,
                float* __restrict__ out, int E) {
    int idx = blockIdx.x * 256 + threadIdx.x;
    int e = idx / C_OUT, c = idx - e * C_OUT;
    if (e >= E) return;
    int r = row[e], cl = col[e];
    float val = dinv[cl] * dinv[r];
    atomicAdd(&out[(size_t)cl * C_OUT + c], val * G[(size_t)r * C_OUT + c]);
}

__global__ __launch_bounds__(256)
void bn_relu_add_f2(const float* __restrict__ X,
                    const double* __restrict__ sum, const double* __restrict__ sumsq,
                    const float* __restrict__ g, const float* __restrict__ b, double invM,
                    const float* __restrict__ add, float* __restrict__ out, int NC, int Ch) {
    int i = blockIdx.x * 256 + threadIdx.x;
    if (i >= NC) return;
    int c = i % Ch;
    double sc, sh;
    bn_params(sum, sumsq, g, b, invM, c, sc, sh);
    double v = (double)X[i] * sc + sh;
    v = v > 0.0 ? v : 0.0;
    if (add) v += (double)add[i];
    out[i] = (float)v;
}

__global__ __launch_bounds__(256)
void mix_kernel(const float* __restrict__ G, const float* __restrict__ Y,
                float* __restrict__ P, int NC) {
    int i = blockIdx.x * 256 + threadIdx.x;
    if (i >= NC) return;
    double y = 0.5 * ((double)Y[i] + (double)Y[(size_t)i + NC]);
    P[i] = (float)(0.8 * (double)G[i] + 0.2 * y);
}

__global__ __launch_bounds__(256)
void final_fc_kernel(const float* __restrict__ A, const float* __restrict__ W,
                     const float* __restrict__ bias, float* __restrict__ out) {
    __shared__ float Ws[40][40];
    for (int idx = threadIdx.x; idx < 1600; idx += 256)
        Ws[idx / 40][idx % 40] = W[idx];
    __syncthreads();
    int i = blockIdx.x * 256 + threadIdx.x;
    if (i >= N_NODES * C_OUT) return;
    int n = i / 40, c = i - n * 40;
    const float* a = A + (size_t)n * 40;
    double acc = (double)bias[c];
#pragma unroll 8
    for (int k = 0; k < 40; ++k) acc += (double)a[k] * (double)Ws[k][c];
    out[i] = (float)acc;
}

// ===========================================================================
// Host orchestration
// ===========================================================================
static inline dim3 grid1(long n) { return dim3((unsigned)((n + 255) / 256)); }

extern "C" void kernel_launch(void* const* d_in, const int* in_sizes, int n_in,
                              void* d_out, int out_size, void* d_ws, size_t ws_size,
                              hipStream_t stream) {
    const float* x      = (const float*)d_in[0];
    const float* fc0_w  = (const float*)d_in[1];
    const float* fc0_b  = (const float*)d_in[2];
    const float* ln_g   = (const float*)d_in[3];
    const float* ln_b   = (const float*)d_in[4];
    const float* wq     = (const float*)d_in[5];
    const float* wk     = (const float*)d_in[6];
    const float* wv     = (const float*)d_in[7];
    const float* wo     = (const float*)d_in[8];
    const float* bnq_g  = (const float*)d_in[9];
    const float* bnq_b  = (const float*)d_in[10];
    const float* bnk_g  = (const float*)d_in[11];
    const float* bnk_b  = (const float*)d_in[12];
    const float* bnv_g  = (const float*)d_in[13];
    const float* bnv_b  = (const float*)d_in[14];
    const float* bno_g  = (const float*)d_in[15];
    const float* bno_b  = (const float*)d_in[16];
    const float* w1     = (const float*)d_in[17];
    const float* bn1_g  = (const float*)d_in[18];
    const float* bn1_b  = (const float*)d_in[19];
    const float* w2     = (const float*)d_in[20];
    const float* bn2_g  = (const float*)d_in[21];
    const float* bn2_b  = (const float*)d_in[22];
    const float* head_w = (const float*)d_in[23];
    const float* head_b = (const float*)d_in[24];
    const float* gfc_w  = (const float*)d_in[25];
    const float* gfc_b  = (const float*)d_in[26];
    const float* gbn0_g = (const float*)d_in[27];
    const float* gbn0_b = (const float*)d_in[28];
    const float* gconv_w= (const float*)d_in[29];
    const float* gconv_b= (const float*)d_in[30];
    const float* gbn_g  = (const float*)d_in[31];
    const float* gbn_b  = (const float*)d_in[32];
    const float* fc_w   = (const float*)d_in[33];
    const float* fc_b   = (const float*)d_in[34];
    const int*   edge   = (const int*)d_in[35];

    const int E = in_sizes[35] / 2;
    const int* erow = edge;
    const int* ecol = edge + E;
    const int NC = N_NODES * C_OUT;

    // ---- workspace layout (~224 MiB) ----
    uint8_t* wsbase = (uint8_t*)d_ws;
    size_t off = 0;
    auto alloc = [&](size_t bytes, size_t align) -> void* {
        off = (off + align - 1) & ~(align - 1);
        void* p = wsbase + off;
        off += bytes;
        return p;
    };
    double*   statBuf = (double*)alloc((size_t)64 * 2048 * sizeof(double), 256); // per-gate stats (1024 sum + 1024 sumsq)
    float*    h_buf  = (float*)alloc((size_t)2 * ND * sizeof(float), 256);       // 67 MB
    float*    Pf     = (float*)alloc((size_t)M2 * 1024 * sizeof(float), 256);    // 134 MB
    uint8_t*  Wdig   = (uint8_t*)alloc((size_t)WD_TOTAL, 256);                   // 10.5 MB
    uint64_t* s_bits = (uint64_t*)alloc((size_t)2 * N_NODES * 8 * 8, 256);
    uint64_t* q_bits = (uint64_t*)alloc((size_t)2 * N_NODES * 8 * 8, 256);
    uint64_t* k_bits = (uint64_t*)alloc((size_t)2 * N_NODES * 8 * 8, 256);
    uint64_t* v_bits = (uint64_t*)alloc((size_t)2 * N_NODES * 8 * 8, 256);
    uint64_t* m_bits = (uint64_t*)alloc((size_t)2 * N_NODES * 16 * 8, 256);      // 4.2 MB
    float*    ybuf   = (float*)m_bits;  // alias: y written at head, after m_bits dead
    (void)alloc((size_t)2 * NC * sizeof(float) > (size_t)2 * N_NODES * 16 * 8
                ? (size_t)2 * NC * sizeof(float) - (size_t)2 * N_NODES * 16 * 8 : 0, 256);
    float*    g0     = (float*)alloc((size_t)NC * sizeof(float), 256);
    float*    gg     = (float*)alloc((size_t)NC * sizeof(float), 256);
    float*    ag     = (float*)alloc((size_t)NC * sizeof(float), 256);
    float*    kvb    = (float*)alloc((size_t)65536 * sizeof(float), 256);
    float*    deg    = (float*)alloc((size_t)N_NODES * sizeof(float), 256);
    if (off > ws_size) return;

    const dim3 blk(256);
    const dim3 gBN512((unsigned)(2 * N_NODES));       // N*512/256
    const dim3 gBN1024((unsigned)(4 * N_NODES));      // N*1024/256
    const dim3 gGEMM(8, M2 / 128);                    // 512 cols per launch
    const dim3 gGEMMw1(16, M2 / 128);                 // 1024 cols per launch
    const double invM2 = 1.0 / (double)M2;
    const double invMN = 1.0 / (double)N_NODES;

    hipMemsetAsync(statBuf, 0, (size_t)64 * 2048 * sizeof(double), stream);

    int gate = 0;
    auto nextStat = [&]() { return statBuf + (size_t)(gate++) * 2048; };

    // ===== transformer branch =====
    hipLaunchKernelGGL(gemm_f32d, dim3(8, N_NODES / 64), blk, 0, stream,
                       x, 512, fc0_w, 512, fc0_b, Pf, 512, N_NODES, 512, 512);
    hipLaunchKernelGGL(ln_relu_lif, dim3(N_NODES), blk, 0, stream, Pf, ln_g, ln_b, h_buf, s_bits);

    for (int l = 0; l < 4; ++l) {
        // one prep launch for all 6 matrices of this layer
        hipLaunchKernelGGL(w_digits_layer, dim3(512), blk, 0, stream,
                           wq + (size_t)l * 262144, wk + (size_t)l * 262144,
                           wv + (size_t)l * 262144, wo + (size_t)l * 262144,
                           w1 + (size_t)l * 524288, w2 + (size_t)l * 524288, Wdig);

        uint64_t* qkvb[3] = {q_bits, k_bits, v_bits};
        const size_t wdoff[3] = {WD_Q, WD_K, WD_V};
        const float* gmat[3] = {bnq_g + l * 512, bnk_g + l * 512, bnv_g + l * 512};
        const float* bmat[3] = {bnq_b + l * 512, bnk_b + l * 512, bnv_b + l * 512};
        for (int j = 0; j < 3; ++j) {
            double* st = nextStat();
            hipLaunchKernelGGL(gemm_i8_bits, gGEMM, blk, 0, stream,
                               s_bits, 8, Wdig + wdoff[j], 512, 0, Pf, 512, 512, st, st + 1024);
            hipLaunchKernelGGL(bn_lif_bits2, gBN512, blk, 0, stream,
                               Pf, st, st + 1024, gmat[j], bmat[j], invM2, qkvb[j], 9, 8);
        }

        // attention (exact); fused O-proj input: lif(o) bits -> q_bits in place
        hipMemsetAsync(kvb, 0, 65536 * sizeof(float), stream);
        hipLaunchKernelGGL(kv_bits, dim3(16, 16), blk, 0, stream, k_bits, v_bits, kvb, 1024);
        hipLaunchKernelGGL(o_lif_bits, dim3(N_NODES / 64, 8), blk, 0, stream, q_bits, kvb, q_bits);

        // h += bn(lif(o) @ wo); emit s = lif(h_new) into s_bits
        {
            double* st = nextStat();
            hipLaunchKernelGGL(gemm_i8_bits, gGEMM, blk, 0, stream,
                               q_bits, 8, Wdig + WD_O, 512, 0, Pf, 512, 512, st, st + 1024);
            hipLaunchKernelGGL(bn_add_lif2, gBN512, blk, 0, stream,
                               Pf, st, st + 1024, bno_g + l * 512, bno_b + l * 512,
                               invM2, h_buf, s_bits);
        }

        // MLP: m = lif(bn1(s @ w1)) — single 1024-col launch
        {
            double* st = nextStat();
            hipLaunchKernelGGL(gemm_i8_bits, gGEMMw1, blk, 0, stream,
                               s_bits, 8, Wdig + WD_1, 1024, 0, Pf, 1024, 512, st, st + 1024);
            hipLaunchKernelGGL(bn_lif_bits2, gBN1024, blk, 0, stream,
                               Pf, st, st + 1024, bn1_g + l * 1024, bn1_b + l * 1024,
                               invM2, m_bits, 10, 16);
        }
        // h += bn2(m @ w2); emit s = lif(h_new) for next layer / head
        {
            double* st = nextStat();
            hipLaunchKernelGGL(gemm_i8_bits, gGEMM, blk, 0, stream,
                               m_bits, 16, Wdig + WD_2, 512, 0, Pf, 512, 1024, st, st + 1024);
            hipLaunchKernelGGL(bn_add_lif2, gBN512, blk, 0, stream,
                               Pf, st, st + 1024, bn2_g + l * 512, bn2_b + l * 512,
                               invM2, h_buf, s_bits);
        }
    }

    // head: y = s @ head_w + head_b (s_bits already = lif(h_final))
    hipLaunchKernelGGL(head_gather, dim3(M2 / 4), blk, 0, stream, s_bits, head_w, head_b, ybuf);

    // ===== GNN branch (fp32) =====
    hipLaunchKernelGGL(gemm_f32, dim3(1, N_NODES / 64), blk, 0, stream,
                       x, 512, gfc_w, 40, gfc_b, ag, 40, N_NODES, 40, 512);
    {
        double* st = nextStat();
        dim3 gs(1, (N_NODES + 511) / 512);
        hipLaunchKernelGGL(col_stats_f, gs, blk, 0, stream, ag, N_NODES, 40, 512, st, st + 1024);
        hipLaunchKernelGGL(bn_relu_add_f2, grid1(NC), blk, 0, stream,
                           ag, st, st + 1024, gbn0_g, gbn0_b, invMN,
                           (const float*)nullptr, g0, NC, 40);
    }

    hipMemsetAsync(deg, 0, N_NODES * sizeof(float), stream);
    hipLaunchKernelGGL(deg_kernel, grid1(E), blk, 0, stream, ecol, deg, E);
    hipLaunchKernelGGL(dinv_kernel, grid1(N_NODES), blk, 0, stream, deg, N_NODES);

    const float* gsrc = g0;
    for (int i = 0; i < 2; ++i) {
        hipMemsetAsync(ag, 0, (size_t)NC * sizeof(float), stream);
        hipLaunchKernelGGL(agg_kernel, grid1((long)E * C_OUT), blk, 0, stream,
                           gsrc, erow, ecol, deg, ag, E);
        hipLaunchKernelGGL(gemm_f32, dim3(1, N_NODES / 64), blk, 0, stream,
                           ag, 40, gconv_w + (size_t)i * 40 * 40, 40, gconv_b + i * 40,
                           gg, 40, N_NODES, 40, 40);
        double* st = nextStat();
        dim3 gs(1, (N_NODES + 511) / 512);
        hipLaunchKernelGGL(col_stats_f, gs, blk, 0, stream, gg, N_NODES, 40, 512, st, st + 1024);
        hipLaunchKernelGGL(bn_relu_add_f2, grid1(NC), blk, 0, stream,
                           gg, st, st + 1024, gbn_g + i * 40, gbn_b + i * 40, invMN, g0, gg, NC, 40);
        gsrc = gg;
    }

    // out = (0.8*g + 0.2*mean_t(y)) @ fc_w + fc_b
    hipLaunchKernelGGL(mix_kernel, grid1(NC), blk, 0, stream, gg, ybuf, ag, NC);
    hipLaunchKernelGGL(final_fc_kernel, grid1((long)N_NODES * C_OUT), blk, 0, stream,
                       ag, fc_w, fc_b, (float*)d_out);
}

// Round 8
// 5716.808 us; speedup vs baseline: 2.2821x; 1.0084x over previous
//
#include <hip/hip_runtime.h>
#include <cstddef>
#include <cstdint>

constexpr int N_NODES = 16384;
constexpr int D_MODEL = 512;
constexpr int C_OUT   = 40;
constexpr int ND      = N_NODES * D_MODEL;   // per-timestep elements (512-ch)
constexpr int M2      = 2 * N_NODES;         // T*N rows

typedef int i32x4 __attribute__((ext_vector_type(4)));

// digit scales: w ≈ Σ d_j * S_j, residual ≤ 2^-38 (5 digits)
#define S0 0.001953125                      // 2^-9
#define S1 1.52587890625e-05                // 2^-16
#define S2 1.1920928955078125e-07           // 2^-23
#define S3 9.31322574615478515625e-10       // 2^-30
#define S4 7.2759576141834259033203125e-12  // 2^-37

// digit-plane offsets within the per-layer buffer (bytes)
#define WD_Q 0
#define WD_K 1310720
#define WD_V 2621440
#define WD_O 3932160
#define WD_1 5242880
#define WD_2 7864320
#define WD_TOTAL 10485760

// LDS ktile stride: 5120 data bytes + 32 pad (distinct bank offsets per q).
#define KT_STRIDE 5152

// ===========================================================================
// Per-layer weight -> 5 signed-i8 digit planes in MFMA B-fragment order:
// byte at ((k/16)*N + n)*80 + j*16 + (k%16).
// ===========================================================================
__global__ __launch_bounds__(256)
void w_digits_layer(const float* __restrict__ wq, const float* __restrict__ wk,
                    const float* __restrict__ wv, const float* __restrict__ wo,
                    const float* __restrict__ w1, const float* __restrict__ w2,
                    uint8_t* __restrict__ Wd) {
    int idx = blockIdx.x * 256 + threadIdx.x;   // [0, 131072)
    const float* W;
    uint8_t* outb;
    int N, rem;
    if (idx < 65536) {                          // wq,wk,wv,wo: 4 x (32 kg x 512 n)
        int mm = idx >> 14;
        rem = idx & 16383;
        const float* ptrs[4] = {wq, wk, wv, wo};
        W = ptrs[mm]; outb = Wd + (size_t)mm * 1310720; N = 512;
    } else if (idx < 98304) {                   // w1: 32 kg x 1024 n
        rem = idx - 65536; W = w1; outb = Wd + WD_1; N = 1024;
    } else {                                    // w2: 64 kg x 512 n
        rem = idx - 98304; W = w2; outb = Wd + WD_2; N = 512;
    }
    int kg = rem / N, n = rem - kg * N;
    const float* Wp = W + (size_t)kg * 16 * N + n;
    uint8_t* out = outb + (size_t)(kg * N + n) * 80;
    const double scl[5] = {512.0, 65536.0, 8388608.0, 1073741824.0, 137438953472.0};
    const double inv[5] = {S0, S1, S2, S3, S4};
    union { uint8_t b[5][16]; i32x4 v[5]; } db;
#pragma unroll
    for (int kk = 0; kk < 16; ++kk) {
        double r = (double)Wp[(size_t)kk * N];
#pragma unroll
        for (int j = 0; j < 5; ++j) {
            int d = (int)rint(r * scl[j]);
            d = d > 127 ? 127 : (d < -127 ? -127 : d);
            r -= (double)d * inv[j];
            db.b[j][kk] = (uint8_t)(int8_t)d;
        }
    }
#pragma unroll
    for (int j = 0; j < 5; ++j)
        *reinterpret_cast<i32x4*>(out + j * 16) = db.v[j];
}

// ===========================================================================
// Spike GEMM via i8 MFMA, exact fixed-point. 128-row blocks.
// v4: single-barrier double-buffered LDS pipeline — loads for tile k+1
// issued before computing tile k (latency covered by the MFMA section),
// write to the other buffer, ONE barrier per k-step. Staging geometry
// hoisted out of the loop (no per-kstep divisions).
// ===========================================================================
__global__ __launch_bounds__(256)
void gemm_i8_bits(const uint64_t* __restrict__ bits, int kWords,
                  const uint8_t* __restrict__ Wd, int Nmat, int colOff,
                  float* __restrict__ C, int ldc, int K,
                  double* __restrict__ sum, double* __restrict__ sumsq) {
    __shared__ __attribute__((aligned(16))) uint8_t Bs[2][4 * KT_STRIDE];
    const int lane = threadIdx.x & 63;
    const int wv   = threadIdx.x >> 6;
    const int m    = lane & 15;
    const int q    = lane >> 4;
    const int rowT = blockIdx.y * 128 + wv * 32;   // this wave's 32-row tile
    const int colB = blockIdx.x * 64;

    // k-invariant staging geometry (removes per-kstep divisions)
    int lofs[5];
    size_t gofs[5];
    {
        const size_t cb = (size_t)(colOff + colB);
#pragma unroll
        for (int c5 = 0; c5 < 5; ++c5) {
            int c  = threadIdx.x + c5 * 256;       // [0,1280) 16B chunks
            int kt = c / 320;                      // ktile (5120B data each)
            int of = c - kt * 320;
            lofs[c5] = kt * KT_STRIDE + of * 16;
            gofs[c5] = ((size_t)kt * Nmat + cb) * 80 + (size_t)of * 16;
        }
    }
    const size_t kAdv = (size_t)Nmat * 5;          // bytes per k of 1 (kb*kAdv)

    i32x4 acc[2][4][5];
#pragma unroll
    for (int rt = 0; rt < 2; ++rt)
#pragma unroll
        for (int t = 0; t < 4; ++t)
#pragma unroll
            for (int j = 0; j < 5; ++j) acc[rt][t][j] = (i32x4){0, 0, 0, 0};

    const uint64_t* brow0 = bits + (size_t)(rowT + m) * kWords;
    const uint64_t* brow1 = brow0 + (size_t)16 * kWords;

    // ---- prologue: stage tile 0, prefetch A words for tile 0 ----
    i32x4 tmp[5];
#pragma unroll
    for (int c5 = 0; c5 < 5; ++c5)
        tmp[c5] = *reinterpret_cast<const i32x4*>(Wd + gofs[c5]);
    uint64_t wb0 = brow0[0];
    uint64_t wb1 = brow1[0];
#pragma unroll
    for (int c5 = 0; c5 < 5; ++c5)
        *reinterpret_cast<i32x4*>(&Bs[0][lofs[c5]]) = tmp[c5];
    __syncthreads();

    int p = 0;
    for (int kb = 0; kb < K; kb += 64) {
        const bool more = (kb + 64) < K;
        // issue next-tile loads (latency hides under this iteration's MFMAs)
        if (more) {
            const uint8_t* Wn = Wd + (size_t)(kb + 64) * kAdv;
#pragma unroll
            for (int c5 = 0; c5 < 5; ++c5)
                tmp[c5] = *reinterpret_cast<const i32x4*>(Wn + gofs[c5]);
        }
        uint64_t nb0 = 0, nb1 = 0;
        if (more) { nb0 = brow0[(kb >> 6) + 1]; nb1 = brow1[(kb >> 6) + 1]; }

        // A spike fragments for both row-tiles (current k-step)
        uint32_t hw0 = (uint32_t)(wb0 >> (q * 16)) & 0xFFFFu;
        uint32_t hw1 = (uint32_t)(wb1 >> (q * 16)) & 0xFFFFu;
        i32x4 af0, af1;
#pragma unroll
        for (int i = 0; i < 4; ++i) {
            af0[i] = (int)((((hw0 >> (4 * i)) & 0xFu) * 0x00204081u) & 0x01010101u);
            af1[i] = (int)((((hw1 >> (4 * i)) & 0xFu) * 0x00204081u) & 0x01010101u);
        }

        // compute current tile from Bs[p]
#pragma unroll
        for (int t = 0; t < 4; ++t) {
            const uint8_t* bt = &Bs[p][q * KT_STRIDE + (t * 16 + m) * 80];
            i32x4 bf[5];
#pragma unroll
            for (int j = 0; j < 5; ++j)
                bf[j] = *reinterpret_cast<const i32x4*>(bt + j * 16);
#pragma unroll
            for (int j = 0; j < 5; ++j) {
                acc[0][t][j] = __builtin_amdgcn_mfma_i32_16x16x64_i8(af0, bf[j], acc[0][t][j], 0, 0, 0);
                acc[1][t][j] = __builtin_amdgcn_mfma_i32_16x16x64_i8(af1, bf[j], acc[1][t][j], 0, 0, 0);
            }
        }

        // stage next tile into the other buffer (no pre-write barrier needed)
        if (more) {
#pragma unroll
            for (int c5 = 0; c5 < 5; ++c5)
                *reinterpret_cast<i32x4*>(&Bs[p ^ 1][lofs[c5]]) = tmp[c5];
        }
        __syncthreads();   // single barrier per k-step
        p ^= 1;
        wb0 = nb0; wb1 = nb1;
    }

    double sarr[4], qarr[4];
#pragma unroll
    for (int t = 0; t < 4; ++t) { sarr[t] = 0.0; qarr[t] = 0.0; }
#pragma unroll
    for (int rt = 0; rt < 2; ++rt) {
        const int orow = rowT + rt * 16 + q * 4;
#pragma unroll
        for (int t = 0; t < 4; ++t) {
            float* Cc = C + (size_t)orow * ldc + colB + t * 16 + m;
#pragma unroll
            for (int i = 0; i < 4; ++i) {
                double p2 = (double)acc[rt][t][0][i] * S0 + (double)acc[rt][t][1][i] * S1
                          + (double)acc[rt][t][2][i] * S2 + (double)acc[rt][t][3][i] * S3
                          + (double)acc[rt][t][4][i] * S4;
                Cc[(size_t)i * ldc] = (float)p2;
                sarr[t] += p2; qarr[t] += p2 * p2;
            }
        }
    }
    __shared__ double ls[4][64], lq[4][64];
#pragma unroll
    for (int t = 0; t < 4; ++t) {
        double s = sarr[t], qq = qarr[t];
        s  += __shfl_xor(s, 16);  s  += __shfl_xor(s, 32);
        qq += __shfl_xor(qq, 16); qq += __shfl_xor(qq, 32);
        if (lane < 16) { ls[wv][t * 16 + lane] = s; lq[wv][t * 16 + lane] = qq; }
    }
    __syncthreads();
    if (threadIdx.x < 64) {
        int t = threadIdx.x;
        double s  = ls[0][t] + ls[1][t] + ls[2][t] + ls[3][t];
        double qq = lq[0][t] + lq[1][t] + lq[2][t] + lq[3][t];
        atomicAdd(&sum[colB + t], s);
        atomicAdd(&sumsq[colB + t], qq);
    }
}

// head GEMM: exact f64 gather (immune to any MFMA layout quirk)
__global__ __launch_bounds__(256)
void head_gather(const uint64_t* __restrict__ bits, const float* __restrict__ W,
                 const float* __restrict__ bias, float* __restrict__ Y) {
    const int lane = threadIdx.x & 63;
    const int wid  = threadIdx.x >> 6;
    const int r = blockIdx.x * 4 + wid;
    if (lane >= C_OUT) return;
    double acc = (double)bias[lane];
    const uint64_t* bw = bits + (size_t)r * 8;
    for (int j = 0; j < 8; ++j) {
        uint64_t w = bw[j];
        const float* Wk = W + (size_t)j * 64 * C_OUT + lane;
        while (w) {
            int k = __builtin_ctzll(w);
            w &= w - 1;
            acc += (double)Wk[(size_t)k * C_OUT];
        }
    }
    Y[(size_t)r * C_OUT + lane] = (float)acc;
}

// GEMM (float A, float out, f64 acc) — fc0 only. Swizzled f32 LDS (R2-proven).
__global__ __launch_bounds__(256)
void gemm_f32d(const float* __restrict__ A, int lda,
               const float* __restrict__ B, int ldb,
               const float* __restrict__ bias,
               float* __restrict__ C, int ldc, int M, int Nc, int K) {
    __shared__ float As[16][64];
    __shared__ float Bs[16][64];
    const int tid = threadIdx.x;
    const int tx  = tid & 15, ty = tid >> 4;
    const int row0 = blockIdx.y * 64 + ty * 4;
    const int col0 = blockIdx.x * 64 + tx * 4;
    const int ar = tid >> 2, ak = (tid & 3) * 4;   // A: row ar, k ak..ak+3
    const int bk = tid >> 4, bn = (tid & 15) * 4;  // B: k-row bk, cols bn..bn+3
    const int gm = blockIdx.y * 64 + ar;
    double acc[4][4];
#pragma unroll
    for (int i = 0; i < 4; i++)
#pragma unroll
        for (int j = 0; j < 4; j++) acc[i][j] = 0.0;
    for (int k0 = 0; k0 < K; k0 += 16) {
        float4 av = *reinterpret_cast<const float4*>(&A[(size_t)gm * lda + k0 + ak]);
        const float* avp = reinterpret_cast<const float*>(&av);
#pragma unroll
        for (int j = 0; j < 4; j++)
            As[ak + j][ar ^ ((ak + j) & 12)] = avp[j];
        float4 bv = *reinterpret_cast<const float4*>(
            &B[(size_t)(k0 + bk) * ldb + blockIdx.x * 64 + bn]);
        *reinterpret_cast<float4*>(&Bs[bk][bn ^ ((bk & 3) << 2)]) = bv;
        __syncthreads();
#pragma unroll
        for (int kk = 0; kk < 16; kk++) {
            float4 a4 = *reinterpret_cast<const float4*>(&As[kk][(ty * 4) ^ (kk & 12)]);
            float4 b4 = *reinterpret_cast<const float4*>(&Bs[kk][(tx * 4) ^ ((kk & 3) << 2)]);
            const float* ap = reinterpret_cast<const float*>(&a4);
            const float* bp = reinterpret_cast<const float*>(&b4);
#pragma unroll
            for (int i = 0; i < 4; i++)
#pragma unroll
                for (int j = 0; j < 4; j++)
                    acc[i][j] = fma((double)ap[i], (double)bp[j], acc[i][j]);
        }
        __syncthreads();
    }
#pragma unroll
    for (int i = 0; i < 4; i++) {
        int r = row0 + i;
        if (r >= M) continue;
#pragma unroll
        for (int j = 0; j < 4; j++) {
            int c = col0 + j;
            if (c < Nc) {
                double v = acc[i][j];
                if (bias) v += (double)bias[c];
                C[(size_t)r * ldc + c] = (float)v;
            }
        }
    }
}

// GEMM (float A/B/C, double acc) — GNN branch.
__global__ __launch_bounds__(256)
void gemm_f32(const float* __restrict__ A, int lda,
              const float* __restrict__ B, int ldb,
              const float* __restrict__ bias,
              float* __restrict__ C, int ldc, int M, int Nc, int K) {
    __shared__ float As[16][64];
    __shared__ float Bs[16][64];
    const int tid = threadIdx.x;
    const int tx  = tid & 15, ty = tid >> 4;
    const int row0 = blockIdx.y * 64 + ty * 4;
    const int col0 = blockIdx.x * 64 + tx * 4;
    const int ar = tid >> 2, ak = (tid & 3) * 4;
    const int bk = tid >> 4, bn = (tid & 15) * 4;
    const int gm = blockIdx.y * 64 + ar;
    double acc[4][4];
#pragma unroll
    for (int i = 0; i < 4; i++)
#pragma unroll
        for (int j = 0; j < 4; j++) acc[i][j] = 0.0;
    for (int k0 = 0; k0 < K; k0 += 16) {
#pragma unroll
        for (int j = 0; j < 4; j++) {
            int kk = k0 + ak + j;
            As[ak + j][ar] = (gm < M && kk < K) ? A[(size_t)gm * lda + kk] : 0.f;
        }
#pragma unroll
        for (int j = 0; j < 4; j++) {
            int gn = blockIdx.x * 64 + bn + j;
            int kk = k0 + bk;
            Bs[bk][bn + j] = (gn < Nc && kk < K) ? B[(size_t)kk * ldb + gn] : 0.f;
        }
        __syncthreads();
#pragma unroll
        for (int kk = 0; kk < 16; kk++) {
            float a4[4], b4[4];
#pragma unroll
            for (int i = 0; i < 4; i++) a4[i] = As[kk][ty * 4 + i];
#pragma unroll
            for (int j = 0; j < 4; j++) b4[j] = Bs[kk][tx * 4 + j];
#pragma unroll
            for (int i = 0; i < 4; i++)
#pragma unroll
                for (int j = 0; j < 4; j++) acc[i][j] = fma((double)a4[i], (double)b4[j], acc[i][j]);
        }
        __syncthreads();
    }
#pragma unroll
    for (int i = 0; i < 4; i++) {
        int r = row0 + i;
        if (r >= M) continue;
#pragma unroll
        for (int j = 0; j < 4; j++) {
            int c = col0 + j;
            if (c < Nc) {
                double v = acc[i][j];
                if (bias) v += (double)bias[c];
                C[(size_t)r * ldc + c] = (float)v;
            }
        }
    }
}

// BN stats for fp32 inputs (GNN branch) -> per-gate buffers
__global__ __launch_bounds__(256)
void col_stats_f(const float* __restrict__ X, int M, int Ch, int rowsPerBlock,
                 double* __restrict__ sum, double* __restrict__ sumsq) {
    const int cl = threadIdx.x & 63;
    const int c  = blockIdx.x * 64 + cl;
    const int rg = threadIdx.x >> 6;
    const int r0 = blockIdx.y * rowsPerBlock;
    const int r1 = min(r0 + rowsPerBlock, M);
    double s = 0.0, q = 0.0;
    if (c < Ch) {
        for (int r = r0 + rg; r < r1; r += 4) {
            double v = (double)X[(size_t)r * Ch + c];
            s += v; q += v * v;
        }
    }
    __shared__ double ls[4][64], lq[4][64];
    ls[rg][cl] = s; lq[rg][cl] = q;
    __syncthreads();
    if (rg == 0 && c < Ch) {
        s = ls[0][cl] + ls[1][cl] + ls[2][cl] + ls[3][cl];
        q = lq[0][cl] + lq[1][cl] + lq[2][cl] + lq[3][cl];
        atomicAdd(&sum[c], s);
        atomicAdd(&sumsq[c], q);
    }
}

// ===========================================================================
// LIF helpers (exact ref arithmetic, f64)
// ===========================================================================
__device__ __forceinline__ void lif2(double x0, double x1, bool& s0, bool& s1) {
    double v = x0 * 0.5;
    s0 = (v >= 1.0);
    v = s0 ? 0.0 : v;
    v = v + (x1 - v) * 0.5;
    s1 = (v >= 1.0);
}

__device__ __forceinline__ void bn_params(const double* sum, const double* sumsq,
                                          const float* g, const float* b, double invM,
                                          int c, double& sc, double& sh) {
    double m   = sum[c] * invM;
    double var = sumsq[c] * invM - m * m;
    sc = (double)g[c] / sqrt(var + 1e-5);
    sh = (double)b[c] - m * sc;
}

// BN + LIF over a full chunk of (1<<chBits) cols (f32 activations) -> bits
__global__ __launch_bounds__(256)
void bn_lif_bits2(const float* __restrict__ X,
                  const double* __restrict__ sum, const double* __restrict__ sumsq,
                  const float* __restrict__ g, const float* __restrict__ b, double invM,
                  uint64_t* __restrict__ S, int chBits, int osWords) {
    int i = blockIdx.x * 256 + threadIdx.x;   // i < N << chBits
    int n = i >> chBits, c = i & ((1 << chBits) - 1);
    double sc, sh;
    bn_params(sum, sumsq, g, b, invM, c, sc, sh);
    bool s0, s1;
    lif2((double)X[i] * sc + sh,
         (double)X[(size_t)i + ((size_t)N_NODES << chBits)] * sc + sh, s0, s1);
    uint64_t b0 = __ballot(s0), b1 = __ballot(s1);
    if ((threadIdx.x & 63) == 0) {
        int widx = n * osWords + (c >> 6);
        S[widx] = b0;
        S[widx + N_NODES * osWords] = b1;
    }
}

// h += bn(X) over a full 512-col row (f32 H, f64 compute) AND emit lif(h) bits
__global__ __launch_bounds__(256)
void bn_add_lif2(const float* __restrict__ X,
                 const double* __restrict__ sum, const double* __restrict__ sumsq,
                 const float* __restrict__ g, const float* __restrict__ b, double invM,
                 float* __restrict__ H, uint64_t* __restrict__ S) {
    int i = blockIdx.x * 256 + threadIdx.x;   // i < N*512 (== n*512 + c)
    int n = i >> 9, c = i & 511;
    double sc, sh;
    bn_params(sum, sumsq, g, b, invM, c, sc, sh);
    double h0 = (double)H[i] + ((double)X[i] * sc + sh);
    double h1 = (double)H[(size_t)i + ND] + ((double)X[(size_t)i + ND] * sc + sh);
    H[i] = (float)h0;
    H[(size_t)i + ND] = (float)h1;
    bool s0, s1;
    lif2(h0, h1, s0, s1);
    uint64_t b0 = __ballot(s0), b1 = __ballot(s1);
    if ((threadIdx.x & 63) == 0) {
        int widx = n * 8 + (c >> 6);
        S[widx] = b0;
        S[widx + N_NODES * 8] = b1;
    }
}

// LayerNorm(512)+ReLU on fc0 output (f32); write both t-slices of h (f32) + lif bits
__global__ __launch_bounds__(256)
void ln_relu_lif(const float* __restrict__ X, const float* __restrict__ g,
                 const float* __restrict__ b, float* __restrict__ H,
                 uint64_t* __restrict__ S) {
    int n = blockIdx.x;
    const float* x = X + (size_t)n * 512;
    int c0 = threadIdx.x, c1 = threadIdx.x + 256;
    double v0 = (double)x[c0], v1 = (double)x[c1];
    __shared__ double ls[256], lq[256];
    ls[threadIdx.x] = v0 + v1;
    lq[threadIdx.x] = v0 * v0 + v1 * v1;
    __syncthreads();
    for (int off = 128; off > 0; off >>= 1) {
        if (threadIdx.x < off) {
            ls[threadIdx.x] += ls[threadIdx.x + off];
            lq[threadIdx.x] += lq[threadIdx.x + off];
        }
        __syncthreads();
    }
    double m    = ls[0] * (1.0 / 512);
    double var  = lq[0] * (1.0 / 512) - m * m;
    double rstd = 1.0 / sqrt(var + 1e-5);
    double o0 = (v0 - m) * rstd * (double)g[c0] + (double)b[c0];
    double o1 = (v1 - m) * rstd * (double)g[c1] + (double)b[c1];
    o0 = o0 > 0.0 ? o0 : 0.0;
    o1 = o1 > 0.0 ? o1 : 0.0;
    float* h0 = H + (size_t)n * 512;
    h0[c0] = (float)o0; h0[c1] = (float)o1;
    h0[ND + c0] = (float)o0; h0[ND + c1] = (float)o1;
    // lif with x0 == x1 == o
    bool a0, a1, d0, d1;
    lif2(o0, o0, a0, a1);
    lif2(o1, o1, d0, d1);
    uint64_t ba0 = __ballot(a0), ba1 = __ballot(a1);
    uint64_t bd0 = __ballot(d0), bd1 = __ballot(d1);
    if ((threadIdx.x & 63) == 0) {
        int w = threadIdx.x >> 6;
        S[n * 8 + w] = ba0;
        S[n * 8 + w + N_NODES * 8] = ba1;
        S[n * 8 + 4 + w] = bd0;
        S[n * 8 + 4 + w + N_NODES * 8] = bd1;
    }
}

// ===========================================================================
// Attention on bit spikes (integer-exact in fp32).
// ===========================================================================
__global__ __launch_bounds__(256)
void kv_bits(const uint64_t* __restrict__ Kb, const uint64_t* __restrict__ Vb,
             float* __restrict__ KV, int nPerBlock) {
    const int th = blockIdx.x;
    const int t = th >> 3, h = th & 7;
    const int nbase = blockIdx.y * nPerBlock;
    const int e = threadIdx.x & 63, dg = threadIdx.x >> 6;
    float acc[16];
#pragma unroll
    for (int i = 0; i < 16; i++) acc[i] = 0.f;
    __shared__ float ks[16][64], vs[16][64];
    const size_t wbase = (size_t)t * N_NODES * 8 + h;
    for (int n0 = 0; n0 < nPerBlock; n0 += 16) {
        for (int idx = threadIdx.x; idx < 16 * 128; idx += 256) {
            int r = idx >> 7, c = idx & 127;
            size_t wi = wbase + (size_t)(nbase + n0 + r) * 8;
            if (c < 64) ks[r][c] = (float)((Kb[wi] >> c) & 1ull);
            else        vs[r][c - 64] = (float)((Vb[wi] >> (c - 64)) & 1ull);
        }
        __syncthreads();
#pragma unroll
        for (int r = 0; r < 16; ++r) {
            float ve = vs[r][e];
#pragma unroll
            for (int i = 0; i < 16; ++i) acc[i] += ks[r][dg * 16 + i] * ve;
        }
        __syncthreads();
    }
    float* kvp = KV + (size_t)th * 4096;
    for (int i = 0; i < 16; ++i)
        atomicAdd(&kvp[(dg * 16 + i) * 64 + e], acc[i]);
}

// O = (Q @ KV) * 0.125 for BOTH timesteps, LIF in-register, emit bits.
__global__ __launch_bounds__(256)
void o_lif_bits(const uint64_t* __restrict__ Qb, const float* __restrict__ KV,
                uint64_t* __restrict__ S) {
    const int h  = blockIdx.y;     // 8 heads
    const int nb = blockIdx.x;     // N/64 row blocks
    __shared__ float kvs[64][64];
    __shared__ float qs[64][65];
    const int e = threadIdx.x & 63, rg = threadIdx.x >> 6;
    float acc0[16], acc1[16];
#pragma unroll
    for (int i = 0; i < 16; ++i) { acc0[i] = 0.f; acc1[i] = 0.f; }
#pragma unroll
    for (int t = 0; t < 2; ++t) {
        const float* kvp = KV + (size_t)(t * 8 + h) * 4096;
        for (int idx = threadIdx.x; idx < 4096; idx += 256)
            kvs[idx >> 6][idx & 63] = kvp[idx];
        const size_t wbase = ((size_t)t * N_NODES + (size_t)nb * 64) * 8 + h;
        for (int idx = threadIdx.x; idx < 4096; idx += 256) {
            int r = idx >> 6, c = idx & 63;
            qs[r][c] = (float)((Qb[wbase + (size_t)r * 8] >> c) & 1ull);
        }
        __syncthreads();
        float* acc = t == 0 ? acc0 : acc1;
        for (int d = 0; d < 64; ++d) {
            float kv = kvs[d][e];
#pragma unroll
            for (int i = 0; i < 16; ++i) acc[i] += qs[rg * 16 + i][d] * kv;
        }
        __syncthreads();   // LDS reloaded next t
    }
#pragma unroll
    for (int i = 0; i < 16; ++i) {
        float o0 = acc0[i] * 0.125f;
        float o1 = acc1[i] * 0.125f;
        bool s0, s1;
        lif2((double)o0, (double)o1, s0, s1);
        uint64_t b0 = __ballot(s0), b1 = __ballot(s1);
        if (e == 0) {
            size_t row = (size_t)nb * 64 + rg * 16 + i;
            S[row * 8 + h] = b0;
            S[row * 8 + h + (size_t)N_NODES * 8] = b1;
        }
    }
}

// ===========================================================================
// GNN branch (fp32)
// ===========================================================================
__global__ __launch_bounds__(256)
void deg_kernel(const int* __restrict__ col, float* __restrict__ deg, int E) {
    int e = blockIdx.x * 256 + threadIdx.x;
    if (e < E) atomicAdd(&deg[col[e]], 1.0f);
}

__global__ __launch_bounds__(256)
void dinv_kernel(float* __restrict__ deg, int n) {
    int i = blockIdx.x * 256 + threadIdx.x;
    if (i < n) {
        double d = (double)deg[i];
        deg[i] = d > 0.0 ? (float)(1.0 / sqrt(d)) : 0.f;
    }
}

// 40 threads per edge (no idle lanes)
__global__ __launch_bounds__(256)
void agg_kernel(const float* __restrict__ G, const int* __restrict__ row,
                const int* __restrict__ col, const float* __restrict__ dinv,
                float* __restrict__ out, int E) {
    int idx = blockIdx.x * 256 + threadIdx.x;
    int e = idx / C_OUT, c = idx - e * C_OUT;
    if (e >= E) return;
    int r = row[e], cl = col[e];
    float val = dinv[cl] * dinv[r];
    atomicAdd(&out[(size_t)cl * C_OUT + c], val * G[(size_t)r * C_OUT + c]);
}

__global__ __launch_bounds__(256)
void bn_relu_add_f2(const float* __restrict__ X,
                    const double* __restrict__ sum, const double* __restrict__ sumsq,
                    const float* __restrict__ g, const float* __restrict__ b, double invM,
                    const float* __restrict__ add, float* __restrict__ out, int NC, int Ch) {
    int i = blockIdx.x * 256 + threadIdx.x;
    if (i >= NC) return;
    int c = i % Ch;
    double sc, sh;
    bn_params(sum, sumsq, g, b, invM, c, sc, sh);
    double v = (double)X[i] * sc + sh;
    v = v > 0.0 ? v : 0.0;
    if (add) v += (double)add[i];
    out[i] = (float)v;
}

__global__ __launch_bounds__(256)
void mix_kernel(const float* __restrict__ G, const float* __restrict__ Y,
                float* __restrict__ P, int NC) {
    int i = blockIdx.x * 256 + threadIdx.x;
    if (i >= NC) return;
    double y = 0.5 * ((double)Y[i] + (double)Y[(size_t)i + NC]);
    P[i] = (float)(0.8 * (double)G[i] + 0.2 * y);
}

__global__ __launch_bounds__(256)
void final_fc_kernel(const float* __restrict__ A, const float* __restrict__ W,
                     const float* __restrict__ bias, float* __restrict__ out) {
    __shared__ float Ws[40][40];
    for (int idx = threadIdx.x; idx < 1600; idx += 256)
        Ws[idx / 40][idx % 40] = W[idx];
    __syncthreads();
    int i = blockIdx.x * 256 + threadIdx.x;
    if (i >= N_NODES * C_OUT) return;
    int n = i / 40, c = i - n * 40;
    const float* a = A + (size_t)n * 40;
    double acc = (double)bias[c];
#pragma unroll 8
    for (int k = 0; k < 40; ++k) acc += (double)a[k] * (double)Ws[k][c];
    out[i] = (float)acc;
}

// ===========================================================================
// Host orchestration
// ===========================================================================
static inline dim3 grid1(long n) { return dim3((unsigned)((n + 255) / 256)); }

extern "C" void kernel_launch(void* const* d_in, const int* in_sizes, int n_in,
                              void* d_out, int out_size, void* d_ws, size_t ws_size,
                              hipStream_t stream) {
    const float* x      = (const float*)d_in[0];
    const float* fc0_w  = (const float*)d_in[1];
    const float* fc0_b  = (const float*)d_in[2];
    const float* ln_g   = (const float*)d_in[3];
    const float* ln_b   = (const float*)d_in[4];
    const float* wq     = (const float*)d_in[5];
    const float* wk     = (const float*)d_in[6];
    const float* wv     = (const float*)d_in[7];
    const float* wo     = (const float*)d_in[8];
    const float* bnq_g  = (const float*)d_in[9];
    const float* bnq_b  = (const float*)d_in[10];
    const float* bnk_g  = (const float*)d_in[11];
    const float* bnk_b  = (const float*)d_in[12];
    const float* bnv_g  = (const float*)d_in[13];
    const float* bnv_b  = (const float*)d_in[14];
    const float* bno_g  = (const float*)d_in[15];
    const float* bno_b  = (const float*)d_in[16];
    const float* w1     = (const float*)d_in[17];
    const float* bn1_g  = (const float*)d_in[18];
    const float* bn1_b  = (const float*)d_in[19];
    const float* w2     = (const float*)d_in[20];
    const float* bn2_g  = (const float*)d_in[21];
    const float* bn2_b  = (const float*)d_in[22];
    const float* head_w = (const float*)d_in[23];
    const float* head_b = (const float*)d_in[24];
    const float* gfc_w  = (const float*)d_in[25];
    const float* gfc_b  = (const float*)d_in[26];
    const float* gbn0_g = (const float*)d_in[27];
    const float* gbn0_b = (const float*)d_in[28];
    const float* gconv_w= (const float*)d_in[29];
    const float* gconv_b= (const float*)d_in[30];
    const float* gbn_g  = (const float*)d_in[31];
    const float* gbn_b  = (const float*)d_in[32];
    const float* fc_w   = (const float*)d_in[33];
    const float* fc_b   = (const float*)d_in[34];
    const int*   edge   = (const int*)d_in[35];

    const int E = in_sizes[35] / 2;
    const int* erow = edge;
    const int* ecol = edge + E;
    const int NC = N_NODES * C_OUT;

    // ---- workspace layout (~224 MiB) ----
    uint8_t* wsbase = (uint8_t*)d_ws;
    size_t off = 0;
    auto alloc = [&](size_t bytes, size_t align) -> void* {
        off = (off + align - 1) & ~(align - 1);
        void* p = wsbase + off;
        off += bytes;
        return p;
    };
    double*   statBuf = (double*)alloc((size_t)64 * 2048 * sizeof(double), 256); // per-gate stats (1024 sum + 1024 sumsq)
    float*    h_buf  = (float*)alloc((size_t)2 * ND * sizeof(float), 256);       // 67 MB
    float*    Pf     = (float*)alloc((size_t)M2 * 1024 * sizeof(float), 256);    // 134 MB
    uint8_t*  Wdig   = (uint8_t*)alloc((size_t)WD_TOTAL, 256);                   // 10.5 MB
    uint64_t* s_bits = (uint64_t*)alloc((size_t)2 * N_NODES * 8 * 8, 256);
    uint64_t* q_bits = (uint64_t*)alloc((size_t)2 * N_NODES * 8 * 8, 256);
    uint64_t* k_bits = (uint64_t*)alloc((size_t)2 * N_NODES * 8 * 8, 256);
    uint64_t* v_bits = (uint64_t*)alloc((size_t)2 * N_NODES * 8 * 8, 256);
    uint64_t* m_bits = (uint64_t*)alloc((size_t)2 * N_NODES * 16 * 8, 256);      // 4.2 MB
    float*    ybuf   = (float*)m_bits;  // alias: y written at head, after m_bits dead
    (void)alloc((size_t)2 * NC * sizeof(float) > (size_t)2 * N_NODES * 16 * 8
                ? (size_t)2 * NC * sizeof(float) - (size_t)2 * N_NODES * 16 * 8 : 0, 256);
    float*    g0     = (float*)alloc((size_t)NC * sizeof(float), 256);
    float*    gg     = (float*)alloc((size_t)NC * sizeof(float), 256);
    float*    ag     = (float*)alloc((size_t)NC * sizeof(float), 256);
    float*    kvb    = (float*)alloc((size_t)65536 * sizeof(float), 256);
    float*    deg    = (float*)alloc((size_t)N_NODES * sizeof(float), 256);
    if (off > ws_size) return;

    const dim3 blk(256);
    const dim3 gBN512((unsigned)(2 * N_NODES));       // N*512/256
    const dim3 gBN1024((unsigned)(4 * N_NODES));      // N*1024/256
    const dim3 gGEMM(8, M2 / 128);                    // 512 cols per launch
    const dim3 gGEMMw1(16, M2 / 128);                 // 1024 cols per launch
    const double invM2 = 1.0 / (double)M2;
    const double invMN = 1.0 / (double)N_NODES;

    hipMemsetAsync(statBuf, 0, (size_t)64 * 2048 * sizeof(double), stream);

    int gate = 0;
    auto nextStat = [&]() { return statBuf + (size_t)(gate++) * 2048; };

    // ===== transformer branch =====
    hipLaunchKernelGGL(gemm_f32d, dim3(8, N_NODES / 64), blk, 0, stream,
                       x, 512, fc0_w, 512, fc0_b, Pf, 512, N_NODES, 512, 512);
    hipLaunchKernelGGL(ln_relu_lif, dim3(N_NODES), blk, 0, stream, Pf, ln_g, ln_b, h_buf, s_bits);

    for (int l = 0; l < 4; ++l) {
        // one prep launch for all 6 matrices of this layer
        hipLaunchKernelGGL(w_digits_layer, dim3(512), blk, 0, stream,
                           wq + (size_t)l * 262144, wk + (size_t)l * 262144,
                           wv + (size_t)l * 262144, wo + (size_t)l * 262144,
                           w1 + (size_t)l * 524288, w2 + (size_t)l * 524288, Wdig);

        uint64_t* qkvb[3] = {q_bits, k_bits, v_bits};
        const size_t wdoff[3] = {WD_Q, WD_K, WD_V};
        const float* gmat[3] = {bnq_g + l * 512, bnk_g + l * 512, bnv_g + l * 512};
        const float* bmat[3] = {bnq_b + l * 512, bnk_b + l * 512, bnv_b + l * 512};
        for (int j = 0; j < 3; ++j) {
            double* st = nextStat();
            hipLaunchKernelGGL(gemm_i8_bits, gGEMM, blk, 0, stream,
                               s_bits, 8, Wdig + wdoff[j], 512, 0, Pf, 512, 512, st, st + 1024);
            hipLaunchKernelGGL(bn_lif_bits2, gBN512, blk, 0, stream,
                               Pf, st, st + 1024, gmat[j], bmat[j], invM2, qkvb[j], 9, 8);
        }

        // attention (exact); fused O-proj input: lif(o) bits -> q_bits in place
        hipMemsetAsync(kvb, 0, 65536 * sizeof(float), stream);
        hipLaunchKernelGGL(kv_bits, dim3(16, 16), blk, 0, stream, k_bits, v_bits, kvb, 1024);
        hipLaunchKernelGGL(o_lif_bits, dim3(N_NODES / 64, 8), blk, 0, stream, q_bits, kvb, q_bits);

        // h += bn(lif(o) @ wo); emit s = lif(h_new) into s_bits
        {
            double* st = nextStat();
            hipLaunchKernelGGL(gemm_i8_bits, gGEMM, blk, 0, stream,
                               q_bits, 8, Wdig + WD_O, 512, 0, Pf, 512, 512, st, st + 1024);
            hipLaunchKernelGGL(bn_add_lif2, gBN512, blk, 0, stream,
                               Pf, st, st + 1024, bno_g + l * 512, bno_b + l * 512,
                               invM2, h_buf, s_bits);
        }

        // MLP: m = lif(bn1(s @ w1)) — single 1024-col launch
        {
            double* st = nextStat();
            hipLaunchKernelGGL(gemm_i8_bits, gGEMMw1, blk, 0, stream,
                               s_bits, 8, Wdig + WD_1, 1024, 0, Pf, 1024, 512, st, st + 1024);
            hipLaunchKernelGGL(bn_lif_bits2, gBN1024, blk, 0, stream,
                               Pf, st, st + 1024, bn1_g + l * 1024, bn1_b + l * 1024,
                               invM2, m_bits, 10, 16);
        }
        // h += bn2(m @ w2); emit s = lif(h_new) for next layer / head
        {
            double* st = nextStat();
            hipLaunchKernelGGL(gemm_i8_bits, gGEMM, blk, 0, stream,
                               m_bits, 16, Wdig + WD_2, 512, 0, Pf, 512, 1024, st, st + 1024);
            hipLaunchKernelGGL(bn_add_lif2, gBN512, blk, 0, stream,
                               Pf, st, st + 1024, bn2_g + l * 512, bn2_b + l * 512,
                               invM2, h_buf, s_bits);
        }
    }

    // head: y = s @ head_w + head_b (s_bits already = lif(h_final))
    hipLaunchKernelGGL(head_gather, dim3(M2 / 4), blk, 0, stream, s_bits, head_w, head_b, ybuf);

    // ===== GNN branch (fp32) =====
    hipLaunchKernelGGL(gemm_f32, dim3(1, N_NODES / 64), blk, 0, stream,
                       x, 512, gfc_w, 40, gfc_b, ag, 40, N_NODES, 40, 512);
    {
        double* st = nextStat();
        dim3 gs(1, (N_NODES + 511) / 512);
        hipLaunchKernelGGL(col_stats_f, gs, blk, 0, stream, ag, N_NODES, 40, 512, st, st + 1024);
        hipLaunchKernelGGL(bn_relu_add_f2, grid1(NC), blk, 0, stream,
                           ag, st, st + 1024, gbn0_g, gbn0_b, invMN,
                           (const float*)nullptr, g0, NC, 40);
    }

    hipMemsetAsync(deg, 0, N_NODES * sizeof(float), stream);
    hipLaunchKernelGGL(deg_kernel, grid1(E), blk, 0, stream, ecol, deg, E);
    hipLaunchKernelGGL(dinv_kernel, grid1(N_NODES), blk, 0, stream, deg, N_NODES);

    const float* gsrc = g0;
    for (int i = 0; i < 2; ++i) {
        hipMemsetAsync(ag, 0, (size_t)NC * sizeof(float), stream);
        hipLaunchKernelGGL(agg_kernel, grid1((long)E * C_OUT), blk, 0, stream,
                           gsrc, erow, ecol, deg, ag, E);
        hipLaunchKernelGGL(gemm_f32, dim3(1, N_NODES / 64), blk, 0, stream,
                           ag, 40, gconv_w + (size_t)i * 40 * 40, 40, gconv_b + i * 40,
                           gg, 40, N_NODES, 40, 40);
        double* st = nextStat();
        dim3 gs(1, (N_NODES + 511) / 512);
        hipLaunchKernelGGL(col_stats_f, gs, blk, 0, stream, gg, N_NODES, 40, 512, st, st + 1024);
        hipLaunchKernelGGL(bn_relu_add_f2, grid1(NC), blk, 0, stream,
                           gg, st, st + 1024, gbn_g + i * 40, gbn_b + i * 40, invMN, g0, gg, NC, 40);
        gsrc = gg;
    }

    // out = (0.8*g + 0.2*mean_t(y)) @ fc_w + fc_b
    hipLaunchKernelGGL(mix_kernel, grid1(NC), blk, 0, stream, gg, ybuf, ag, NC);
    hipLaunchKernelGGL(final_fc_kernel, grid1((long)N_NODES * C_OUT), blk, 0, stream,
                       ag, fc_w, fc_b, (float*)d_out);
}